// Round 1
// baseline (2163.853 us; speedup 1.0000x reference)
//
#include <hip/hip_runtime.h>

#define NN 50000
#define FIN 128
#define HID 256
#define NE 1600000
#define NBG 64
#define NC 10

static __device__ __forceinline__ unsigned fenc(float f){
  unsigned u = __float_as_uint(f);
  return (u & 0x80000000u) ? ~u : (u | 0x80000000u);
}
static __device__ __forceinline__ float fdec(unsigned u){
  return (u & 0x80000000u) ? __uint_as_float(u & 0x7fffffffu) : __uint_as_float(~u);
}

__global__ void k_init(int* __restrict__ deg, unsigned* __restrict__ menc,
                       float* __restrict__ s, float* __restrict__ pooled){
  int i = blockIdx.x*256 + threadIdx.x;
  if (i < NN) deg[i] = 0;
  if (i < NBG*HID) pooled[i] = 0.f;
  if (i < NBG){ s[i] = 0.f; menc[i] = fenc(-3.0e38f); }
}

__global__ void k_hist(const int* __restrict__ dst, int* __restrict__ deg){
  for (int e = blockIdx.x*blockDim.x + threadIdx.x; e < NE; e += gridDim.x*blockDim.x)
    atomicAdd(&deg[dst[e]], 1);
}

__global__ void k_partial(const int* __restrict__ deg, int* __restrict__ part){
  __shared__ int sm[256];
  int t = threadIdx.x; int i0 = blockIdx.x*512;
  int v = 0;
  if (i0 + t < NN) v += deg[i0+t];
  if (i0 + t + 256 < NN) v += deg[i0+t+256];
  sm[t] = v; __syncthreads();
  for (int o=128;o>0;o>>=1){ if (t<o) sm[t]+=sm[t+o]; __syncthreads(); }
  if (t==0) part[blockIdx.x] = sm[0];
}

__global__ void k_scanp(const int* __restrict__ part, int* __restrict__ poffs, int nb){
  if (threadIdx.x==0 && blockIdx.x==0){
    int run=0;
    for (int i=0;i<nb;++i){ poffs[i]=run; run+=part[i]; }
  }
}

__global__ void k_chunkscan(const int* __restrict__ deg, const int* __restrict__ poffs,
                            int* __restrict__ rowp, int* __restrict__ cur, float* __restrict__ invd){
  __shared__ int buf[2][512];
  int t = threadIdx.x; int i = blockIdx.x*512 + t;
  int v = (i<NN)? deg[i] : 0;
  buf[0][t] = v; __syncthreads();
  int pp = 0;
  for (int off=1; off<512; off<<=1){
    int nv = buf[pp][t];
    if (t >= off) nv += buf[pp][t-off];
    buf[pp^1][t] = nv; __syncthreads(); pp ^= 1;
  }
  if (i < NN){
    int excl = poffs[blockIdx.x] + buf[pp][t] - v;
    rowp[i] = excl; cur[i] = excl;
    invd[i] = 1.0f / (float)max(v, 1);
  }
}

__global__ void k_scatter(const int* __restrict__ src, const int* __restrict__ dst,
                          int* __restrict__ cur, int* __restrict__ srcs){
  for (int e = blockIdx.x*blockDim.x + threadIdx.x; e < NE; e += gridDim.x*blockDim.x){
    int d = dst[e];
    int pos = atomicAdd(&cur[d], 1);
    srcs[pos] = src[e];
  }
}

// one wave per destination node; F/64 floats per lane
template<int F>
__global__ void k_agg(const float* __restrict__ x, const int* __restrict__ srcs,
                      const int* __restrict__ rowp, const int* __restrict__ deg,
                      const float* __restrict__ invd, float* __restrict__ out){
  constexpr int V = F/64;
  int w = blockIdx.x*4 + (threadIdx.x>>6);
  int lane = threadIdx.x & 63;
  if (w >= NN) return;
  int st = rowp[w], d = deg[w];
  float acc[V];
  #pragma unroll
  for (int v=0;v<V;++v) acc[v]=0.f;
  for (int j=0;j<d;++j){
    int idx = srcs[st+j];
    const float* p = x + (size_t)idx*F + lane*V;
    if constexpr (V==4){
      float4 vv = *(const float4*)p;
      acc[0]+=vv.x; acc[1]+=vv.y; acc[2]+=vv.z; acc[3]+=vv.w;
    } else {
      float2 vv = *(const float2*)p;
      acc[0]+=vv.x; acc[1]+=vv.y;
    }
  }
  float sc = invd[w];
  float* o = out + (size_t)w*HID + lane*V;   // output stride is always HID
  if constexpr (V==4){ float4 vv = {acc[0]*sc, acc[1]*sc, acc[2]*sc, acc[3]*sc}; *(float4*)o = vv; }
  else               { float2 vv = {acc[0]*sc, acc[1]*sc}; *(float2*)o = vv; }
}

// out[m][j] = relu( sum_k A1[m][k]*Wl[j][k] + sum_k A2[m][k]*Wr[j][k] + bias[j] )
// BM=128, BN=256 (full width -> block owns its rows; in-place over A1 is safe), BK=16
__global__ __launch_bounds__(512) void k_gemm(
    const float* __restrict__ A1, int ldA1,
    const float* __restrict__ A2, int ldA2,
    const float* __restrict__ Wl, const float* __restrict__ Wr, int F,
    const float* __restrict__ bias, float* __restrict__ out, int M)
{
  __shared__ float As[16][132];
  __shared__ float Bs[16][260];
  int t = threadIdx.x;
  int m0 = blockIdx.x * 128;
  int tx = t & 31, ty = t >> 5;
  float acc[2][2][4][4];
  #pragma unroll
  for (int a=0;a<2;++a)
  #pragma unroll
  for (int b=0;b<2;++b)
  #pragma unroll
  for (int c=0;c<4;++c)
  #pragma unroll
  for (int d=0;d<4;++d) acc[a][b][c][d]=0.f;

  int nk = (2*F)/16;
  int r = t >> 2, kq = t & 3;
  for (int kt=0; kt<nk; ++kt){
    int kk = kt*16 + kq*4;
    { // A tile: 128 rows x 16 k
      int m = m0 + r;
      float4 v = make_float4(0.f,0.f,0.f,0.f);
      if (m < M){
        const float* p = (kk < F) ? (A1 + (size_t)m*ldA1 + kk)
                                  : (A2 + (size_t)m*ldA2 + (kk - F));
        v = *(const float4*)p;
      }
      As[kq*4+0][r]=v.x; As[kq*4+1][r]=v.y; As[kq*4+2][r]=v.z; As[kq*4+3][r]=v.w;
    }
    { // B tile: 256 j x 16 k
      const float* W = (kk < F) ? Wl : Wr;
      int kl = (kk < F) ? kk : kk - F;
      #pragma unroll
      for (int pass=0; pass<2; ++pass){
        int jj = r + pass*128;
        float4 v = *(const float4*)(W + (size_t)jj*F + kl);
        Bs[kq*4+0][jj]=v.x; Bs[kq*4+1][jj]=v.y; Bs[kq*4+2][jj]=v.z; Bs[kq*4+3][jj]=v.w;
      }
    }
    __syncthreads();
    #pragma unroll
    for (int k=0;k<16;++k){
      float4 a0 = *(const float4*)&As[k][ty*4];
      float4 a1 = *(const float4*)&As[k][ty*4+64];
      float4 b0 = *(const float4*)&Bs[k][tx*4];
      float4 b1 = *(const float4*)&Bs[k][tx*4+128];
      float ar[2][4] = {{a0.x,a0.y,a0.z,a0.w},{a1.x,a1.y,a1.z,a1.w}};
      float br[2][4] = {{b0.x,b0.y,b0.z,b0.w},{b1.x,b1.y,b1.z,b1.w}};
      #pragma unroll
      for (int rr=0;rr<2;++rr)
      #pragma unroll
      for (int cc=0;cc<2;++cc)
      #pragma unroll
      for (int i=0;i<4;++i)
      #pragma unroll
      for (int c=0;c<4;++c)
        acc[rr][cc][i][c] = fmaf(ar[rr][i], br[cc][c], acc[rr][cc][i][c]);
    }
    __syncthreads();
  }
  #pragma unroll
  for (int rr=0;rr<2;++rr)
  #pragma unroll
  for (int i=0;i<4;++i){
    int m = m0 + rr*64 + ty*4 + i;
    if (m >= M) continue;
    #pragma unroll
    for (int cc=0;cc<2;++cc){
      int j = cc*128 + tx*4;
      float4 bb = *(const float4*)&bias[j];
      float4 v;
      v.x = fmaxf(acc[rr][cc][i][0] + bb.x, 0.f);
      v.y = fmaxf(acc[rr][cc][i][1] + bb.y, 0.f);
      v.z = fmaxf(acc[rr][cc][i][2] + bb.z, 0.f);
      v.w = fmaxf(acc[rr][cc][i][3] + bb.w, 0.f);
      *(float4*)(out + (size_t)m*HID + j) = v;
    }
  }
}

__global__ void k_gate(const float* __restrict__ h, const float* __restrict__ Wg,
                       const float* __restrict__ bg, const int* __restrict__ batch,
                       float* __restrict__ gate, unsigned* __restrict__ menc){
  int w = blockIdx.x*4 + (threadIdx.x>>6);
  int lane = threadIdx.x & 63;
  if (w >= NN) return;
  float4 hv = *(const float4*)(h + (size_t)w*HID + lane*4);
  float4 wg = *(const float4*)(Wg + lane*4);
  float d = hv.x*wg.x + hv.y*wg.y + hv.z*wg.z + hv.w*wg.w;
  #pragma unroll
  for (int o=32;o>0;o>>=1) d += __shfl_down(d, o);
  if (lane==0){
    float g = d + bg[0];
    gate[w] = g;
    atomicMax(&menc[batch[w]], fenc(g));
  }
}

__global__ void k_e(const float* __restrict__ gate, const int* __restrict__ batch,
                    const unsigned* __restrict__ menc, float* __restrict__ ex, float* __restrict__ s){
  int i = blockIdx.x*256 + threadIdx.x;
  if (i >= NN) return;
  int b = batch[i];
  float e = expf(gate[i] - fdec(menc[b]));
  ex[i] = e;
  atomicAdd(&s[b], e);
}

__global__ void k_c(float* __restrict__ ex, const int* __restrict__ batch, const float* __restrict__ s){
  int i = blockIdx.x*256 + threadIdx.x;
  if (i >= NN) return;
  ex[i] = ex[i] / s[batch[i]];
}

// batch is sorted: block handles 256 consecutive nodes, thread t = feature t,
// register-accumulate within a segment, atomic only at segment boundaries.
__global__ void k_pool(const float* __restrict__ h, const float* __restrict__ c,
                       const int* __restrict__ batch, float* __restrict__ pooled){
  int t = threadIdx.x;
  int i0 = blockIdx.x*256;
  int iend = min(i0+256, NN);
  float acc = 0.f;
  int bcur = batch[i0];
  for (int i=i0;i<iend;++i){
    int b = batch[i];
    if (b != bcur){
      atomicAdd(&pooled[bcur*HID + t], acc);
      acc = 0.f; bcur = b;
    }
    acc = fmaf(c[i], h[(size_t)i*HID + t], acc);
  }
  atomicAdd(&pooled[bcur*HID + t], acc);
}

__global__ void k_head(const float* __restrict__ pooled, const float* __restrict__ Wl1,
                       const float* __restrict__ bl1, const float* __restrict__ Wl2,
                       const float* __restrict__ bl2, float* __restrict__ out){
  __shared__ float pr[256]; __shared__ float o1[256]; __shared__ float lg[16];
  int b = blockIdx.x, t = threadIdx.x;
  pr[t] = pooled[b*HID + t];
  __syncthreads();
  float a = bl1[t];
  const float* wr = Wl1 + (size_t)t*HID;
  #pragma unroll 4
  for (int k=0;k<HID;k+=4){
    float4 w4 = *(const float4*)(wr + k);
    a += pr[k]*w4.x + pr[k+1]*w4.y + pr[k+2]*w4.z + pr[k+3]*w4.w;
  }
  o1[t] = fmaxf(a, 0.f);
  __syncthreads();
  if (t < NC){
    float a2 = bl2[t];
    const float* w2 = Wl2 + (size_t)t*HID;
    for (int k=0;k<HID;++k) a2 += o1[k]*w2[k];
    lg[t] = a2;
  }
  __syncthreads();
  if (t == 0){
    float mx = lg[0];
    for (int c2=1;c2<NC;++c2) mx = fmaxf(mx, lg[c2]);
    float se = 0.f;
    for (int c2=0;c2<NC;++c2) se += expf(lg[c2]-mx);
    float lse = mx + logf(se);
    for (int c2=0;c2<NC;++c2) out[b*NC + c2] = lg[c2] - lse;
  }
}

extern "C" void kernel_launch(void* const* d_in, const int* in_sizes, int n_in,
                              void* d_out, int out_size, void* d_ws, size_t ws_size,
                              hipStream_t stream){
  const float* x   = (const float*)d_in[0];
  const int*   ei  = (const int*)d_in[1];
  const int*   bat = (const int*)d_in[2];
  const float* W1l = (const float*)d_in[3];
  const float* b1l = (const float*)d_in[4];
  const float* W1r = (const float*)d_in[5];
  const float* W2l = (const float*)d_in[6];
  const float* b2l = (const float*)d_in[7];
  const float* W2r = (const float*)d_in[8];
  const float* W3l = (const float*)d_in[9];
  const float* b3l = (const float*)d_in[10];
  const float* W3r = (const float*)d_in[11];
  const float* Wg  = (const float*)d_in[12];
  const float* bg  = (const float*)d_in[13];
  const float* Wl1 = (const float*)d_in[14];
  const float* bl1 = (const float*)d_in[15];
  const float* Wl2 = (const float*)d_in[16];
  const float* bl2 = (const float*)d_in[17];
  const int* srcI = ei;
  const int* dstI = ei + NE;
  float* out = (float*)d_out;

  char* w = (char*)d_ws;
  auto take = [&](size_t bytes)->char*{
    char* p = w; w += (bytes + 255) & ~(size_t)255; return p;
  };
  int*      deg    = (int*)take((size_t)NN*4);
  float*    invd   = (float*)take((size_t)NN*4);
  int*      rowp   = (int*)take((size_t)NN*4);
  int*      cur    = (int*)take((size_t)NN*4);
  int*      srcs   = (int*)take((size_t)NE*4);
  int*      part   = (int*)take(128*4);
  int*      poffs  = (int*)take(128*4);
  float*    gate   = (float*)take((size_t)NN*4);
  float*    ex     = (float*)take((size_t)NN*4);
  unsigned* menc   = (unsigned*)take(64*4);
  float*    s      = (float*)take(64*4);
  float*    pooled = (float*)take(64*256*4);
  float*    bufA   = (float*)take((size_t)NN*HID*4);
  float*    bufB   = (float*)take((size_t)NN*HID*4);

  int nb = (NN + 511)/512;

  k_init<<<(NN+255)/256, 256, 0, stream>>>(deg, menc, s, pooled);
  k_hist<<<1024, 256, 0, stream>>>(dstI, deg);
  k_partial<<<nb, 256, 0, stream>>>(deg, part);
  k_scanp<<<1, 64, 0, stream>>>(part, poffs, nb);
  k_chunkscan<<<nb, 512, 0, stream>>>(deg, poffs, rowp, cur, invd);
  k_scatter<<<1024, 256, 0, stream>>>(srcI, dstI, cur, srcs);

  // layer 1: agg(x) -> bufA ; h1 = gemm(bufA, x) -> bufB
  k_agg<128><<<(NN+3)/4, 256, 0, stream>>>(x, srcs, rowp, deg, invd, bufA);
  k_gemm<<<(NN+127)/128, 512, 0, stream>>>(bufA, HID, x, FIN, W1l, W1r, FIN, b1l, bufB, NN);
  // layer 2: agg(h1=bufB) -> bufA ; h2 = gemm(bufA, bufB) -> bufA (in-place safe: BN=full width)
  k_agg<256><<<(NN+3)/4, 256, 0, stream>>>(bufB, srcs, rowp, deg, invd, bufA);
  k_gemm<<<(NN+127)/128, 512, 0, stream>>>(bufA, HID, bufB, HID, W2l, W2r, HID, b2l, bufA, NN);
  // layer 3: agg(h2=bufA) -> bufB ; h3 = gemm(bufB, bufA) -> bufB
  k_agg<256><<<(NN+3)/4, 256, 0, stream>>>(bufA, srcs, rowp, deg, invd, bufB);
  k_gemm<<<(NN+127)/128, 512, 0, stream>>>(bufB, HID, bufA, HID, W3l, W3r, HID, b3l, bufB, NN);

  // attention pooling over h3 = bufB
  k_gate<<<(NN+3)/4, 256, 0, stream>>>(bufB, Wg, bg, bat, gate, menc);
  k_e<<<(NN+255)/256, 256, 0, stream>>>(gate, bat, menc, ex, s);
  k_c<<<(NN+255)/256, 256, 0, stream>>>(ex, bat, s);
  k_pool<<<(NN+255)/256, 256, 0, stream>>>(bufB, ex, bat, pooled);
  k_head<<<NBG, 256, 0, stream>>>(pooled, Wl1, bl1, Wl2, bl2, out);
}

// Round 2
// 1530.461 us; speedup vs baseline: 1.4139x; 1.4139x over previous
//
#include <hip/hip_runtime.h>

#define NN 50000
#define FIN 128
#define HID 256
#define NE 1600000
#define NBG 64
#define NC 10

__global__ void k_init(int* __restrict__ deg, float* __restrict__ pooled){
  int i = blockIdx.x*256 + threadIdx.x;
  if (i < NN) deg[i] = 0;
  if (i < NBG*HID) pooled[i] = 0.f;
}

__global__ void k_hist(const int* __restrict__ dst, int* __restrict__ deg){
  for (int e = blockIdx.x*blockDim.x + threadIdx.x; e < NE; e += gridDim.x*blockDim.x)
    atomicAdd(&deg[dst[e]], 1);
}

__global__ void k_partial(const int* __restrict__ deg, int* __restrict__ part){
  __shared__ int sm[256];
  int t = threadIdx.x; int i0 = blockIdx.x*512;
  int v = 0;
  if (i0 + t < NN) v += deg[i0+t];
  if (i0 + t + 256 < NN) v += deg[i0+t+256];
  sm[t] = v; __syncthreads();
  for (int o=128;o>0;o>>=1){ if (t<o) sm[t]+=sm[t+o]; __syncthreads(); }
  if (t==0) part[blockIdx.x] = sm[0];
}

__global__ void k_scanp(const int* __restrict__ part, int* __restrict__ poffs, int nb){
  if (threadIdx.x==0 && blockIdx.x==0){
    int run=0;
    for (int i=0;i<nb;++i){ poffs[i]=run; run+=part[i]; }
  }
}

__global__ void k_chunkscan(const int* __restrict__ deg, const int* __restrict__ poffs,
                            int* __restrict__ rowp, int* __restrict__ cur, float* __restrict__ invd){
  __shared__ int buf[2][512];
  int t = threadIdx.x; int i = blockIdx.x*512 + t;
  int v = (i<NN)? deg[i] : 0;
  buf[0][t] = v; __syncthreads();
  int pp = 0;
  for (int off=1; off<512; off<<=1){
    int nv = buf[pp][t];
    if (t >= off) nv += buf[pp][t-off];
    buf[pp^1][t] = nv; __syncthreads(); pp ^= 1;
  }
  if (i < NN){
    int excl = poffs[blockIdx.x] + buf[pp][t] - v;
    rowp[i] = excl; cur[i] = excl;
    invd[i] = 1.0f / (float)max(v, 1);
  }
}

__global__ void k_scatter(const int* __restrict__ src, const int* __restrict__ dst,
                          int* __restrict__ cur, int* __restrict__ srcs){
  for (int e = blockIdx.x*blockDim.x + threadIdx.x; e < NE; e += gridDim.x*blockDim.x){
    int d = dst[e];
    int pos = atomicAdd(&cur[d], 1);
    srcs[pos] = src[e];
  }
}

// one wave per destination node; F/64 floats per lane
template<int F>
__global__ void k_agg(const float* __restrict__ x, const int* __restrict__ srcs,
                      const int* __restrict__ rowp, const int* __restrict__ deg,
                      const float* __restrict__ invd, float* __restrict__ out){
  constexpr int V = F/64;
  int w = blockIdx.x*4 + (threadIdx.x>>6);
  int lane = threadIdx.x & 63;
  if (w >= NN) return;
  int st = rowp[w], d = deg[w];
  float acc[V];
  #pragma unroll
  for (int v=0;v<V;++v) acc[v]=0.f;
  for (int j=0;j<d;++j){
    int idx = srcs[st+j];
    const float* p = x + (size_t)idx*F + lane*V;
    if constexpr (V==4){
      float4 vv = *(const float4*)p;
      acc[0]+=vv.x; acc[1]+=vv.y; acc[2]+=vv.z; acc[3]+=vv.w;
    } else {
      float2 vv = *(const float2*)p;
      acc[0]+=vv.x; acc[1]+=vv.y;
    }
  }
  float sc = invd[w];
  float* o = out + (size_t)w*HID + lane*V;   // output stride is always HID
  if constexpr (V==4){ float4 vv = {acc[0]*sc, acc[1]*sc, acc[2]*sc, acc[3]*sc}; *(float4*)o = vv; }
  else               { float2 vv = {acc[0]*sc, acc[1]*sc}; *(float2*)o = vv; }
}

// out[m][j] = relu( sum_k A1[m][k]*Wl[j][k] + sum_k A2[m][k]*Wr[j][k] + bias[j] )
// BM=128, BN=256 (full width -> block owns its rows; in-place over A1 is safe), BK=16
__global__ __launch_bounds__(512) void k_gemm(
    const float* __restrict__ A1, int ldA1,
    const float* __restrict__ A2, int ldA2,
    const float* __restrict__ Wl, const float* __restrict__ Wr, int F,
    const float* __restrict__ bias, float* __restrict__ out, int M)
{
  __shared__ float As[16][132];
  __shared__ float Bs[16][260];
  int t = threadIdx.x;
  int m0 = blockIdx.x * 128;
  int tx = t & 31, ty = t >> 5;
  float acc[2][2][4][4];
  #pragma unroll
  for (int a=0;a<2;++a)
  #pragma unroll
  for (int b=0;b<2;++b)
  #pragma unroll
  for (int c=0;c<4;++c)
  #pragma unroll
  for (int d=0;d<4;++d) acc[a][b][c][d]=0.f;

  int nk = (2*F)/16;
  int r = t >> 2, kq = t & 3;
  for (int kt=0; kt<nk; ++kt){
    int kk = kt*16 + kq*4;
    { // A tile: 128 rows x 16 k
      int m = m0 + r;
      float4 v = make_float4(0.f,0.f,0.f,0.f);
      if (m < M){
        const float* p = (kk < F) ? (A1 + (size_t)m*ldA1 + kk)
                                  : (A2 + (size_t)m*ldA2 + (kk - F));
        v = *(const float4*)p;
      }
      As[kq*4+0][r]=v.x; As[kq*4+1][r]=v.y; As[kq*4+2][r]=v.z; As[kq*4+3][r]=v.w;
    }
    { // B tile: 256 j x 16 k
      const float* W = (kk < F) ? Wl : Wr;
      int kl = (kk < F) ? kk : kk - F;
      #pragma unroll
      for (int pass=0; pass<2; ++pass){
        int jj = r + pass*128;
        float4 v = *(const float4*)(W + (size_t)jj*F + kl);
        Bs[kq*4+0][jj]=v.x; Bs[kq*4+1][jj]=v.y; Bs[kq*4+2][jj]=v.z; Bs[kq*4+3][jj]=v.w;
      }
    }
    __syncthreads();
    #pragma unroll
    for (int k=0;k<16;++k){
      float4 a0 = *(const float4*)&As[k][ty*4];
      float4 a1 = *(const float4*)&As[k][ty*4+64];
      float4 b0 = *(const float4*)&Bs[k][tx*4];
      float4 b1 = *(const float4*)&Bs[k][tx*4+128];
      float ar[2][4] = {{a0.x,a0.y,a0.z,a0.w},{a1.x,a1.y,a1.z,a1.w}};
      float br[2][4] = {{b0.x,b0.y,b0.z,b0.w},{b1.x,b1.y,b1.z,b1.w}};
      #pragma unroll
      for (int rr=0;rr<2;++rr)
      #pragma unroll
      for (int cc=0;cc<2;++cc)
      #pragma unroll
      for (int i=0;i<4;++i)
      #pragma unroll
      for (int c=0;c<4;++c)
        acc[rr][cc][i][c] = fmaf(ar[rr][i], br[cc][c], acc[rr][cc][i][c]);
    }
    __syncthreads();
  }
  #pragma unroll
  for (int rr=0;rr<2;++rr)
  #pragma unroll
  for (int i=0;i<4;++i){
    int m = m0 + rr*64 + ty*4 + i;
    if (m >= M) continue;
    #pragma unroll
    for (int cc=0;cc<2;++cc){
      int j = cc*128 + tx*4;
      float4 bb = *(const float4*)&bias[j];
      float4 v;
      v.x = fmaxf(acc[rr][cc][i][0] + bb.x, 0.f);
      v.y = fmaxf(acc[rr][cc][i][1] + bb.y, 0.f);
      v.z = fmaxf(acc[rr][cc][i][2] + bb.z, 0.f);
      v.w = fmaxf(acc[rr][cc][i][3] + bb.w, 0.f);
      *(float4*)(out + (size_t)m*HID + j) = v;
    }
  }
}

// gate GEMV only — no atomics
__global__ void k_gate(const float* __restrict__ h, const float* __restrict__ Wg,
                       const float* __restrict__ bg, float* __restrict__ gate){
  int w = blockIdx.x*4 + (threadIdx.x>>6);
  int lane = threadIdx.x & 63;
  if (w >= NN) return;
  float4 hv = *(const float4*)(h + (size_t)w*HID + lane*4);
  float4 wg = *(const float4*)(Wg + lane*4);
  float d = hv.x*wg.x + hv.y*wg.y + hv.z*wg.z + hv.w*wg.w;
  #pragma unroll
  for (int o=32;o>0;o>>=1) d += __shfl_down(d, o);
  if (lane==0) gate[w] = d + bg[0];
}

// segment starts via binary search over sorted batch (handles empty segments)
__global__ void k_seg(const int* __restrict__ batch, int* __restrict__ starts){
  int b = threadIdx.x;
  if (b > NBG) return;
  int lo = 0, hi = NN;
  while (lo < hi){ int mid = (lo+hi)>>1; if (batch[mid] < b) lo = mid+1; else hi = mid; }
  starts[b] = lo;
}

// per-segment max and sum-of-exp, one block per batch element, no atomics
__global__ void k_msum(const float* __restrict__ gate, const int* __restrict__ starts,
                       float* __restrict__ m, float* __restrict__ s){
  __shared__ float sm[256];
  int b = blockIdx.x, t = threadIdx.x;
  int st = starts[b], en = starts[b+1];
  float mx = -3.0e38f;
  for (int i = st + t; i < en; i += 256) mx = fmaxf(mx, gate[i]);
  sm[t] = mx; __syncthreads();
  for (int o=128;o>0;o>>=1){ if (t<o) sm[t]=fmaxf(sm[t],sm[t+o]); __syncthreads(); }
  float M = sm[0]; __syncthreads();
  float su = 0.f;
  for (int i = st + t; i < en; i += 256) su += expf(gate[i]-M);
  sm[t] = su; __syncthreads();
  for (int o=128;o>0;o>>=1){ if (t<o) sm[t]+=sm[t+o]; __syncthreads(); }
  if (t==0){ m[b]=M; s[b]=sm[0]; }
}

// fused attention-weight + pooling: block = 256 consecutive nodes, thread = feature,
// a_i precomputed in shared, register accumulate, atomic only at segment boundaries.
__global__ void k_pool(const float* __restrict__ h, const float* __restrict__ gate,
                       const int* __restrict__ batch, const float* __restrict__ m,
                       const float* __restrict__ s, float* __restrict__ pooled){
  __shared__ float sa[256];
  __shared__ int sb[256];
  int t = threadIdx.x;
  int i0 = blockIdx.x*256;
  int iend = min(i0+256, NN);
  {
    int i = i0 + t;
    if (i < NN){
      int b = batch[i];
      sb[t] = b;
      sa[t] = expf(gate[i] - m[b]) / s[b];
    }
  }
  __syncthreads();
  float acc = 0.f;
  int bcur = sb[0];
  for (int i=i0;i<iend;++i){
    int b = sb[i-i0];
    if (b != bcur){
      atomicAdd(&pooled[bcur*HID + t], acc);
      acc = 0.f; bcur = b;
    }
    acc = fmaf(sa[i-i0], h[(size_t)i*HID + t], acc);
  }
  atomicAdd(&pooled[bcur*HID + t], acc);
}

__global__ void k_head(const float* __restrict__ pooled, const float* __restrict__ Wl1,
                       const float* __restrict__ bl1, const float* __restrict__ Wl2,
                       const float* __restrict__ bl2, float* __restrict__ out){
  __shared__ float pr[256]; __shared__ float o1[256]; __shared__ float lg[16];
  int b = blockIdx.x, t = threadIdx.x;
  pr[t] = pooled[b*HID + t];
  __syncthreads();
  float a = bl1[t];
  const float* wr = Wl1 + (size_t)t*HID;
  #pragma unroll 4
  for (int k=0;k<HID;k+=4){
    float4 w4 = *(const float4*)(wr + k);
    a += pr[k]*w4.x + pr[k+1]*w4.y + pr[k+2]*w4.z + pr[k+3]*w4.w;
  }
  o1[t] = fmaxf(a, 0.f);
  __syncthreads();
  if (t < NC){
    float a2 = bl2[t];
    const float* w2 = Wl2 + (size_t)t*HID;
    for (int k=0;k<HID;++k) a2 += o1[k]*w2[k];
    lg[t] = a2;
  }
  __syncthreads();
  if (t == 0){
    float mx = lg[0];
    for (int c2=1;c2<NC;++c2) mx = fmaxf(mx, lg[c2]);
    float se = 0.f;
    for (int c2=0;c2<NC;++c2) se += expf(lg[c2]-mx);
    float lse = mx + logf(se);
    for (int c2=0;c2<NC;++c2) out[b*NC + c2] = lg[c2] - lse;
  }
}

extern "C" void kernel_launch(void* const* d_in, const int* in_sizes, int n_in,
                              void* d_out, int out_size, void* d_ws, size_t ws_size,
                              hipStream_t stream){
  const float* x   = (const float*)d_in[0];
  const int*   ei  = (const int*)d_in[1];
  const int*   bat = (const int*)d_in[2];
  const float* W1l = (const float*)d_in[3];
  const float* b1l = (const float*)d_in[4];
  const float* W1r = (const float*)d_in[5];
  const float* W2l = (const float*)d_in[6];
  const float* b2l = (const float*)d_in[7];
  const float* W2r = (const float*)d_in[8];
  const float* W3l = (const float*)d_in[9];
  const float* b3l = (const float*)d_in[10];
  const float* W3r = (const float*)d_in[11];
  const float* Wg  = (const float*)d_in[12];
  const float* bg  = (const float*)d_in[13];
  const float* Wl1 = (const float*)d_in[14];
  const float* bl1 = (const float*)d_in[15];
  const float* Wl2 = (const float*)d_in[16];
  const float* bl2 = (const float*)d_in[17];
  const int* srcI = ei;
  const int* dstI = ei + NE;
  float* out = (float*)d_out;

  char* w = (char*)d_ws;
  auto take = [&](size_t bytes)->char*{
    char* p = w; w += (bytes + 255) & ~(size_t)255; return p;
  };
  int*      deg    = (int*)take((size_t)NN*4);
  float*    invd   = (float*)take((size_t)NN*4);
  int*      rowp   = (int*)take((size_t)NN*4);
  int*      cur    = (int*)take((size_t)NN*4);
  int*      srcs   = (int*)take((size_t)NE*4);
  int*      part   = (int*)take(128*4);
  int*      poffs  = (int*)take(128*4);
  float*    gate   = (float*)take((size_t)NN*4);
  int*      starts = (int*)take(128*4);
  float*    m      = (float*)take(64*4);
  float*    s      = (float*)take(64*4);
  float*    pooled = (float*)take(64*256*4);
  float*    bufA   = (float*)take((size_t)NN*HID*4);
  float*    bufB   = (float*)take((size_t)NN*HID*4);

  int nb = (NN + 511)/512;

  k_init<<<(NN+255)/256, 256, 0, stream>>>(deg, pooled);
  k_hist<<<1024, 256, 0, stream>>>(dstI, deg);
  k_partial<<<nb, 256, 0, stream>>>(deg, part);
  k_scanp<<<1, 64, 0, stream>>>(part, poffs, nb);
  k_chunkscan<<<nb, 512, 0, stream>>>(deg, poffs, rowp, cur, invd);
  k_scatter<<<1024, 256, 0, stream>>>(srcI, dstI, cur, srcs);

  // layer 1: agg(x) -> bufA ; h1 = gemm(bufA, x) -> bufB
  k_agg<128><<<(NN+3)/4, 256, 0, stream>>>(x, srcs, rowp, deg, invd, bufA);
  k_gemm<<<(NN+127)/128, 512, 0, stream>>>(bufA, HID, x, FIN, W1l, W1r, FIN, b1l, bufB, NN);
  // layer 2: agg(h1=bufB) -> bufA ; h2 = gemm(bufA, bufB) -> bufA (in-place safe: BN=full width)
  k_agg<256><<<(NN+3)/4, 256, 0, stream>>>(bufB, srcs, rowp, deg, invd, bufA);
  k_gemm<<<(NN+127)/128, 512, 0, stream>>>(bufA, HID, bufB, HID, W2l, W2r, HID, b2l, bufA, NN);
  // layer 3: agg(h2=bufA) -> bufB ; h3 = gemm(bufB, bufA) -> bufB
  k_agg<256><<<(NN+3)/4, 256, 0, stream>>>(bufA, srcs, rowp, deg, invd, bufB);
  k_gemm<<<(NN+127)/128, 512, 0, stream>>>(bufB, HID, bufA, HID, W3l, W3r, HID, b3l, bufB, NN);

  // attention pooling over h3 = bufB
  k_gate<<<(NN+3)/4, 256, 0, stream>>>(bufB, Wg, bg, gate);
  k_seg<<<1, 128, 0, stream>>>(bat, starts);
  k_msum<<<NBG, 256, 0, stream>>>(gate, starts, m, s);
  k_pool<<<(NN+255)/256, 256, 0, stream>>>(bufB, gate, bat, m, s, pooled);
  k_head<<<NBG, 256, 0, stream>>>(pooled, Wl1, bl1, Wl2, bl2, out);
}

// Round 3
// 990.467 us; speedup vs baseline: 2.1847x; 1.5452x over previous
//
#include <hip/hip_runtime.h>

#define NN 50000
#define FIN 128
#define HID 256
#define NE 1600000
#define NBG 64
#define NC 10

typedef short bf16x8 __attribute__((ext_vector_type(8)));
typedef float f32x4 __attribute__((ext_vector_type(4)));

static __device__ __forceinline__ ushort f2b(float f){
  unsigned u = __float_as_uint(f);
  unsigned r = (u + 0x7FFFu + ((u >> 16) & 1u)) >> 16;
  return (ushort)r;
}
static __device__ __forceinline__ float b2f(ushort u){
  return __uint_as_float(((unsigned)u) << 16);
}

__global__ void k_init(int* __restrict__ deg, float* __restrict__ pooled){
  int i = blockIdx.x*256 + threadIdx.x;
  if (i < NN) deg[i] = 0;
  if (i < NBG*HID) pooled[i] = 0.f;
}

// x fp32 [NN][128] -> bf16
__global__ void k_xb(const float* __restrict__ x, ushort* __restrict__ xb){
  int i = blockIdx.x*256 + threadIdx.x;           // element quad index
  if (i >= NN*FIN/4) return;
  float4 v = *(const float4*)(x + (size_t)i*4);
  ushort4 o; o.x=f2b(v.x); o.y=f2b(v.y); o.z=f2b(v.z); o.w=f2b(v.w);
  *(ushort4*)(xb + (size_t)i*4) = o;
}

// Wcat bf16 [256][2F] = [Wl | Wr]
__global__ void k_wcat(const float* __restrict__ Wl, const float* __restrict__ Wr,
                       int F, ushort* __restrict__ Wc){
  int F2 = 2*F;
  int i = blockIdx.x*256 + threadIdx.x;
  if (i >= HID*F2) return;
  int n = i / F2, k = i % F2;
  float v = (k < F) ? Wl[(size_t)n*F + k] : Wr[(size_t)n*F + (k-F)];
  Wc[i] = f2b(v);
}

__global__ void k_hist(const int* __restrict__ dst, int* __restrict__ deg){
  for (int e = blockIdx.x*blockDim.x + threadIdx.x; e < NE; e += gridDim.x*blockDim.x)
    atomicAdd(&deg[dst[e]], 1);
}

__global__ void k_partial(const int* __restrict__ deg, int* __restrict__ part){
  __shared__ int sm[256];
  int t = threadIdx.x; int i0 = blockIdx.x*512;
  int v = 0;
  if (i0 + t < NN) v += deg[i0+t];
  if (i0 + t + 256 < NN) v += deg[i0+t+256];
  sm[t] = v; __syncthreads();
  for (int o=128;o>0;o>>=1){ if (t<o) sm[t]+=sm[t+o]; __syncthreads(); }
  if (t==0) part[blockIdx.x] = sm[0];
}

__global__ void k_scanp(const int* __restrict__ part, int* __restrict__ poffs, int nb){
  if (threadIdx.x==0 && blockIdx.x==0){
    int run=0;
    for (int i=0;i<nb;++i){ poffs[i]=run; run+=part[i]; }
  }
}

__global__ void k_chunkscan(const int* __restrict__ deg, const int* __restrict__ poffs,
                            int* __restrict__ rowp, int* __restrict__ cur, float* __restrict__ invd){
  __shared__ int buf[2][512];
  int t = threadIdx.x; int i = blockIdx.x*512 + t;
  int v = (i<NN)? deg[i] : 0;
  buf[0][t] = v; __syncthreads();
  int pp = 0;
  for (int off=1; off<512; off<<=1){
    int nv = buf[pp][t];
    if (t >= off) nv += buf[pp][t-off];
    buf[pp^1][t] = nv; __syncthreads(); pp ^= 1;
  }
  if (i < NN){
    int excl = poffs[blockIdx.x] + buf[pp][t] - v;
    rowp[i] = excl; cur[i] = excl;
    invd[i] = 1.0f / (float)max(v, 1);
  }
}

__global__ void k_scatter(const int* __restrict__ src, const int* __restrict__ dst,
                          int* __restrict__ cur, int* __restrict__ srcs){
  for (int e = blockIdx.x*blockDim.x + threadIdx.x; e < NE; e += gridDim.x*blockDim.x){
    int d = dst[e];
    int pos = atomicAdd(&cur[d], 1);
    srcs[pos] = src[e];
  }
}

// one wave per destination node, bf16 rows, fp32 accumulate
template<int F>
__global__ void k_agg(const ushort* __restrict__ x, const int* __restrict__ srcs,
                      const int* __restrict__ rowp, const int* __restrict__ deg,
                      const float* __restrict__ invd, ushort* __restrict__ out){
  constexpr int V = F/64;                 // ushorts per lane: 2 or 4
  int w = blockIdx.x*4 + (threadIdx.x>>6);
  int lane = threadIdx.x & 63;
  if (w >= NN) return;
  int st = rowp[w], d = deg[w];
  float acc[V];
  #pragma unroll
  for (int v=0;v<V;++v) acc[v]=0.f;
  for (int j=0;j<d;++j){
    int idx = srcs[st+j];
    const ushort* p = x + (size_t)idx*F + lane*V;
    if constexpr (V==4){
      uint2 u = *(const uint2*)p;
      acc[0] += __uint_as_float(u.x<<16);
      acc[1] += __uint_as_float(u.x & 0xFFFF0000u);
      acc[2] += __uint_as_float(u.y<<16);
      acc[3] += __uint_as_float(u.y & 0xFFFF0000u);
    } else {
      unsigned u = *(const unsigned*)p;
      acc[0] += __uint_as_float(u<<16);
      acc[1] += __uint_as_float(u & 0xFFFF0000u);
    }
  }
  float sc = invd[w];
  ushort* o = out + (size_t)w*F + lane*V;
  if constexpr (V==4){
    ushort4 ov; ov.x=f2b(acc[0]*sc); ov.y=f2b(acc[1]*sc); ov.z=f2b(acc[2]*sc); ov.w=f2b(acc[3]*sc);
    *(ushort4*)o = ov;
  } else {
    ushort2 ov; ov.x=f2b(acc[0]*sc); ov.y=f2b(acc[1]*sc);
    *(ushort2*)o = ov;
  }
}

// MFMA GEMM: out[m][n] = relu( sum_k [A1|A2][m][k] * Wc[n][k] + bias[n] ), bf16 in, bf16 out
// BM=128, BN=256 (full width), BK=64, 512 threads = 8 waves (2 Mx4 N), wave tile 64x64.
// Computes transposed-operand mfma(W,X) so each lane stores 4 consecutive cols (ushort4).
#define LDT 72
__global__ __launch_bounds__(512) void k_gemm(
    const ushort* __restrict__ A1, int ldA1,
    const ushort* __restrict__ A2, int ldA2,
    const ushort* __restrict__ Wc, int F2,
    const float* __restrict__ bias, ushort* __restrict__ out, int M)
{
  __shared__ ushort As[128*LDT];
  __shared__ ushort Bs[256*LDT];
  int t = threadIdx.x;
  int l = t & 63;
  int wv = t >> 6;
  int wr = wv >> 2, wc = wv & 3;
  int m0 = blockIdx.x * 128;
  int F = F2 >> 1;
  f32x4 acc[4][4];
  #pragma unroll
  for (int a=0;a<4;++a)
  #pragma unroll
  for (int b=0;b<4;++b) acc[a][b] = (f32x4){0.f,0.f,0.f,0.f};

  int nsteps = F2/64;
  for (int s=0; s<nsteps; ++s){
    int kk = s*64;
    const ushort* src; int ld, kkl;
    if (kk < F){ src = A1; ld = ldA1; kkl = kk; }
    else       { src = A2; ld = ldA2; kkl = kk - F; }
    // A tile: 128 rows x 64 k = 1024 16B-chunks; thread does chunks 2t, 2t+1
    uint4 av[2];
    int arow[2], ack[2];
    #pragma unroll
    for (int i=0;i<2;++i){
      int c = t*2 + i;
      arow[i] = c >> 3; ack[i] = c & 7;
      int m = m0 + arow[i];
      av[i] = make_uint4(0u,0u,0u,0u);
      if (m < M) av[i] = *(const uint4*)(src + (size_t)m*ld + kkl + ack[i]*8);
    }
    // B tile: 256 rows x 64 k = 2048 chunks; thread does 4
    uint4 bv[4];
    int brow[4], bck[4];
    #pragma unroll
    for (int i=0;i<4;++i){
      int c = t*4 + i;
      brow[i] = c >> 3; bck[i] = c & 7;
      bv[i] = *(const uint4*)(Wc + (size_t)brow[i]*F2 + kk + bck[i]*8);
    }
    #pragma unroll
    for (int i=0;i<2;++i)
      *(uint4*)&As[arow[i]*LDT + ack[i]*8] = av[i];
    #pragma unroll
    for (int i=0;i<4;++i)
      *(uint4*)&Bs[brow[i]*LDT + bck[i]*8] = bv[i];
    __syncthreads();

    #pragma unroll
    for (int ks=0; ks<2; ++ks){
      bf16x8 af[4], bf[4];
      int ko = ks*32 + (l>>4)*8;
      #pragma unroll
      for (int mf=0; mf<4; ++mf)
        af[mf] = *(bf16x8*)&As[(wr*64 + mf*16 + (l&15))*LDT + ko];
      #pragma unroll
      for (int nf=0; nf<4; ++nf)
        bf[nf] = *(bf16x8*)&Bs[(wc*64 + nf*16 + (l&15))*LDT + ko];
      #pragma unroll
      for (int mf=0; mf<4; ++mf)
      #pragma unroll
      for (int nf=0; nf<4; ++nf)
        acc[mf][nf] = __builtin_amdgcn_mfma_f32_16x16x32_bf16(bf[nf], af[mf], acc[mf][nf], 0, 0, 0);
    }
    __syncthreads();
  }

  // epilogue: lane holds row m = (l&15)-derived, 4 consecutive cols = (l>>4)*4+r
  #pragma unroll
  for (int mf=0; mf<4; ++mf){
    int m = m0 + wr*64 + mf*16 + (l&15);
    if (m >= M) continue;
    #pragma unroll
    for (int nf=0; nf<4; ++nf){
      int ncol = wc*64 + nf*16 + (l>>4)*4;
      float4 bb = *(const float4*)&bias[ncol];
      ushort4 o;
      o.x = f2b(fmaxf(acc[mf][nf][0] + bb.x, 0.f));
      o.y = f2b(fmaxf(acc[mf][nf][1] + bb.y, 0.f));
      o.z = f2b(fmaxf(acc[mf][nf][2] + bb.z, 0.f));
      o.w = f2b(fmaxf(acc[mf][nf][3] + bb.w, 0.f));
      *(ushort4*)(out + (size_t)m*HID + ncol) = o;
    }
  }
}

// gate GEMV over bf16 h
__global__ void k_gate(const ushort* __restrict__ h, const float* __restrict__ Wg,
                       const float* __restrict__ bg, float* __restrict__ gate){
  int w = blockIdx.x*4 + (threadIdx.x>>6);
  int lane = threadIdx.x & 63;
  if (w >= NN) return;
  uint2 u = *(const uint2*)(h + (size_t)w*HID + lane*4);
  float4 wg = *(const float4*)(Wg + lane*4);
  float d = __uint_as_float(u.x<<16)*wg.x + __uint_as_float(u.x&0xFFFF0000u)*wg.y
          + __uint_as_float(u.y<<16)*wg.z + __uint_as_float(u.y&0xFFFF0000u)*wg.w;
  #pragma unroll
  for (int o=32;o>0;o>>=1) d += __shfl_down(d, o);
  if (lane==0) gate[w] = d + bg[0];
}

__global__ void k_seg(const int* __restrict__ batch, int* __restrict__ starts){
  int b = threadIdx.x;
  if (b > NBG) return;
  int lo = 0, hi = NN;
  while (lo < hi){ int mid = (lo+hi)>>1; if (batch[mid] < b) lo = mid+1; else hi = mid; }
  starts[b] = lo;
}

__global__ void k_msum(const float* __restrict__ gate, const int* __restrict__ starts,
                       float* __restrict__ m, float* __restrict__ s){
  __shared__ float sm[256];
  int b = blockIdx.x, t = threadIdx.x;
  int st = starts[b], en = starts[b+1];
  float mx = -3.0e38f;
  for (int i = st + t; i < en; i += 256) mx = fmaxf(mx, gate[i]);
  sm[t] = mx; __syncthreads();
  for (int o=128;o>0;o>>=1){ if (t<o) sm[t]=fmaxf(sm[t],sm[t+o]); __syncthreads(); }
  float M = sm[0]; __syncthreads();
  float su = 0.f;
  for (int i = st + t; i < en; i += 256) su += expf(gate[i]-M);
  sm[t] = su; __syncthreads();
  for (int o=128;o>0;o>>=1){ if (t<o) sm[t]+=sm[t+o]; __syncthreads(); }
  if (t==0){ m[b]=M; s[b]=sm[0]; }
}

__global__ void k_pool(const ushort* __restrict__ h, const float* __restrict__ gate,
                       const int* __restrict__ batch, const float* __restrict__ m,
                       const float* __restrict__ s, float* __restrict__ pooled){
  __shared__ float sa[256];
  __shared__ int sb[256];
  int t = threadIdx.x;
  int i0 = blockIdx.x*256;
  int iend = min(i0+256, NN);
  {
    int i = i0 + t;
    if (i < NN){
      int b = batch[i];
      sb[t] = b;
      sa[t] = expf(gate[i] - m[b]) / s[b];
    }
  }
  __syncthreads();
  float acc = 0.f;
  int bcur = sb[0];
  for (int i=i0;i<iend;++i){
    int b = sb[i-i0];
    if (b != bcur){
      atomicAdd(&pooled[bcur*HID + t], acc);
      acc = 0.f; bcur = b;
    }
    acc = fmaf(sa[i-i0], b2f(h[(size_t)i*HID + t]), acc);
  }
  atomicAdd(&pooled[bcur*HID + t], acc);
}

__global__ void k_head(const float* __restrict__ pooled, const float* __restrict__ Wl1,
                       const float* __restrict__ bl1, const float* __restrict__ Wl2,
                       const float* __restrict__ bl2, float* __restrict__ out){
  __shared__ float pr[256]; __shared__ float o1[256]; __shared__ float lg[16];
  int b = blockIdx.x, t = threadIdx.x;
  pr[t] = pooled[b*HID + t];
  __syncthreads();
  float a = bl1[t];
  const float* wr = Wl1 + (size_t)t*HID;
  #pragma unroll 4
  for (int k=0;k<HID;k+=4){
    float4 w4 = *(const float4*)(wr + k);
    a += pr[k]*w4.x + pr[k+1]*w4.y + pr[k+2]*w4.z + pr[k+3]*w4.w;
  }
  o1[t] = fmaxf(a, 0.f);
  __syncthreads();
  if (t < NC){
    float a2 = bl2[t];
    const float* w2 = Wl2 + (size_t)t*HID;
    for (int k=0;k<HID;++k) a2 += o1[k]*w2[k];
    lg[t] = a2;
  }
  __syncthreads();
  if (t == 0){
    float mx = lg[0];
    for (int c2=1;c2<NC;++c2) mx = fmaxf(mx, lg[c2]);
    float se = 0.f;
    for (int c2=0;c2<NC;++c2) se += expf(lg[c2]-mx);
    float lse = mx + logf(se);
    for (int c2=0;c2<NC;++c2) out[b*NC + c2] = lg[c2] - lse;
  }
}

extern "C" void kernel_launch(void* const* d_in, const int* in_sizes, int n_in,
                              void* d_out, int out_size, void* d_ws, size_t ws_size,
                              hipStream_t stream){
  const float* x   = (const float*)d_in[0];
  const int*   ei  = (const int*)d_in[1];
  const int*   bat = (const int*)d_in[2];
  const float* W1l = (const float*)d_in[3];
  const float* b1l = (const float*)d_in[4];
  const float* W1r = (const float*)d_in[5];
  const float* W2l = (const float*)d_in[6];
  const float* b2l = (const float*)d_in[7];
  const float* W2r = (const float*)d_in[8];
  const float* W3l = (const float*)d_in[9];
  const float* b3l = (const float*)d_in[10];
  const float* W3r = (const float*)d_in[11];
  const float* Wg  = (const float*)d_in[12];
  const float* bg  = (const float*)d_in[13];
  const float* Wl1 = (const float*)d_in[14];
  const float* bl1 = (const float*)d_in[15];
  const float* Wl2 = (const float*)d_in[16];
  const float* bl2 = (const float*)d_in[17];
  const int* srcI = ei;
  const int* dstI = ei + NE;
  float* out = (float*)d_out;

  char* w = (char*)d_ws;
  auto take = [&](size_t bytes)->char*{
    char* p = w; w += (bytes + 255) & ~(size_t)255; return p;
  };
  int*      deg    = (int*)take((size_t)NN*4);
  float*    invd   = (float*)take((size_t)NN*4);
  int*      rowp   = (int*)take((size_t)NN*4);
  int*      cur    = (int*)take((size_t)NN*4);
  int*      srcs   = (int*)take((size_t)NE*4);
  int*      part   = (int*)take(128*4);
  int*      poffs  = (int*)take(128*4);
  float*    gate   = (float*)take((size_t)NN*4);
  int*      starts = (int*)take(128*4);
  float*    m      = (float*)take(64*4);
  float*    s      = (float*)take(64*4);
  float*    pooled = (float*)take(64*256*4);
  ushort*   xb     = (ushort*)take((size_t)NN*FIN*2);
  ushort*   Wc1    = (ushort*)take((size_t)HID*2*FIN*2);
  ushort*   Wc2    = (ushort*)take((size_t)HID*2*HID*2);
  ushort*   Wc3    = (ushort*)take((size_t)HID*2*HID*2);
  ushort*   AG     = (ushort*)take((size_t)NN*HID*2);
  ushort*   HB     = (ushort*)take((size_t)NN*HID*2);

  int nb = (NN + 511)/512;

  k_init<<<(NN+255)/256, 256, 0, stream>>>(deg, pooled);
  k_xb<<<(NN*FIN/4+255)/256, 256, 0, stream>>>(x, xb);
  k_wcat<<<(HID*2*FIN+255)/256, 256, 0, stream>>>(W1l, W1r, FIN, Wc1);
  k_wcat<<<(HID*2*HID+255)/256, 256, 0, stream>>>(W2l, W2r, HID, Wc2);
  k_wcat<<<(HID*2*HID+255)/256, 256, 0, stream>>>(W3l, W3r, HID, Wc3);
  k_hist<<<1024, 256, 0, stream>>>(dstI, deg);
  k_partial<<<nb, 256, 0, stream>>>(deg, part);
  k_scanp<<<1, 64, 0, stream>>>(part, poffs, nb);
  k_chunkscan<<<nb, 512, 0, stream>>>(deg, poffs, rowp, cur, invd);
  k_scatter<<<1024, 256, 0, stream>>>(srcI, dstI, cur, srcs);

  int gblocks = (NN + 127)/128;
  // layer 1: agg(xb) -> AG (ld 128); h1 = gemm(AG, xb) -> HB
  k_agg<128><<<(NN+3)/4, 256, 0, stream>>>(xb, srcs, rowp, deg, invd, AG);
  k_gemm<<<gblocks, 512, 0, stream>>>(AG, FIN, xb, FIN, Wc1, 2*FIN, b1l, HB, NN);
  // layer 2: agg(HB) -> AG; h2 = gemm(AG, HB) -> AG (in-place over A1, block owns rows)
  k_agg<256><<<(NN+3)/4, 256, 0, stream>>>(HB, srcs, rowp, deg, invd, AG);
  k_gemm<<<gblocks, 512, 0, stream>>>(AG, HID, HB, HID, Wc2, 2*HID, b2l, AG, NN);
  // layer 3: agg(AG) -> HB; h3 = gemm(HB, AG) -> HB
  k_agg<256><<<(NN+3)/4, 256, 0, stream>>>(AG, srcs, rowp, deg, invd, HB);
  k_gemm<<<gblocks, 512, 0, stream>>>(HB, HID, AG, HID, Wc3, 2*HID, b3l, HB, NN);

  // attention pooling over h3 = HB
  k_gate<<<(NN+3)/4, 256, 0, stream>>>(HB, Wg, bg, gate);
  k_seg<<<1, 128, 0, stream>>>(bat, starts);
  k_msum<<<NBG, 256, 0, stream>>>(gate, starts, m, s);
  k_pool<<<(NN+255)/256, 256, 0, stream>>>(HB, gate, bat, m, s, pooled);
  k_head<<<NBG, 256, 0, stream>>>(pooled, Wl1, bl1, Wl2, bl2, out);
}

// Round 4
// 767.372 us; speedup vs baseline: 2.8198x; 1.2907x over previous
//
#include <hip/hip_runtime.h>

#define NN 50000
#define FIN 128
#define HID 256
#define NE 1600000
#define NBG 64
#define NC 10

typedef short bf16x8 __attribute__((ext_vector_type(8)));
typedef float f32x4 __attribute__((ext_vector_type(4)));

static __device__ __forceinline__ ushort f2b(float f){
  unsigned u = __float_as_uint(f);
  unsigned r = (u + 0x7FFFu + ((u >> 16) & 1u)) >> 16;
  return (ushort)r;
}
static __device__ __forceinline__ float b2f(ushort u){
  return __uint_as_float(((unsigned)u) << 16);
}

__global__ void k_init(int* __restrict__ deg, float* __restrict__ pooled){
  int i = blockIdx.x*256 + threadIdx.x;
  if (i < NN) deg[i] = 0;
  if (i < NBG*HID) pooled[i] = 0.f;
}

// x fp32 [NN][128] -> bf16
__global__ void k_xb(const float* __restrict__ x, ushort* __restrict__ xb){
  int i = blockIdx.x*256 + threadIdx.x;           // element quad index
  if (i >= NN*FIN/4) return;
  float4 v = *(const float4*)(x + (size_t)i*4);
  ushort4 o; o.x=f2b(v.x); o.y=f2b(v.y); o.z=f2b(v.z); o.w=f2b(v.w);
  *(ushort4*)(xb + (size_t)i*4) = o;
}

// Wcat bf16 [256][2F] = [Wl | Wr]
__global__ void k_wcat(const float* __restrict__ Wl, const float* __restrict__ Wr,
                       int F, ushort* __restrict__ Wc){
  int F2 = 2*F;
  int i = blockIdx.x*256 + threadIdx.x;
  if (i >= HID*F2) return;
  int n = i / F2, k = i % F2;
  float v = (k < F) ? Wl[(size_t)n*F + k] : Wr[(size_t)n*F + (k-F)];
  Wc[i] = f2b(v);
}

__global__ void k_hist(const int* __restrict__ dst, int* __restrict__ deg){
  for (int e = blockIdx.x*blockDim.x + threadIdx.x; e < NE; e += gridDim.x*blockDim.x)
    atomicAdd(&deg[dst[e]], 1);
}

__global__ void k_partial(const int* __restrict__ deg, int* __restrict__ part){
  __shared__ int sm[256];
  int t = threadIdx.x; int i0 = blockIdx.x*512;
  int v = 0;
  if (i0 + t < NN) v += deg[i0+t];
  if (i0 + t + 256 < NN) v += deg[i0+t+256];
  sm[t] = v; __syncthreads();
  for (int o=128;o>0;o>>=1){ if (t<o) sm[t]+=sm[t+o]; __syncthreads(); }
  if (t==0) part[blockIdx.x] = sm[0];
}

__global__ void k_scanp(const int* __restrict__ part, int* __restrict__ poffs, int nb){
  if (threadIdx.x==0 && blockIdx.x==0){
    int run=0;
    for (int i=0;i<nb;++i){ poffs[i]=run; run+=part[i]; }
  }
}

__global__ void k_chunkscan(const int* __restrict__ deg, const int* __restrict__ poffs,
                            int* __restrict__ rowp, int* __restrict__ cur, float* __restrict__ invd){
  __shared__ int buf[2][512];
  int t = threadIdx.x; int i = blockIdx.x*512 + t;
  int v = (i<NN)? deg[i] : 0;
  buf[0][t] = v; __syncthreads();
  int pp = 0;
  for (int off=1; off<512; off<<=1){
    int nv = buf[pp][t];
    if (t >= off) nv += buf[pp][t-off];
    buf[pp^1][t] = nv; __syncthreads(); pp ^= 1;
  }
  if (i < NN){
    int excl = poffs[blockIdx.x] + buf[pp][t] - v;
    rowp[i] = excl; cur[i] = excl;
    invd[i] = 1.0f / (float)max(v, 1);
  }
}

__global__ void k_scatter(const int* __restrict__ src, const int* __restrict__ dst,
                          int* __restrict__ cur, int* __restrict__ srcs){
  for (int e = blockIdx.x*blockDim.x + threadIdx.x; e < NE; e += gridDim.x*blockDim.x){
    int d = dst[e];
    int pos = atomicAdd(&cur[d], 1);
    srcs[pos] = src[e];
  }
}

// one wave per destination node; 16B (8 bf16) per lane => F/8 lanes per row,
// wave processes EPI=64/(F/8) edges concurrently; unroll x2 => 2*EPI rows in flight.
template<int F>
__global__ void k_agg(const ushort* __restrict__ x, const int* __restrict__ srcs,
                      const int* __restrict__ rowp, const int* __restrict__ deg,
                      const float* __restrict__ invd, ushort* __restrict__ out){
  constexpr int LPR = F/8;        // lanes per row: 16 (F=128) or 32 (F=256)
  constexpr int EPI = 64/LPR;     // edge slots per wave-iter: 4 or 2
  int w = blockIdx.x*4 + (threadIdx.x>>6);
  int lane = threadIdx.x & 63;
  if (w >= NN) return;
  int st = rowp[w], d = deg[w];
  int grp = lane / LPR;
  int fo  = (lane % LPR)*8;       // feature offset (elements)
  float acc[8];
  #pragma unroll
  for (int v=0;v<8;++v) acc[v]=0.f;

  auto accum = [&](uint4 u){
    acc[0] += __uint_as_float(u.x<<16); acc[1] += __uint_as_float(u.x & 0xFFFF0000u);
    acc[2] += __uint_as_float(u.y<<16); acc[3] += __uint_as_float(u.y & 0xFFFF0000u);
    acc[4] += __uint_as_float(u.z<<16); acc[5] += __uint_as_float(u.z & 0xFFFF0000u);
    acc[6] += __uint_as_float(u.w<<16); acc[7] += __uint_as_float(u.w & 0xFFFF0000u);
  };

  int j = 0;
  for (; j + 2*EPI <= d; j += 2*EPI){
    int i0 = srcs[st + j + grp];
    int i1 = srcs[st + j + EPI + grp];
    uint4 u0 = *(const uint4*)(x + (size_t)i0*F + fo);
    uint4 u1 = *(const uint4*)(x + (size_t)i1*F + fo);
    accum(u0); accum(u1);
  }
  for (; j < d; j += EPI){
    int jj = j + grp;
    if (jj < d){
      int i0 = srcs[st + jj];
      uint4 u0 = *(const uint4*)(x + (size_t)i0*F + fo);
      accum(u0);
    }
  }
  // cross-group reduction: sum the EPI edge slots
  #pragma unroll
  for (int off = LPR; off < 64; off <<= 1){
    #pragma unroll
    for (int v=0;v<8;++v) acc[v] += __shfl_xor(acc[v], off);
  }
  if (grp == 0){
    float sc = invd[w];
    uint4 o;
    o.x = (unsigned)f2b(acc[0]*sc) | ((unsigned)f2b(acc[1]*sc)<<16);
    o.y = (unsigned)f2b(acc[2]*sc) | ((unsigned)f2b(acc[3]*sc)<<16);
    o.z = (unsigned)f2b(acc[4]*sc) | ((unsigned)f2b(acc[5]*sc)<<16);
    o.w = (unsigned)f2b(acc[6]*sc) | ((unsigned)f2b(acc[7]*sc)<<16);
    *(uint4*)(out + (size_t)w*F + fo) = o;
  }
}

// MFMA GEMM: out[m][n] = relu( sum_k [A1|A2][m][k] * Wc[n][k] + bias[n] ), bf16 in, bf16 out
// BM=128, BN=256 (full width), BK=64, 512 threads = 8 waves (2 Mx4 N), wave tile 64x64.
#define LDT 72
__global__ __launch_bounds__(512) void k_gemm(
    const ushort* __restrict__ A1, int ldA1,
    const ushort* __restrict__ A2, int ldA2,
    const ushort* __restrict__ Wc, int F2,
    const float* __restrict__ bias, ushort* __restrict__ out, int M)
{
  __shared__ ushort As[128*LDT];
  __shared__ ushort Bs[256*LDT];
  int t = threadIdx.x;
  int l = t & 63;
  int wv = t >> 6;
  int wr = wv >> 2, wc = wv & 3;
  int m0 = blockIdx.x * 128;
  int F = F2 >> 1;
  f32x4 acc[4][4];
  #pragma unroll
  for (int a=0;a<4;++a)
  #pragma unroll
  for (int b=0;b<4;++b) acc[a][b] = (f32x4){0.f,0.f,0.f,0.f};

  int nsteps = F2/64;
  for (int s=0; s<nsteps; ++s){
    int kk = s*64;
    const ushort* src; int ld, kkl;
    if (kk < F){ src = A1; ld = ldA1; kkl = kk; }
    else       { src = A2; ld = ldA2; kkl = kk - F; }
    uint4 av[2];
    int arow[2], ack[2];
    #pragma unroll
    for (int i=0;i<2;++i){
      int c = t*2 + i;
      arow[i] = c >> 3; ack[i] = c & 7;
      int m = m0 + arow[i];
      av[i] = make_uint4(0u,0u,0u,0u);
      if (m < M) av[i] = *(const uint4*)(src + (size_t)m*ld + kkl + ack[i]*8);
    }
    uint4 bv[4];
    int brow[4], bck[4];
    #pragma unroll
    for (int i=0;i<4;++i){
      int c = t*4 + i;
      brow[i] = c >> 3; bck[i] = c & 7;
      bv[i] = *(const uint4*)(Wc + (size_t)brow[i]*F2 + kk + bck[i]*8);
    }
    #pragma unroll
    for (int i=0;i<2;++i)
      *(uint4*)&As[arow[i]*LDT + ack[i]*8] = av[i];
    #pragma unroll
    for (int i=0;i<4;++i)
      *(uint4*)&Bs[brow[i]*LDT + bck[i]*8] = bv[i];
    __syncthreads();

    #pragma unroll
    for (int ks=0; ks<2; ++ks){
      bf16x8 af[4], bf[4];
      int ko = ks*32 + (l>>4)*8;
      #pragma unroll
      for (int mf=0; mf<4; ++mf)
        af[mf] = *(bf16x8*)&As[(wr*64 + mf*16 + (l&15))*LDT + ko];
      #pragma unroll
      for (int nf=0; nf<4; ++nf)
        bf[nf] = *(bf16x8*)&Bs[(wc*64 + nf*16 + (l&15))*LDT + ko];
      #pragma unroll
      for (int mf=0; mf<4; ++mf)
      #pragma unroll
      for (int nf=0; nf<4; ++nf)
        acc[mf][nf] = __builtin_amdgcn_mfma_f32_16x16x32_bf16(bf[nf], af[mf], acc[mf][nf], 0, 0, 0);
    }
    __syncthreads();
  }

  #pragma unroll
  for (int mf=0; mf<4; ++mf){
    int m = m0 + wr*64 + mf*16 + (l&15);
    if (m >= M) continue;
    #pragma unroll
    for (int nf=0; nf<4; ++nf){
      int ncol = wc*64 + nf*16 + (l>>4)*4;
      float4 bb = *(const float4*)&bias[ncol];
      ushort4 o;
      o.x = f2b(fmaxf(acc[mf][nf][0] + bb.x, 0.f));
      o.y = f2b(fmaxf(acc[mf][nf][1] + bb.y, 0.f));
      o.z = f2b(fmaxf(acc[mf][nf][2] + bb.z, 0.f));
      o.w = f2b(fmaxf(acc[mf][nf][3] + bb.w, 0.f));
      *(ushort4*)(out + (size_t)m*HID + ncol) = o;
    }
  }
}

// gate GEMV over bf16 h
__global__ void k_gate(const ushort* __restrict__ h, const float* __restrict__ Wg,
                       const float* __restrict__ bg, float* __restrict__ gate){
  int w = blockIdx.x*4 + (threadIdx.x>>6);
  int lane = threadIdx.x & 63;
  if (w >= NN) return;
  uint2 u = *(const uint2*)(h + (size_t)w*HID + lane*4);
  float4 wg = *(const float4*)(Wg + lane*4);
  float d = __uint_as_float(u.x<<16)*wg.x + __uint_as_float(u.x&0xFFFF0000u)*wg.y
          + __uint_as_float(u.y<<16)*wg.z + __uint_as_float(u.y&0xFFFF0000u)*wg.w;
  #pragma unroll
  for (int o=32;o>0;o>>=1) d += __shfl_down(d, o);
  if (lane==0) gate[w] = d + bg[0];
}

__global__ void k_seg(const int* __restrict__ batch, int* __restrict__ starts){
  int b = threadIdx.x;
  if (b > NBG) return;
  int lo = 0, hi = NN;
  while (lo < hi){ int mid = (lo+hi)>>1; if (batch[mid] < b) lo = mid+1; else hi = mid; }
  starts[b] = lo;
}

__global__ void k_msum(const float* __restrict__ gate, const int* __restrict__ starts,
                       float* __restrict__ m, float* __restrict__ s){
  __shared__ float sm[256];
  int b = blockIdx.x, t = threadIdx.x;
  int st = starts[b], en = starts[b+1];
  float mx = -3.0e38f;
  for (int i = st + t; i < en; i += 256) mx = fmaxf(mx, gate[i]);
  sm[t] = mx; __syncthreads();
  for (int o=128;o>0;o>>=1){ if (t<o) sm[t]=fmaxf(sm[t],sm[t+o]); __syncthreads(); }
  float M = sm[0]; __syncthreads();
  float su = 0.f;
  for (int i = st + t; i < en; i += 256) su += expf(gate[i]-M);
  sm[t] = su; __syncthreads();
  for (int o=128;o>0;o>>=1){ if (t<o) sm[t]+=sm[t+o]; __syncthreads(); }
  if (t==0){ m[b]=M; s[b]=sm[0]; }
}

__global__ void k_pool(const ushort* __restrict__ h, const float* __restrict__ gate,
                       const int* __restrict__ batch, const float* __restrict__ m,
                       const float* __restrict__ s, float* __restrict__ pooled){
  __shared__ float sa[256];
  __shared__ int sb[256];
  int t = threadIdx.x;
  int i0 = blockIdx.x*256;
  int iend = min(i0+256, NN);
  {
    int i = i0 + t;
    if (i < NN){
      int b = batch[i];
      sb[t] = b;
      sa[t] = expf(gate[i] - m[b]) / s[b];
    }
  }
  __syncthreads();
  float acc = 0.f;
  int bcur = sb[0];
  for (int i=i0;i<iend;++i){
    int b = sb[i-i0];
    if (b != bcur){
      atomicAdd(&pooled[bcur*HID + t], acc);
      acc = 0.f; bcur = b;
    }
    acc = fmaf(sa[i-i0], b2f(h[(size_t)i*HID + t]), acc);
  }
  atomicAdd(&pooled[bcur*HID + t], acc);
}

__global__ void k_head(const float* __restrict__ pooled, const float* __restrict__ Wl1,
                       const float* __restrict__ bl1, const float* __restrict__ Wl2,
                       const float* __restrict__ bl2, float* __restrict__ out){
  __shared__ float pr[256]; __shared__ float o1[256]; __shared__ float lg[16];
  int b = blockIdx.x, t = threadIdx.x;
  pr[t] = pooled[b*HID + t];
  __syncthreads();
  float a = bl1[t];
  const float* wr = Wl1 + (size_t)t*HID;
  #pragma unroll 4
  for (int k=0;k<HID;k+=4){
    float4 w4 = *(const float4*)(wr + k);
    a += pr[k]*w4.x + pr[k+1]*w4.y + pr[k+2]*w4.z + pr[k+3]*w4.w;
  }
  o1[t] = fmaxf(a, 0.f);
  __syncthreads();
  if (t < NC){
    float a2 = bl2[t];
    const float* w2 = Wl2 + (size_t)t*HID;
    for (int k=0;k<HID;++k) a2 += o1[k]*w2[k];
    lg[t] = a2;
  }
  __syncthreads();
  if (t == 0){
    float mx = lg[0];
    for (int c2=1;c2<NC;++c2) mx = fmaxf(mx, lg[c2]);
    float se = 0.f;
    for (int c2=0;c2<NC;++c2) se += expf(lg[c2]-mx);
    float lse = mx + logf(se);
    for (int c2=0;c2<NC;++c2) out[b*NC + c2] = lg[c2] - lse;
  }
}

extern "C" void kernel_launch(void* const* d_in, const int* in_sizes, int n_in,
                              void* d_out, int out_size, void* d_ws, size_t ws_size,
                              hipStream_t stream){
  const float* x   = (const float*)d_in[0];
  const int*   ei  = (const int*)d_in[1];
  const int*   bat = (const int*)d_in[2];
  const float* W1l = (const float*)d_in[3];
  const float* b1l = (const float*)d_in[4];
  const float* W1r = (const float*)d_in[5];
  const float* W2l = (const float*)d_in[6];
  const float* b2l = (const float*)d_in[7];
  const float* W2r = (const float*)d_in[8];
  const float* W3l = (const float*)d_in[9];
  const float* b3l = (const float*)d_in[10];
  const float* W3r = (const float*)d_in[11];
  const float* Wg  = (const float*)d_in[12];
  const float* bg  = (const float*)d_in[13];
  const float* Wl1 = (const float*)d_in[14];
  const float* bl1 = (const float*)d_in[15];
  const float* Wl2 = (const float*)d_in[16];
  const float* bl2 = (const float*)d_in[17];
  const int* srcI = ei;
  const int* dstI = ei + NE;
  float* out = (float*)d_out;

  char* w = (char*)d_ws;
  auto take = [&](size_t bytes)->char*{
    char* p = w; w += (bytes + 255) & ~(size_t)255; return p;
  };
  int*      deg    = (int*)take((size_t)NN*4);
  float*    invd   = (float*)take((size_t)NN*4);
  int*      rowp   = (int*)take((size_t)NN*4);
  int*      cur    = (int*)take((size_t)NN*4);
  int*      srcs   = (int*)take((size_t)NE*4);
  int*      part   = (int*)take(128*4);
  int*      poffs  = (int*)take(128*4);
  float*    gate   = (float*)take((size_t)NN*4);
  int*      starts = (int*)take(128*4);
  float*    m      = (float*)take(64*4);
  float*    s      = (float*)take(64*4);
  float*    pooled = (float*)take(64*256*4);
  ushort*   xb     = (ushort*)take((size_t)NN*FIN*2);
  ushort*   Wc1    = (ushort*)take((size_t)HID*2*FIN*2);
  ushort*   Wc2    = (ushort*)take((size_t)HID*2*HID*2);
  ushort*   Wc3    = (ushort*)take((size_t)HID*2*HID*2);
  ushort*   AG     = (ushort*)take((size_t)NN*HID*2);
  ushort*   HB     = (ushort*)take((size_t)NN*HID*2);

  int nb = (NN + 511)/512;

  k_init<<<(NN+255)/256, 256, 0, stream>>>(deg, pooled);
  k_xb<<<(NN*FIN/4+255)/256, 256, 0, stream>>>(x, xb);
  k_wcat<<<(HID*2*FIN+255)/256, 256, 0, stream>>>(W1l, W1r, FIN, Wc1);
  k_wcat<<<(HID*2*HID+255)/256, 256, 0, stream>>>(W2l, W2r, HID, Wc2);
  k_wcat<<<(HID*2*HID+255)/256, 256, 0, stream>>>(W3l, W3r, HID, Wc3);
  k_hist<<<1024, 256, 0, stream>>>(dstI, deg);
  k_partial<<<nb, 256, 0, stream>>>(deg, part);
  k_scanp<<<1, 64, 0, stream>>>(part, poffs, nb);
  k_chunkscan<<<nb, 512, 0, stream>>>(deg, poffs, rowp, cur, invd);
  k_scatter<<<1024, 256, 0, stream>>>(srcI, dstI, cur, srcs);

  int gblocks = (NN + 127)/128;
  // layer 1: agg(xb) -> AG (ld 128); h1 = gemm(AG, xb) -> HB
  k_agg<128><<<(NN+3)/4, 256, 0, stream>>>(xb, srcs, rowp, deg, invd, AG);
  k_gemm<<<gblocks, 512, 0, stream>>>(AG, FIN, xb, FIN, Wc1, 2*FIN, b1l, HB, NN);
  // layer 2: agg(HB) -> AG; h2 = gemm(AG, HB) -> AG (in-place over A1, block owns rows)
  k_agg<256><<<(NN+3)/4, 256, 0, stream>>>(HB, srcs, rowp, deg, invd, AG);
  k_gemm<<<gblocks, 512, 0, stream>>>(AG, HID, HB, HID, Wc2, 2*HID, b2l, AG, NN);
  // layer 3: agg(AG) -> HB; h3 = gemm(HB, AG) -> HB
  k_agg<256><<<(NN+3)/4, 256, 0, stream>>>(AG, srcs, rowp, deg, invd, HB);
  k_gemm<<<gblocks, 512, 0, stream>>>(HB, HID, AG, HID, Wc3, 2*HID, b3l, HB, NN);

  // attention pooling over h3 = HB
  k_gate<<<(NN+3)/4, 256, 0, stream>>>(HB, Wg, bg, gate);
  k_seg<<<1, 128, 0, stream>>>(bat, starts);
  k_msum<<<NBG, 256, 0, stream>>>(gate, starts, m, s);
  k_pool<<<(NN+255)/256, 256, 0, stream>>>(HB, gate, bat, m, s, pooled);
  k_head<<<NBG, 256, 0, stream>>>(pooled, Wl1, bl1, Wl2, bl2, out);
}

// Round 5
// 671.268 us; speedup vs baseline: 3.2235x; 1.1432x over previous
//
#include <hip/hip_runtime.h>

#define NN 50000
#define FIN 128
#define HID 256
#define NE 1600000
#define NBG 64
#define NC 10
#define NBINS ((NN + 255) >> 8)   // 196

typedef short bf16x8 __attribute__((ext_vector_type(8)));
typedef float f32x4 __attribute__((ext_vector_type(4)));

static __device__ __forceinline__ ushort f2b(float f){
  unsigned u = __float_as_uint(f);
  unsigned r = (u + 0x7FFFu + ((u >> 16) & 1u)) >> 16;
  return (ushort)r;
}
static __device__ __forceinline__ float b2f(ushort u){
  return __uint_as_float(((unsigned)u) << 16);
}

__global__ void k_init(int* __restrict__ deg, float* __restrict__ pooled){
  int i = blockIdx.x*256 + threadIdx.x;
  if (i < NN) deg[i] = 0;
  if (i < NBG*HID) pooled[i] = 0.f;
}

// x fp32 [NN][128] -> bf16
__global__ void k_xb(const float* __restrict__ x, ushort* __restrict__ xb){
  int i = blockIdx.x*256 + threadIdx.x;           // element quad index
  if (i >= NN*FIN/4) return;
  float4 v = *(const float4*)(x + (size_t)i*4);
  ushort4 o; o.x=f2b(v.x); o.y=f2b(v.y); o.z=f2b(v.z); o.w=f2b(v.w);
  *(ushort4*)(xb + (size_t)i*4) = o;
}

// Wcat bf16 [256][2F] = [Wl | Wr]
__global__ void k_wcat(const float* __restrict__ Wl, const float* __restrict__ Wr,
                       int F, ushort* __restrict__ Wc){
  int F2 = 2*F;
  int i = blockIdx.x*256 + threadIdx.x;
  if (i >= HID*F2) return;
  int n = i / F2, k = i % F2;
  float v = (k < F) ? Wl[(size_t)n*F + k] : Wr[(size_t)n*F + (k-F)];
  Wc[i] = f2b(v);
}

__global__ void k_hist(const int* __restrict__ dst, int* __restrict__ deg){
  for (int e = blockIdx.x*blockDim.x + threadIdx.x; e < NE; e += gridDim.x*blockDim.x)
    atomicAdd(&deg[dst[e]], 1);
}

__global__ void k_partial(const int* __restrict__ deg, int* __restrict__ part){
  __shared__ int sm[256];
  int t = threadIdx.x; int i0 = blockIdx.x*512;
  int v = 0;
  if (i0 + t < NN) v += deg[i0+t];
  if (i0 + t + 256 < NN) v += deg[i0+t+256];
  sm[t] = v; __syncthreads();
  for (int o=128;o>0;o>>=1){ if (t<o) sm[t]+=sm[t+o]; __syncthreads(); }
  if (t==0) part[blockIdx.x] = sm[0];
}

__global__ void k_scanp(const int* __restrict__ part, int* __restrict__ poffs, int nb){
  if (threadIdx.x==0 && blockIdx.x==0){
    int run=0;
    for (int i=0;i<nb;++i){ poffs[i]=run; run+=part[i]; }
  }
}

__global__ void k_chunkscan(const int* __restrict__ deg, const int* __restrict__ poffs,
                            int* __restrict__ rowp, float* __restrict__ invd){
  __shared__ int buf[2][512];
  int t = threadIdx.x; int i = blockIdx.x*512 + t;
  int v = (i<NN)? deg[i] : 0;
  buf[0][t] = v; __syncthreads();
  int pp = 0;
  for (int off=1; off<512; off<<=1){
    int nv = buf[pp][t];
    if (t >= off) nv += buf[pp][t-off];
    buf[pp^1][t] = nv; __syncthreads(); pp ^= 1;
  }
  if (i < NN){
    int excl = poffs[blockIdx.x] + buf[pp][t] - v;
    rowp[i] = excl;
    invd[i] = 1.0f / (float)max(v, 1);
  }
}

// bin cursors = CSR offset of each bin's first dst (CSR order is dst-ordered)
__global__ void k_bininit(const int* __restrict__ rowp, int* __restrict__ gcur){
  int b = threadIdx.x;
  if (b < NBINS) gcur[b] = rowp[b << 8];
}

// pass 1: partition edges into 196 dst-bins; packed word = (dst&255)<<24 | src
__global__ __launch_bounds__(256) void k_pass1(const int* __restrict__ src,
                                               const int* __restrict__ dst,
                                               int* __restrict__ gcur,
                                               unsigned* __restrict__ ebin){
  __shared__ int lhist[NBINS];
  __shared__ int lbase[NBINS];
  int t = threadIdx.x;
  long e0 = (long)blockIdx.x * 4096;
  for (int i=t; i<NBINS; i+=256) lhist[i]=0;
  __syncthreads();
  unsigned pk[16]; int bn[16]; int rk[16];
  #pragma unroll
  for (int k=0;k<16;++k){
    long e = e0 + k*256 + t;
    bn[k] = -1;
    if (e < NE){
      int d = dst[e];
      int s = src[e];
      bn[k] = d >> 8;
      pk[k] = (unsigned)s | ((unsigned)(d & 255) << 24);
      rk[k] = atomicAdd(&lhist[bn[k]], 1);
    }
  }
  __syncthreads();
  for (int i=t; i<NBINS; i+=256)
    lbase[i] = atomicAdd(&gcur[i], lhist[i]);
  __syncthreads();
  #pragma unroll
  for (int k=0;k<16;++k)
    if (bn[k] >= 0) ebin[lbase[bn[k]] + rk[k]] = pk[k];
}

// pass 2: within each bin, scatter to exact CSR position via LDS cursors
__global__ __launch_bounds__(256) void k_pass2(const unsigned* __restrict__ ebin,
                                               const int* __restrict__ rowp,
                                               int* __restrict__ srcs){
  __shared__ int cur[256];
  int b = blockIdx.x, t = threadIdx.x;
  int d0 = b << 8;
  if (d0 + t < NN) cur[t] = rowp[d0 + t];
  __syncthreads();
  int st = rowp[d0];
  int en = (d0 + 256 < NN) ? rowp[d0 + 256] : NE;
  for (int i = st + t; i < en; i += 256){
    unsigned p = ebin[i];
    int doff = p >> 24;
    int s = (int)(p & 0xFFFFFFu);
    int pos = atomicAdd(&cur[doff], 1);
    srcs[pos] = s;
  }
}

// one wave per destination node; 16B (8 bf16) per lane => F/8 lanes per row,
// wave processes EPI=64/(F/8) edges concurrently; unroll x2 => 2*EPI rows in flight.
template<int F>
__global__ void k_agg(const ushort* __restrict__ x, const int* __restrict__ srcs,
                      const int* __restrict__ rowp, const int* __restrict__ deg,
                      const float* __restrict__ invd, ushort* __restrict__ out){
  constexpr int LPR = F/8;        // lanes per row: 16 (F=128) or 32 (F=256)
  constexpr int EPI = 64/LPR;     // edge slots per wave-iter: 4 or 2
  int w = blockIdx.x*4 + (threadIdx.x>>6);
  int lane = threadIdx.x & 63;
  if (w >= NN) return;
  int st = rowp[w], d = deg[w];
  int grp = lane / LPR;
  int fo  = (lane % LPR)*8;       // feature offset (elements)
  float acc[8];
  #pragma unroll
  for (int v=0;v<8;++v) acc[v]=0.f;

  auto accum = [&](uint4 u){
    acc[0] += __uint_as_float(u.x<<16); acc[1] += __uint_as_float(u.x & 0xFFFF0000u);
    acc[2] += __uint_as_float(u.y<<16); acc[3] += __uint_as_float(u.y & 0xFFFF0000u);
    acc[4] += __uint_as_float(u.z<<16); acc[5] += __uint_as_float(u.z & 0xFFFF0000u);
    acc[6] += __uint_as_float(u.w<<16); acc[7] += __uint_as_float(u.w & 0xFFFF0000u);
  };

  int j = 0;
  for (; j + 2*EPI <= d; j += 2*EPI){
    int i0 = srcs[st + j + grp];
    int i1 = srcs[st + j + EPI + grp];
    uint4 u0 = *(const uint4*)(x + (size_t)i0*F + fo);
    uint4 u1 = *(const uint4*)(x + (size_t)i1*F + fo);
    accum(u0); accum(u1);
  }
  for (; j < d; j += EPI){
    int jj = j + grp;
    if (jj < d){
      int i0 = srcs[st + jj];
      uint4 u0 = *(const uint4*)(x + (size_t)i0*F + fo);
      accum(u0);
    }
  }
  #pragma unroll
  for (int off = LPR; off < 64; off <<= 1){
    #pragma unroll
    for (int v=0;v<8;++v) acc[v] += __shfl_xor(acc[v], off);
  }
  if (grp == 0){
    float sc = invd[w];
    uint4 o;
    o.x = (unsigned)f2b(acc[0]*sc) | ((unsigned)f2b(acc[1]*sc)<<16);
    o.y = (unsigned)f2b(acc[2]*sc) | ((unsigned)f2b(acc[3]*sc)<<16);
    o.z = (unsigned)f2b(acc[4]*sc) | ((unsigned)f2b(acc[5]*sc)<<16);
    o.w = (unsigned)f2b(acc[6]*sc) | ((unsigned)f2b(acc[7]*sc)<<16);
    *(uint4*)(out + (size_t)w*F + fo) = o;
  }
}

// MFMA GEMM: out[m][n] = relu( sum_k [A1|A2][m][k] * Wc[n][k] + bias[n] ), bf16 in, bf16 out
// BM=128, BN=256 (full width), BK=64, 512 threads = 8 waves (2 Mx4 N), wave tile 64x64.
#define LDT 72
__global__ __launch_bounds__(512) void k_gemm(
    const ushort* __restrict__ A1, int ldA1,
    const ushort* __restrict__ A2, int ldA2,
    const ushort* __restrict__ Wc, int F2,
    const float* __restrict__ bias, ushort* __restrict__ out, int M)
{
  __shared__ ushort As[128*LDT];
  __shared__ ushort Bs[256*LDT];
  int t = threadIdx.x;
  int l = t & 63;
  int wv = t >> 6;
  int wr = wv >> 2, wc = wv & 3;
  int m0 = blockIdx.x * 128;
  int F = F2 >> 1;
  f32x4 acc[4][4];
  #pragma unroll
  for (int a=0;a<4;++a)
  #pragma unroll
  for (int b=0;b<4;++b) acc[a][b] = (f32x4){0.f,0.f,0.f,0.f};

  int nsteps = F2/64;
  for (int s=0; s<nsteps; ++s){
    int kk = s*64;
    const ushort* src; int ld, kkl;
    if (kk < F){ src = A1; ld = ldA1; kkl = kk; }
    else       { src = A2; ld = ldA2; kkl = kk - F; }
    uint4 av[2];
    int arow[2], ack[2];
    #pragma unroll
    for (int i=0;i<2;++i){
      int c = t*2 + i;
      arow[i] = c >> 3; ack[i] = c & 7;
      int m = m0 + arow[i];
      av[i] = make_uint4(0u,0u,0u,0u);
      if (m < M) av[i] = *(const uint4*)(src + (size_t)m*ld + kkl + ack[i]*8);
    }
    uint4 bv[4];
    int brow[4], bck[4];
    #pragma unroll
    for (int i=0;i<4;++i){
      int c = t*4 + i;
      brow[i] = c >> 3; bck[i] = c & 7;
      bv[i] = *(const uint4*)(Wc + (size_t)brow[i]*F2 + kk + bck[i]*8);
    }
    #pragma unroll
    for (int i=0;i<2;++i)
      *(uint4*)&As[arow[i]*LDT + ack[i]*8] = av[i];
    #pragma unroll
    for (int i=0;i<4;++i)
      *(uint4*)&Bs[brow[i]*LDT + bck[i]*8] = bv[i];
    __syncthreads();

    #pragma unroll
    for (int ks=0; ks<2; ++ks){
      bf16x8 af[4], bf[4];
      int ko = ks*32 + (l>>4)*8;
      #pragma unroll
      for (int mf=0; mf<4; ++mf)
        af[mf] = *(bf16x8*)&As[(wr*64 + mf*16 + (l&15))*LDT + ko];
      #pragma unroll
      for (int nf=0; nf<4; ++nf)
        bf[nf] = *(bf16x8*)&Bs[(wc*64 + nf*16 + (l&15))*LDT + ko];
      #pragma unroll
      for (int mf=0; mf<4; ++mf)
      #pragma unroll
      for (int nf=0; nf<4; ++nf)
        acc[mf][nf] = __builtin_amdgcn_mfma_f32_16x16x32_bf16(bf[nf], af[mf], acc[mf][nf], 0, 0, 0);
    }
    __syncthreads();
  }

  #pragma unroll
  for (int mf=0; mf<4; ++mf){
    int m = m0 + wr*64 + mf*16 + (l&15);
    if (m >= M) continue;
    #pragma unroll
    for (int nf=0; nf<4; ++nf){
      int ncol = wc*64 + nf*16 + (l>>4)*4;
      float4 bb = *(const float4*)&bias[ncol];
      ushort4 o;
      o.x = f2b(fmaxf(acc[mf][nf][0] + bb.x, 0.f));
      o.y = f2b(fmaxf(acc[mf][nf][1] + bb.y, 0.f));
      o.z = f2b(fmaxf(acc[mf][nf][2] + bb.z, 0.f));
      o.w = f2b(fmaxf(acc[mf][nf][3] + bb.w, 0.f));
      *(ushort4*)(out + (size_t)m*HID + ncol) = o;
    }
  }
}

// gate GEMV over bf16 h
__global__ void k_gate(const ushort* __restrict__ h, const float* __restrict__ Wg,
                       const float* __restrict__ bg, float* __restrict__ gate){
  int w = blockIdx.x*4 + (threadIdx.x>>6);
  int lane = threadIdx.x & 63;
  if (w >= NN) return;
  uint2 u = *(const uint2*)(h + (size_t)w*HID + lane*4);
  float4 wg = *(const float4*)(Wg + lane*4);
  float d = __uint_as_float(u.x<<16)*wg.x + __uint_as_float(u.x&0xFFFF0000u)*wg.y
          + __uint_as_float(u.y<<16)*wg.z + __uint_as_float(u.y&0xFFFF0000u)*wg.w;
  #pragma unroll
  for (int o=32;o>0;o>>=1) d += __shfl_down(d, o);
  if (lane==0) gate[w] = d + bg[0];
}

__global__ void k_seg(const int* __restrict__ batch, int* __restrict__ starts){
  int b = threadIdx.x;
  if (b > NBG) return;
  int lo = 0, hi = NN;
  while (lo < hi){ int mid = (lo+hi)>>1; if (batch[mid] < b) lo = mid+1; else hi = mid; }
  starts[b] = lo;
}

__global__ void k_msum(const float* __restrict__ gate, const int* __restrict__ starts,
                       float* __restrict__ m, float* __restrict__ s){
  __shared__ float sm[256];
  int b = blockIdx.x, t = threadIdx.x;
  int st = starts[b], en = starts[b+1];
  float mx = -3.0e38f;
  for (int i = st + t; i < en; i += 256) mx = fmaxf(mx, gate[i]);
  sm[t] = mx; __syncthreads();
  for (int o=128;o>0;o>>=1){ if (t<o) sm[t]=fmaxf(sm[t],sm[t+o]); __syncthreads(); }
  float M = sm[0]; __syncthreads();
  float su = 0.f;
  for (int i = st + t; i < en; i += 256) su += expf(gate[i]-M);
  sm[t] = su; __syncthreads();
  for (int o=128;o>0;o>>=1){ if (t<o) sm[t]+=sm[t+o]; __syncthreads(); }
  if (t==0){ m[b]=M; s[b]=sm[0]; }
}

__global__ void k_pool(const ushort* __restrict__ h, const float* __restrict__ gate,
                       const int* __restrict__ batch, const float* __restrict__ m,
                       const float* __restrict__ s, float* __restrict__ pooled){
  __shared__ float sa[256];
  __shared__ int sb[256];
  int t = threadIdx.x;
  int i0 = blockIdx.x*256;
  int iend = min(i0+256, NN);
  {
    int i = i0 + t;
    if (i < NN){
      int b = batch[i];
      sb[t] = b;
      sa[t] = expf(gate[i] - m[b]) / s[b];
    }
  }
  __syncthreads();
  float acc = 0.f;
  int bcur = sb[0];
  for (int i=i0;i<iend;++i){
    int b = sb[i-i0];
    if (b != bcur){
      atomicAdd(&pooled[bcur*HID + t], acc);
      acc = 0.f; bcur = b;
    }
    acc = fmaf(sa[i-i0], b2f(h[(size_t)i*HID + t]), acc);
  }
  atomicAdd(&pooled[bcur*HID + t], acc);
}

__global__ void k_head(const float* __restrict__ pooled, const float* __restrict__ Wl1,
                       const float* __restrict__ bl1, const float* __restrict__ Wl2,
                       const float* __restrict__ bl2, float* __restrict__ out){
  __shared__ float pr[256]; __shared__ float o1[256]; __shared__ float lg[16];
  int b = blockIdx.x, t = threadIdx.x;
  pr[t] = pooled[b*HID + t];
  __syncthreads();
  float a = bl1[t];
  const float* wr = Wl1 + (size_t)t*HID;
  #pragma unroll 4
  for (int k=0;k<HID;k+=4){
    float4 w4 = *(const float4*)(wr + k);
    a += pr[k]*w4.x + pr[k+1]*w4.y + pr[k+2]*w4.z + pr[k+3]*w4.w;
  }
  o1[t] = fmaxf(a, 0.f);
  __syncthreads();
  if (t < NC){
    float a2 = bl2[t];
    const float* w2 = Wl2 + (size_t)t*HID;
    for (int k=0;k<HID;++k) a2 += o1[k]*w2[k];
    lg[t] = a2;
  }
  __syncthreads();
  if (t == 0){
    float mx = lg[0];
    for (int c2=1;c2<NC;++c2) mx = fmaxf(mx, lg[c2]);
    float se = 0.f;
    for (int c2=0;c2<NC;++c2) se += expf(lg[c2]-mx);
    float lse = mx + logf(se);
    for (int c2=0;c2<NC;++c2) out[b*NC + c2] = lg[c2] - lse;
  }
}

extern "C" void kernel_launch(void* const* d_in, const int* in_sizes, int n_in,
                              void* d_out, int out_size, void* d_ws, size_t ws_size,
                              hipStream_t stream){
  const float* x   = (const float*)d_in[0];
  const int*   ei  = (const int*)d_in[1];
  const int*   bat = (const int*)d_in[2];
  const float* W1l = (const float*)d_in[3];
  const float* b1l = (const float*)d_in[4];
  const float* W1r = (const float*)d_in[5];
  const float* W2l = (const float*)d_in[6];
  const float* b2l = (const float*)d_in[7];
  const float* W2r = (const float*)d_in[8];
  const float* W3l = (const float*)d_in[9];
  const float* b3l = (const float*)d_in[10];
  const float* W3r = (const float*)d_in[11];
  const float* Wg  = (const float*)d_in[12];
  const float* bg  = (const float*)d_in[13];
  const float* Wl1 = (const float*)d_in[14];
  const float* bl1 = (const float*)d_in[15];
  const float* Wl2 = (const float*)d_in[16];
  const float* bl2 = (const float*)d_in[17];
  const int* srcI = ei;
  const int* dstI = ei + NE;
  float* out = (float*)d_out;

  char* w = (char*)d_ws;
  auto take = [&](size_t bytes)->char*{
    char* p = w; w += (bytes + 255) & ~(size_t)255; return p;
  };
  int*      deg    = (int*)take((size_t)NN*4);
  float*    invd   = (float*)take((size_t)NN*4);
  int*      rowp   = (int*)take((size_t)NN*4);
  int*      gcur   = (int*)take(256*4);
  int*      srcs   = (int*)take((size_t)NE*4);
  unsigned* ebin   = (unsigned*)take((size_t)NE*4);
  int*      part   = (int*)take(128*4);
  int*      poffs  = (int*)take(128*4);
  float*    gate   = (float*)take((size_t)NN*4);
  int*      starts = (int*)take(128*4);
  float*    m      = (float*)take(64*4);
  float*    s      = (float*)take(64*4);
  float*    pooled = (float*)take(64*256*4);
  ushort*   xb     = (ushort*)take((size_t)NN*FIN*2);
  ushort*   Wc1    = (ushort*)take((size_t)HID*2*FIN*2);
  ushort*   Wc2    = (ushort*)take((size_t)HID*2*HID*2);
  ushort*   Wc3    = (ushort*)take((size_t)HID*2*HID*2);
  ushort*   AG     = (ushort*)take((size_t)NN*HID*2);
  ushort*   HB     = (ushort*)take((size_t)NN*HID*2);

  int nb = (NN + 511)/512;

  k_init<<<(NN+255)/256, 256, 0, stream>>>(deg, pooled);
  k_xb<<<(NN*FIN/4+255)/256, 256, 0, stream>>>(x, xb);
  k_wcat<<<(HID*2*FIN+255)/256, 256, 0, stream>>>(W1l, W1r, FIN, Wc1);
  k_wcat<<<(HID*2*HID+255)/256, 256, 0, stream>>>(W2l, W2r, HID, Wc2);
  k_wcat<<<(HID*2*HID+255)/256, 256, 0, stream>>>(W3l, W3r, HID, Wc3);
  k_hist<<<1024, 256, 0, stream>>>(dstI, deg);
  k_partial<<<nb, 256, 0, stream>>>(deg, part);
  k_scanp<<<1, 64, 0, stream>>>(part, poffs, nb);
  k_chunkscan<<<nb, 512, 0, stream>>>(deg, poffs, rowp, invd);
  k_bininit<<<1, 256, 0, stream>>>(rowp, gcur);
  k_pass1<<<(NE + 4095)/4096, 256, 0, stream>>>(srcI, dstI, gcur, ebin);
  k_pass2<<<NBINS, 256, 0, stream>>>(ebin, rowp, srcs);

  int gblocks = (NN + 127)/128;
  // layer 1: agg(xb) -> AG (ld 128); h1 = gemm(AG, xb) -> HB
  k_agg<128><<<(NN+3)/4, 256, 0, stream>>>(xb, srcs, rowp, deg, invd, AG);
  k_gemm<<<gblocks, 512, 0, stream>>>(AG, FIN, xb, FIN, Wc1, 2*FIN, b1l, HB, NN);
  // layer 2: agg(HB) -> AG; h2 = gemm(AG, HB) -> AG (in-place over A1, block owns rows)
  k_agg<256><<<(NN+3)/4, 256, 0, stream>>>(HB, srcs, rowp, deg, invd, AG);
  k_gemm<<<gblocks, 512, 0, stream>>>(AG, HID, HB, HID, Wc2, 2*HID, b2l, AG, NN);
  // layer 3: agg(AG) -> HB; h3 = gemm(HB, AG) -> HB
  k_agg<256><<<(NN+3)/4, 256, 0, stream>>>(AG, srcs, rowp, deg, invd, HB);
  k_gemm<<<gblocks, 512, 0, stream>>>(HB, HID, AG, HID, Wc3, 2*HID, b3l, HB, NN);

  // attention pooling over h3 = HB
  k_gate<<<(NN+3)/4, 256, 0, stream>>>(HB, Wg, bg, gate);
  k_seg<<<1, 128, 0, stream>>>(bat, starts);
  k_msum<<<NBG, 256, 0, stream>>>(gate, starts, m, s);
  k_pool<<<(NN+255)/256, 256, 0, stream>>>(HB, gate, bat, m, s, pooled);
  k_head<<<NBG, 256, 0, stream>>>(pooled, Wl1, bl1, Wl2, bl2, out);
}

// Round 6
// 608.527 us; speedup vs baseline: 3.5559x; 1.1031x over previous
//
#include <hip/hip_runtime.h>

#define NN 50000
#define FIN 128
#define HID 256
#define NE 1600000
#define NBG 64
#define NC 10
#define NBINS ((NN + 255) >> 8)   // 196

typedef short bf16x8 __attribute__((ext_vector_type(8)));
typedef float f32x4 __attribute__((ext_vector_type(4)));
typedef float floatx2 __attribute__((ext_vector_type(2)));

static __device__ __forceinline__ ushort f2b(float f){
  unsigned u = __float_as_uint(f);
  unsigned r = (u + 0x7FFFu + ((u >> 16) & 1u)) >> 16;
  return (ushort)r;
}
static __device__ __forceinline__ float b2f(ushort u){
  return __uint_as_float(((unsigned)u) << 16);
}

__global__ void k_init(int* __restrict__ deg, float* __restrict__ pooled){
  int i = blockIdx.x*256 + threadIdx.x;
  if (i < NN) deg[i] = 0;
  if (i < NBG*HID) pooled[i] = 0.f;
}

// x fp32 [NN][128] -> bf16
__global__ void k_xb(const float* __restrict__ x, ushort* __restrict__ xb){
  int i = blockIdx.x*256 + threadIdx.x;           // element quad index
  if (i >= NN*FIN/4) return;
  float4 v = *(const float4*)(x + (size_t)i*4);
  ushort4 o; o.x=f2b(v.x); o.y=f2b(v.y); o.z=f2b(v.z); o.w=f2b(v.w);
  *(ushort4*)(xb + (size_t)i*4) = o;
}

// Wcat bf16 [256][2F] = [Wl | Wr]
__global__ void k_wcat(const float* __restrict__ Wl, const float* __restrict__ Wr,
                       int F, ushort* __restrict__ Wc){
  int F2 = 2*F;
  int i = blockIdx.x*256 + threadIdx.x;
  if (i >= HID*F2) return;
  int n = i / F2, k = i % F2;
  float v = (k < F) ? Wl[(size_t)n*F + k] : Wr[(size_t)n*F + (k-F)];
  Wc[i] = f2b(v);
}

// bf16 [NN][256] -> fp8 e4m3 [NN][256] (HW cvt, coalesced)
__global__ void k_h8(const ushort* __restrict__ h, unsigned* __restrict__ h8){
  int i = blockIdx.x*256 + threadIdx.x;           // 8 elems per thread
  if (i >= NN*HID/8) return;
  uint4 u = *(const uint4*)(h + (size_t)i*8);
  float f0 = b2f((ushort)(u.x & 0xFFFFu)), f1 = b2f((ushort)(u.x >> 16));
  float f2 = b2f((ushort)(u.y & 0xFFFFu)), f3 = b2f((ushort)(u.y >> 16));
  float f4 = b2f((ushort)(u.z & 0xFFFFu)), f5 = b2f((ushort)(u.z >> 16));
  float f6 = b2f((ushort)(u.w & 0xFFFFu)), f7 = b2f((ushort)(u.w >> 16));
  int r0 = __builtin_amdgcn_cvt_pk_fp8_f32(f0, f1, 0, false);
  r0 = __builtin_amdgcn_cvt_pk_fp8_f32(f2, f3, r0, true);
  int r1 = __builtin_amdgcn_cvt_pk_fp8_f32(f4, f5, 0, false);
  r1 = __builtin_amdgcn_cvt_pk_fp8_f32(f6, f7, r1, true);
  uint2 o; o.x = (unsigned)r0; o.y = (unsigned)r1;
  *(uint2*)(h8 + (size_t)i*2) = o;
}

__global__ void k_hist(const int* __restrict__ dst, int* __restrict__ deg){
  for (int e = blockIdx.x*blockDim.x + threadIdx.x; e < NE; e += gridDim.x*blockDim.x)
    atomicAdd(&deg[dst[e]], 1);
}

__global__ void k_partial(const int* __restrict__ deg, int* __restrict__ part){
  __shared__ int sm[256];
  int t = threadIdx.x; int i0 = blockIdx.x*512;
  int v = 0;
  if (i0 + t < NN) v += deg[i0+t];
  if (i0 + t + 256 < NN) v += deg[i0+t+256];
  sm[t] = v; __syncthreads();
  for (int o=128;o>0;o>>=1){ if (t<o) sm[t]+=sm[t+o]; __syncthreads(); }
  if (t==0) part[blockIdx.x] = sm[0];
}

__global__ void k_scanp(const int* __restrict__ part, int* __restrict__ poffs, int nb){
  if (threadIdx.x==0 && blockIdx.x==0){
    int run=0;
    for (int i=0;i<nb;++i){ poffs[i]=run; run+=part[i]; }
  }
}

__global__ void k_chunkscan(const int* __restrict__ deg, const int* __restrict__ poffs,
                            int* __restrict__ rowp, float* __restrict__ invd){
  __shared__ int buf[2][512];
  int t = threadIdx.x; int i = blockIdx.x*512 + t;
  int v = (i<NN)? deg[i] : 0;
  buf[0][t] = v; __syncthreads();
  int pp = 0;
  for (int off=1; off<512; off<<=1){
    int nv = buf[pp][t];
    if (t >= off) nv += buf[pp][t-off];
    buf[pp^1][t] = nv; __syncthreads(); pp ^= 1;
  }
  if (i < NN){
    int excl = poffs[blockIdx.x] + buf[pp][t] - v;
    rowp[i] = excl;
    invd[i] = 1.0f / (float)max(v, 1);
  }
}

// bin cursors = CSR offset of each bin's first dst (CSR order is dst-ordered)
__global__ void k_bininit(const int* __restrict__ rowp, int* __restrict__ gcur){
  int b = threadIdx.x;
  if (b < NBINS) gcur[b] = rowp[b << 8];
}

// pass 1: partition edges into 196 dst-bins; packed word = (dst&255)<<24 | src
__global__ __launch_bounds__(256) void k_pass1(const int* __restrict__ src,
                                               const int* __restrict__ dst,
                                               int* __restrict__ gcur,
                                               unsigned* __restrict__ ebin){
  __shared__ int lhist[NBINS];
  __shared__ int lbase[NBINS];
  int t = threadIdx.x;
  long e0 = (long)blockIdx.x * 4096;
  for (int i=t; i<NBINS; i+=256) lhist[i]=0;
  __syncthreads();
  unsigned pk[16]; int bn[16]; int rk[16];
  #pragma unroll
  for (int k=0;k<16;++k){
    long e = e0 + k*256 + t;
    bn[k] = -1;
    if (e < NE){
      int d = dst[e];
      int s = src[e];
      bn[k] = d >> 8;
      pk[k] = (unsigned)s | ((unsigned)(d & 255) << 24);
      rk[k] = atomicAdd(&lhist[bn[k]], 1);
    }
  }
  __syncthreads();
  for (int i=t; i<NBINS; i+=256)
    lbase[i] = atomicAdd(&gcur[i], lhist[i]);
  __syncthreads();
  #pragma unroll
  for (int k=0;k<16;++k)
    if (bn[k] >= 0) ebin[lbase[bn[k]] + rk[k]] = pk[k];
}

// pass 2: within each bin, scatter to exact CSR position via LDS cursors
__global__ __launch_bounds__(256) void k_pass2(const unsigned* __restrict__ ebin,
                                               const int* __restrict__ rowp,
                                               int* __restrict__ srcs){
  __shared__ int cur[256];
  int b = blockIdx.x, t = threadIdx.x;
  int d0 = b << 8;
  if (d0 + t < NN) cur[t] = rowp[d0 + t];
  __syncthreads();
  int st = rowp[d0];
  int en = (d0 + 256 < NN) ? rowp[d0 + 256] : NE;
  for (int i = st + t; i < en; i += 256){
    unsigned p = ebin[i];
    int doff = p >> 24;
    int s = (int)(p & 0xFFFFFFu);
    int pos = atomicAdd(&cur[doff], 1);
    srcs[pos] = s;
  }
}

// bf16 gather agg (layer 1, F=128): 16B/lane, LPR=F/8 lanes/row, 4 rows in flight/group
template<int F>
__global__ void k_agg(const ushort* __restrict__ x, const int* __restrict__ srcs,
                      const int* __restrict__ rowp, const int* __restrict__ deg,
                      const float* __restrict__ invd, ushort* __restrict__ out){
  constexpr int LPR = F/8;        // lanes per row
  constexpr int EPI = 64/LPR;     // edge slots per wave-iter
  int w = blockIdx.x*4 + (threadIdx.x>>6);
  int lane = threadIdx.x & 63;
  if (w >= NN) return;
  int st = rowp[w], d = deg[w];
  int grp = lane / LPR;
  int fo  = (lane % LPR)*8;       // feature offset (elements)
  float acc[8];
  #pragma unroll
  for (int v=0;v<8;++v) acc[v]=0.f;

  auto accum = [&](uint4 u){
    acc[0] += __uint_as_float(u.x<<16); acc[1] += __uint_as_float(u.x & 0xFFFF0000u);
    acc[2] += __uint_as_float(u.y<<16); acc[3] += __uint_as_float(u.y & 0xFFFF0000u);
    acc[4] += __uint_as_float(u.z<<16); acc[5] += __uint_as_float(u.z & 0xFFFF0000u);
    acc[6] += __uint_as_float(u.w<<16); acc[7] += __uint_as_float(u.w & 0xFFFF0000u);
  };

  int j = 0;
  for (; j + 4*EPI <= d; j += 4*EPI){
    int i0 = srcs[st + j + grp];
    int i1 = srcs[st + j + EPI + grp];
    int i2 = srcs[st + j + 2*EPI + grp];
    int i3 = srcs[st + j + 3*EPI + grp];
    uint4 u0 = *(const uint4*)(x + (size_t)i0*F + fo);
    uint4 u1 = *(const uint4*)(x + (size_t)i1*F + fo);
    uint4 u2 = *(const uint4*)(x + (size_t)i2*F + fo);
    uint4 u3 = *(const uint4*)(x + (size_t)i3*F + fo);
    accum(u0); accum(u1); accum(u2); accum(u3);
  }
  for (; j < d; j += EPI){
    int jj = j + grp;
    if (jj < d){
      int i0 = srcs[st + jj];
      uint4 u0 = *(const uint4*)(x + (size_t)i0*F + fo);
      accum(u0);
    }
  }
  #pragma unroll
  for (int off = LPR; off < 64; off <<= 1){
    #pragma unroll
    for (int v=0;v<8;++v) acc[v] += __shfl_xor(acc[v], off);
  }
  if (grp == 0){
    float sc = invd[w];
    uint4 o;
    o.x = (unsigned)f2b(acc[0]*sc) | ((unsigned)f2b(acc[1]*sc)<<16);
    o.y = (unsigned)f2b(acc[2]*sc) | ((unsigned)f2b(acc[3]*sc)<<16);
    o.z = (unsigned)f2b(acc[4]*sc) | ((unsigned)f2b(acc[5]*sc)<<16);
    o.w = (unsigned)f2b(acc[6]*sc) | ((unsigned)f2b(acc[7]*sc)<<16);
    *(uint4*)(out + (size_t)w*F + fo) = o;
  }
}

// fp8 gather agg (layers 2,3, F=256): row = 256B = 16 lanes x 16B (16 fp8 each),
// 4 edge groups/wave, 4 rows in flight per group; fp32 accumulate; bf16 out.
__global__ void k_agg8(const unsigned* __restrict__ x8, const int* __restrict__ srcs,
                       const int* __restrict__ rowp, const int* __restrict__ deg,
                       const float* __restrict__ invd, ushort* __restrict__ out){
  int w = blockIdx.x*4 + (threadIdx.x>>6);
  int lane = threadIdx.x & 63;
  if (w >= NN) return;
  int st = rowp[w], d = deg[w];
  int grp = lane >> 4;            // 0..3
  int sub = lane & 15;            // 16B chunk within row
  const uint4* xr = (const uint4*)x8;
  float acc[16];
  #pragma unroll
  for (int v=0;v<16;++v) acc[v]=0.f;

  auto accum = [&](uint4 u){
    floatx2 p;
    p = __builtin_amdgcn_cvt_pk_f32_fp8(u.x, false); acc[0]+=p.x;  acc[1]+=p.y;
    p = __builtin_amdgcn_cvt_pk_f32_fp8(u.x, true);  acc[2]+=p.x;  acc[3]+=p.y;
    p = __builtin_amdgcn_cvt_pk_f32_fp8(u.y, false); acc[4]+=p.x;  acc[5]+=p.y;
    p = __builtin_amdgcn_cvt_pk_f32_fp8(u.y, true);  acc[6]+=p.x;  acc[7]+=p.y;
    p = __builtin_amdgcn_cvt_pk_f32_fp8(u.z, false); acc[8]+=p.x;  acc[9]+=p.y;
    p = __builtin_amdgcn_cvt_pk_f32_fp8(u.z, true);  acc[10]+=p.x; acc[11]+=p.y;
    p = __builtin_amdgcn_cvt_pk_f32_fp8(u.w, false); acc[12]+=p.x; acc[13]+=p.y;
    p = __builtin_amdgcn_cvt_pk_f32_fp8(u.w, true);  acc[14]+=p.x; acc[15]+=p.y;
  };

  int j = 0;
  for (; j + 16 <= d; j += 16){
    int i0 = srcs[st + j + grp];
    int i1 = srcs[st + j + 4 + grp];
    int i2 = srcs[st + j + 8 + grp];
    int i3 = srcs[st + j + 12 + grp];
    uint4 u0 = xr[(size_t)i0*16 + sub];
    uint4 u1 = xr[(size_t)i1*16 + sub];
    uint4 u2 = xr[(size_t)i2*16 + sub];
    uint4 u3 = xr[(size_t)i3*16 + sub];
    accum(u0); accum(u1); accum(u2); accum(u3);
  }
  for (; j < d; j += 4){
    int jj = j + grp;
    if (jj < d){
      int i0 = srcs[st + jj];
      uint4 u0 = xr[(size_t)i0*16 + sub];
      accum(u0);
    }
  }
  #pragma unroll
  for (int off = 16; off < 64; off <<= 1){
    #pragma unroll
    for (int v=0;v<16;++v) acc[v] += __shfl_xor(acc[v], off);
  }
  if (grp == 0){
    float sc = invd[w];
    uint4 o1, o2;
    o1.x = (unsigned)f2b(acc[0]*sc)  | ((unsigned)f2b(acc[1]*sc)<<16);
    o1.y = (unsigned)f2b(acc[2]*sc)  | ((unsigned)f2b(acc[3]*sc)<<16);
    o1.z = (unsigned)f2b(acc[4]*sc)  | ((unsigned)f2b(acc[5]*sc)<<16);
    o1.w = (unsigned)f2b(acc[6]*sc)  | ((unsigned)f2b(acc[7]*sc)<<16);
    o2.x = (unsigned)f2b(acc[8]*sc)  | ((unsigned)f2b(acc[9]*sc)<<16);
    o2.y = (unsigned)f2b(acc[10]*sc) | ((unsigned)f2b(acc[11]*sc)<<16);
    o2.z = (unsigned)f2b(acc[12]*sc) | ((unsigned)f2b(acc[13]*sc)<<16);
    o2.w = (unsigned)f2b(acc[14]*sc) | ((unsigned)f2b(acc[15]*sc)<<16);
    ushort* op = out + (size_t)w*HID + sub*16;
    *(uint4*)op = o1;
    *(uint4*)(op + 8) = o2;
  }
}

// MFMA GEMM: out[m][n] = relu( sum_k [A1|A2][m][k] * Wc[n][k] + bias[n] ), bf16 in, bf16 out
// BM=128, BN=256 (full width), BK=64, 512 threads = 8 waves (2 Mx4 N), wave tile 64x64.
#define LDT 72
__global__ __launch_bounds__(512) void k_gemm(
    const ushort* __restrict__ A1, int ldA1,
    const ushort* __restrict__ A2, int ldA2,
    const ushort* __restrict__ Wc, int F2,
    const float* __restrict__ bias, ushort* __restrict__ out, int M)
{
  __shared__ ushort As[128*LDT];
  __shared__ ushort Bs[256*LDT];
  int t = threadIdx.x;
  int l = t & 63;
  int wv = t >> 6;
  int wr = wv >> 2, wc = wv & 3;
  int m0 = blockIdx.x * 128;
  int F = F2 >> 1;
  f32x4 acc[4][4];
  #pragma unroll
  for (int a=0;a<4;++a)
  #pragma unroll
  for (int b=0;b<4;++b) acc[a][b] = (f32x4){0.f,0.f,0.f,0.f};

  int nsteps = F2/64;
  for (int s=0; s<nsteps; ++s){
    int kk = s*64;
    const ushort* src; int ld, kkl;
    if (kk < F){ src = A1; ld = ldA1; kkl = kk; }
    else       { src = A2; ld = ldA2; kkl = kk - F; }
    uint4 av[2];
    int arow[2], ack[2];
    #pragma unroll
    for (int i=0;i<2;++i){
      int c = t*2 + i;
      arow[i] = c >> 3; ack[i] = c & 7;
      int m = m0 + arow[i];
      av[i] = make_uint4(0u,0u,0u,0u);
      if (m < M) av[i] = *(const uint4*)(src + (size_t)m*ld + kkl + ack[i]*8);
    }
    uint4 bv[4];
    int brow[4], bck[4];
    #pragma unroll
    for (int i=0;i<4;++i){
      int c = t*4 + i;
      brow[i] = c >> 3; bck[i] = c & 7;
      bv[i] = *(const uint4*)(Wc + (size_t)brow[i]*F2 + kk + bck[i]*8);
    }
    #pragma unroll
    for (int i=0;i<2;++i)
      *(uint4*)&As[arow[i]*LDT + ack[i]*8] = av[i];
    #pragma unroll
    for (int i=0;i<4;++i)
      *(uint4*)&Bs[brow[i]*LDT + bck[i]*8] = bv[i];
    __syncthreads();

    #pragma unroll
    for (int ks=0; ks<2; ++ks){
      bf16x8 af[4], bf[4];
      int ko = ks*32 + (l>>4)*8;
      #pragma unroll
      for (int mf=0; mf<4; ++mf)
        af[mf] = *(bf16x8*)&As[(wr*64 + mf*16 + (l&15))*LDT + ko];
      #pragma unroll
      for (int nf=0; nf<4; ++nf)
        bf[nf] = *(bf16x8*)&Bs[(wc*64 + nf*16 + (l&15))*LDT + ko];
      #pragma unroll
      for (int mf=0; mf<4; ++mf)
      #pragma unroll
      for (int nf=0; nf<4; ++nf)
        acc[mf][nf] = __builtin_amdgcn_mfma_f32_16x16x32_bf16(bf[nf], af[mf], acc[mf][nf], 0, 0, 0);
    }
    __syncthreads();
  }

  #pragma unroll
  for (int mf=0; mf<4; ++mf){
    int m = m0 + wr*64 + mf*16 + (l&15);
    if (m >= M) continue;
    #pragma unroll
    for (int nf=0; nf<4; ++nf){
      int ncol = wc*64 + nf*16 + (l>>4)*4;
      float4 bb = *(const float4*)&bias[ncol];
      ushort4 o;
      o.x = f2b(fmaxf(acc[mf][nf][0] + bb.x, 0.f));
      o.y = f2b(fmaxf(acc[mf][nf][1] + bb.y, 0.f));
      o.z = f2b(fmaxf(acc[mf][nf][2] + bb.z, 0.f));
      o.w = f2b(fmaxf(acc[mf][nf][3] + bb.w, 0.f));
      *(ushort4*)(out + (size_t)m*HID + ncol) = o;
    }
  }
}

// gate GEMV over bf16 h
__global__ void k_gate(const ushort* __restrict__ h, const float* __restrict__ Wg,
                       const float* __restrict__ bg, float* __restrict__ gate){
  int w = blockIdx.x*4 + (threadIdx.x>>6);
  int lane = threadIdx.x & 63;
  if (w >= NN) return;
  uint2 u = *(const uint2*)(h + (size_t)w*HID + lane*4);
  float4 wg = *(const float4*)(Wg + lane*4);
  float d = __uint_as_float(u.x<<16)*wg.x + __uint_as_float(u.x&0xFFFF0000u)*wg.y
          + __uint_as_float(u.y<<16)*wg.z + __uint_as_float(u.y&0xFFFF0000u)*wg.w;
  #pragma unroll
  for (int o=32;o>0;o>>=1) d += __shfl_down(d, o);
  if (lane==0) gate[w] = d + bg[0];
}

__global__ void k_seg(const int* __restrict__ batch, int* __restrict__ starts){
  int b = threadIdx.x;
  if (b > NBG) return;
  int lo = 0, hi = NN;
  while (lo < hi){ int mid = (lo+hi)>>1; if (batch[mid] < b) lo = mid+1; else hi = mid; }
  starts[b] = lo;
}

__global__ void k_msum(const float* __restrict__ gate, const int* __restrict__ starts,
                       float* __restrict__ m, float* __restrict__ s){
  __shared__ float sm[256];
  int b = blockIdx.x, t = threadIdx.x;
  int st = starts[b], en = starts[b+1];
  float mx = -3.0e38f;
  for (int i = st + t; i < en; i += 256) mx = fmaxf(mx, gate[i]);
  sm[t] = mx; __syncthreads();
  for (int o=128;o>0;o>>=1){ if (t<o) sm[t]=fmaxf(sm[t],sm[t+o]); __syncthreads(); }
  float M = sm[0]; __syncthreads();
  float su = 0.f;
  for (int i = st + t; i < en; i += 256) su += expf(gate[i]-M);
  sm[t] = su; __syncthreads();
  for (int o=128;o>0;o>>=1){ if (t<o) sm[t]+=sm[t+o]; __syncthreads(); }
  if (t==0){ m[b]=M; s[b]=sm[0]; }
}

__global__ void k_pool(const ushort* __restrict__ h, const float* __restrict__ gate,
                       const int* __restrict__ batch, const float* __restrict__ m,
                       const float* __restrict__ s, float* __restrict__ pooled){
  __shared__ float sa[256];
  __shared__ int sb[256];
  int t = threadIdx.x;
  int i0 = blockIdx.x*256;
  int iend = min(i0+256, NN);
  {
    int i = i0 + t;
    if (i < NN){
      int b = batch[i];
      sb[t] = b;
      sa[t] = expf(gate[i] - m[b]) / s[b];
    }
  }
  __syncthreads();
  float acc = 0.f;
  int bcur = sb[0];
  for (int i=i0;i<iend;++i){
    int b = sb[i-i0];
    if (b != bcur){
      atomicAdd(&pooled[bcur*HID + t], acc);
      acc = 0.f; bcur = b;
    }
    acc = fmaf(sa[i-i0], b2f(h[(size_t)i*HID + t]), acc);
  }
  atomicAdd(&pooled[bcur*HID + t], acc);
}

__global__ void k_head(const float* __restrict__ pooled, const float* __restrict__ Wl1,
                       const float* __restrict__ bl1, const float* __restrict__ Wl2,
                       const float* __restrict__ bl2, float* __restrict__ out){
  __shared__ float pr[256]; __shared__ float o1[256]; __shared__ float lg[16];
  int b = blockIdx.x, t = threadIdx.x;
  pr[t] = pooled[b*HID + t];
  __syncthreads();
  float a = bl1[t];
  const float* wr = Wl1 + (size_t)t*HID;
  #pragma unroll 4
  for (int k=0;k<HID;k+=4){
    float4 w4 = *(const float4*)(wr + k);
    a += pr[k]*w4.x + pr[k+1]*w4.y + pr[k+2]*w4.z + pr[k+3]*w4.w;
  }
  o1[t] = fmaxf(a, 0.f);
  __syncthreads();
  if (t < NC){
    float a2 = bl2[t];
    const float* w2 = Wl2 + (size_t)t*HID;
    for (int k=0;k<HID;++k) a2 += o1[k]*w2[k];
    lg[t] = a2;
  }
  __syncthreads();
  if (t == 0){
    float mx = lg[0];
    for (int c2=1;c2<NC;++c2) mx = fmaxf(mx, lg[c2]);
    float se = 0.f;
    for (int c2=0;c2<NC;++c2) se += expf(lg[c2]-mx);
    float lse = mx + logf(se);
    for (int c2=0;c2<NC;++c2) out[b*NC + c2] = lg[c2] - lse;
  }
}

extern "C" void kernel_launch(void* const* d_in, const int* in_sizes, int n_in,
                              void* d_out, int out_size, void* d_ws, size_t ws_size,
                              hipStream_t stream){
  const float* x   = (const float*)d_in[0];
  const int*   ei  = (const int*)d_in[1];
  const int*   bat = (const int*)d_in[2];
  const float* W1l = (const float*)d_in[3];
  const float* b1l = (const float*)d_in[4];
  const float* W1r = (const float*)d_in[5];
  const float* W2l = (const float*)d_in[6];
  const float* b2l = (const float*)d_in[7];
  const float* W2r = (const float*)d_in[8];
  const float* W3l = (const float*)d_in[9];
  const float* b3l = (const float*)d_in[10];
  const float* W3r = (const float*)d_in[11];
  const float* Wg  = (const float*)d_in[12];
  const float* bg  = (const float*)d_in[13];
  const float* Wl1 = (const float*)d_in[14];
  const float* bl1 = (const float*)d_in[15];
  const float* Wl2 = (const float*)d_in[16];
  const float* bl2 = (const float*)d_in[17];
  const int* srcI = ei;
  const int* dstI = ei + NE;
  float* out = (float*)d_out;

  char* w = (char*)d_ws;
  auto take = [&](size_t bytes)->char*{
    char* p = w; w += (bytes + 255) & ~(size_t)255; return p;
  };
  int*      deg    = (int*)take((size_t)NN*4);
  float*    invd   = (float*)take((size_t)NN*4);
  int*      rowp   = (int*)take((size_t)NN*4);
  int*      gcur   = (int*)take(256*4);
  int*      srcs   = (int*)take((size_t)NE*4);
  unsigned* ebin   = (unsigned*)take((size_t)NE*4);
  int*      part   = (int*)take(128*4);
  int*      poffs  = (int*)take(128*4);
  float*    gate   = (float*)take((size_t)NN*4);
  int*      starts = (int*)take(128*4);
  float*    m      = (float*)take(64*4);
  float*    s      = (float*)take(64*4);
  float*    pooled = (float*)take(64*256*4);
  ushort*   xb     = (ushort*)take((size_t)NN*FIN*2);
  ushort*   Wc1    = (ushort*)take((size_t)HID*2*FIN*2);
  ushort*   Wc2    = (ushort*)take((size_t)HID*2*HID*2);
  ushort*   Wc3    = (ushort*)take((size_t)HID*2*HID*2);
  ushort*   AG     = (ushort*)take((size_t)NN*HID*2);
  ushort*   HB     = (ushort*)take((size_t)NN*HID*2);
  unsigned* H8     = (unsigned*)take((size_t)NN*HID);

  int nb = (NN + 511)/512;

  k_init<<<(NN+255)/256, 256, 0, stream>>>(deg, pooled);
  k_xb<<<(NN*FIN/4+255)/256, 256, 0, stream>>>(x, xb);
  k_wcat<<<(HID*2*FIN+255)/256, 256, 0, stream>>>(W1l, W1r, FIN, Wc1);
  k_wcat<<<(HID*2*HID+255)/256, 256, 0, stream>>>(W2l, W2r, HID, Wc2);
  k_wcat<<<(HID*2*HID+255)/256, 256, 0, stream>>>(W3l, W3r, HID, Wc3);
  k_hist<<<1024, 256, 0, stream>>>(dstI, deg);
  k_partial<<<nb, 256, 0, stream>>>(deg, part);
  k_scanp<<<1, 64, 0, stream>>>(part, poffs, nb);
  k_chunkscan<<<nb, 512, 0, stream>>>(deg, poffs, rowp, invd);
  k_bininit<<<1, 256, 0, stream>>>(rowp, gcur);
  k_pass1<<<(NE + 4095)/4096, 256, 0, stream>>>(srcI, dstI, gcur, ebin);
  k_pass2<<<NBINS, 256, 0, stream>>>(ebin, rowp, srcs);

  int gblocks = (NN + 127)/128;
  int h8blocks = (NN*HID/8 + 255)/256;
  // layer 1: agg(xb) -> AG (bf16); h1 = gemm(AG, xb) -> HB; fp8 copy HB -> H8
  k_agg<128><<<(NN+3)/4, 256, 0, stream>>>(xb, srcs, rowp, deg, invd, AG);
  k_gemm<<<gblocks, 512, 0, stream>>>(AG, FIN, xb, FIN, Wc1, 2*FIN, b1l, HB, NN);
  k_h8<<<h8blocks, 256, 0, stream>>>(HB, H8);
  // layer 2: agg8(H8) -> AG; h2 = gemm(AG, HB) -> AG (in-place); fp8 copy AG -> H8
  k_agg8<<<(NN+3)/4, 256, 0, stream>>>(H8, srcs, rowp, deg, invd, AG);
  k_gemm<<<gblocks, 512, 0, stream>>>(AG, HID, HB, HID, Wc2, 2*HID, b2l, AG, NN);
  k_h8<<<h8blocks, 256, 0, stream>>>(AG, H8);
  // layer 3: agg8(H8) -> HB; h3 = gemm(HB, AG) -> HB
  k_agg8<<<(NN+3)/4, 256, 0, stream>>>(H8, srcs, rowp, deg, invd, HB);
  k_gemm<<<gblocks, 512, 0, stream>>>(HB, HID, AG, HID, Wc3, 2*HID, b3l, HB, NN);

  // attention pooling over h3 = HB
  k_gate<<<(NN+3)/4, 256, 0, stream>>>(HB, Wg, bg, gate);
  k_seg<<<1, 128, 0, stream>>>(bat, starts);
  k_msum<<<NBG, 256, 0, stream>>>(gate, starts, m, s);
  k_pool<<<(NN+255)/256, 256, 0, stream>>>(HB, gate, bat, m, s, pooled);
  k_head<<<NBG, 256, 0, stream>>>(pooled, Wl1, bl1, Wl2, bl2, out);
}

// Round 9
// 540.340 us; speedup vs baseline: 4.0046x; 1.1262x over previous
//
#include <hip/hip_runtime.h>

#define NN 50000
#define FIN 128
#define HID 256
#define NE 1600000
#define NBG 64
#define NC 10
#define NBINS ((NN + 255) >> 8)   // 196

typedef short bf16x8 __attribute__((ext_vector_type(8)));
typedef float f32x4 __attribute__((ext_vector_type(4)));
typedef float floatx2 __attribute__((ext_vector_type(2)));

static __device__ __forceinline__ ushort f2b(float f){
  unsigned u = __float_as_uint(f);
  unsigned r = (u + 0x7FFFu + ((u >> 16) & 1u)) >> 16;
  return (ushort)r;
}
static __device__ __forceinline__ float b2f(ushort u){
  return __uint_as_float(((unsigned)u) << 16);
}

__global__ void k_init(int* __restrict__ bincnt, float* __restrict__ pooled){
  int i = blockIdx.x*256 + threadIdx.x;
  if (i < 256) bincnt[i] = 0;
  if (i < NBG*HID) pooled[i] = 0.f;
}

// x fp32 [NN][128] -> bf16
__global__ void k_xb(const float* __restrict__ x, ushort* __restrict__ xb){
  int i = blockIdx.x*256 + threadIdx.x;           // element quad index
  if (i >= NN*FIN/4) return;
  float4 v = *(const float4*)(x + (size_t)i*4);
  ushort4 o; o.x=f2b(v.x); o.y=f2b(v.y); o.z=f2b(v.z); o.w=f2b(v.w);
  *(ushort4*)(xb + (size_t)i*4) = o;
}

// Wcat bf16 [256][2F] = [Wl | Wr]
__global__ void k_wcat(const float* __restrict__ Wl, const float* __restrict__ Wr,
                       int F, ushort* __restrict__ Wc){
  int F2 = 2*F;
  int i = blockIdx.x*256 + threadIdx.x;
  if (i >= HID*F2) return;
  int n = i / F2, k = i % F2;
  float v = (k < F) ? Wl[(size_t)n*F + k] : Wr[(size_t)n*F + (k-F)];
  Wc[i] = f2b(v);
}

// per-block LDS histogram of 196 dst-bins -> one global atomic per bin per block
__global__ __launch_bounds__(256) void k_binhist(const int* __restrict__ dst,
                                                 int* __restrict__ bincnt){
  __shared__ int lh[NBINS];
  int t = threadIdx.x;
  for (int i=t; i<NBINS; i+=256) lh[i]=0;
  __syncthreads();
  long e0 = (long)blockIdx.x * 4096;
  #pragma unroll
  for (int k=0;k<16;++k){
    long e = e0 + k*256 + t;
    if (e < NE) atomicAdd(&lh[dst[e] >> 8], 1);
  }
  __syncthreads();
  for (int i=t; i<NBINS; i+=256)
    if (lh[i]) atomicAdd(&bincnt[i], lh[i]);
}

// one-block exclusive scan of bin counts -> binoff[0..NBINS], seeds gcur
__global__ void k_scanbins(const int* __restrict__ bincnt, int* __restrict__ binoff,
                           int* __restrict__ gcur){
  __shared__ int buf[2][256];
  int t = threadIdx.x;
  int v = (t < NBINS) ? bincnt[t] : 0;
  buf[0][t] = v; __syncthreads();
  int pp = 0;
  for (int off=1; off<256; off<<=1){
    int nv = buf[pp][t];
    if (t >= off) nv += buf[pp][t-off];
    buf[pp^1][t] = nv; __syncthreads(); pp ^= 1;
  }
  int excl = buf[pp][t] - v;
  if (t < NBINS){ binoff[t] = excl; gcur[t] = excl; }
  if (t == 0) binoff[NBINS] = NE;
}

// pass 1: partition edges into 196 dst-bins; packed word = (dst&255)<<24 | src
__global__ __launch_bounds__(256) void k_pass1(const int* __restrict__ src,
                                               const int* __restrict__ dst,
                                               int* __restrict__ gcur,
                                               unsigned* __restrict__ ebin){
  __shared__ int lhist[NBINS];
  __shared__ int lbase[NBINS];
  int t = threadIdx.x;
  long e0 = (long)blockIdx.x * 4096;
  for (int i=t; i<NBINS; i+=256) lhist[i]=0;
  __syncthreads();
  unsigned pk[16]; int bn[16]; int rk[16];
  #pragma unroll
  for (int k=0;k<16;++k){
    long e = e0 + k*256 + t;
    bn[k] = -1;
    if (e < NE){
      int d = dst[e];
      int s = src[e];
      bn[k] = d >> 8;
      pk[k] = (unsigned)s | ((unsigned)(d & 255) << 24);
      rk[k] = atomicAdd(&lhist[bn[k]], 1);
    }
  }
  __syncthreads();
  for (int i=t; i<NBINS; i+=256)
    lbase[i] = atomicAdd(&gcur[i], lhist[i]);
  __syncthreads();
  #pragma unroll
  for (int k=0;k<16;++k)
    if (bn[k] >= 0) ebin[lbase[bn[k]] + rk[k]] = pk[k];
}

// pass 2: per bin, derive per-dst deg/rowp/invd (LDS hist + scan; CSR is
// dst-ordered and bins are dst-contiguous), then scatter srcs via LDS cursors.
__global__ __launch_bounds__(256) void k_pass2(const unsigned* __restrict__ ebin,
                                               const int* __restrict__ binoff,
                                               int* __restrict__ rowp,
                                               int* __restrict__ deg,
                                               float* __restrict__ invd,
                                               int* __restrict__ srcs){
  __shared__ int cnt[256];
  __shared__ int buf[2][256];
  __shared__ int cur[256];
  int b = blockIdx.x, t = threadIdx.x;
  int d0 = b << 8;
  int st = binoff[b], en = binoff[b+1];
  cnt[t] = 0;
  __syncthreads();
  for (int i = st + t; i < en; i += 256)
    atomicAdd(&cnt[ebin[i] >> 24], 1);
  __syncthreads();
  int v = cnt[t];
  buf[0][t] = v; __syncthreads();
  int pp = 0;
  for (int off=1; off<256; off<<=1){
    int nv = buf[pp][t];
    if (t >= off) nv += buf[pp][t-off];
    buf[pp^1][t] = nv; __syncthreads(); pp ^= 1;
  }
  int excl = st + buf[pp][t] - v;
  if (d0 + t < NN){
    rowp[d0 + t] = excl;
    deg[d0 + t] = v;
    invd[d0 + t] = 1.0f / (float)max(v, 1);
  }
  cur[t] = excl;
  __syncthreads();
  for (int i = st + t; i < en; i += 256){
    unsigned p = ebin[i];
    int doff = p >> 24;
    int pos = atomicAdd(&cur[doff], 1);
    srcs[pos] = (int)(p & 0xFFFFFFu);
  }
}

// bf16 gather agg (layer 1, F=128): 16B/lane, LPR=F/8 lanes/row, 4 rows in flight/group
template<int F>
__global__ void k_agg(const ushort* __restrict__ x, const int* __restrict__ srcs,
                      const int* __restrict__ rowp, const int* __restrict__ deg,
                      const float* __restrict__ invd, ushort* __restrict__ out){
  constexpr int LPR = F/8;        // lanes per row
  constexpr int EPI = 64/LPR;     // edge slots per wave-iter
  int w = blockIdx.x*4 + (threadIdx.x>>6);
  int lane = threadIdx.x & 63;
  if (w >= NN) return;
  int st = rowp[w], d = deg[w];
  int grp = lane / LPR;
  int fo  = (lane % LPR)*8;       // feature offset (elements)
  float acc[8];
  #pragma unroll
  for (int v=0;v<8;++v) acc[v]=0.f;

  auto accum = [&](uint4 u){
    acc[0] += __uint_as_float(u.x<<16); acc[1] += __uint_as_float(u.x & 0xFFFF0000u);
    acc[2] += __uint_as_float(u.y<<16); acc[3] += __uint_as_float(u.y & 0xFFFF0000u);
    acc[4] += __uint_as_float(u.z<<16); acc[5] += __uint_as_float(u.z & 0xFFFF0000u);
    acc[6] += __uint_as_float(u.w<<16); acc[7] += __uint_as_float(u.w & 0xFFFF0000u);
  };

  int j = 0;
  for (; j + 4*EPI <= d; j += 4*EPI){
    int i0 = srcs[st + j + grp];
    int i1 = srcs[st + j + EPI + grp];
    int i2 = srcs[st + j + 2*EPI + grp];
    int i3 = srcs[st + j + 3*EPI + grp];
    uint4 u0 = *(const uint4*)(x + (size_t)i0*F + fo);
    uint4 u1 = *(const uint4*)(x + (size_t)i1*F + fo);
    uint4 u2 = *(const uint4*)(x + (size_t)i2*F + fo);
    uint4 u3 = *(const uint4*)(x + (size_t)i3*F + fo);
    accum(u0); accum(u1); accum(u2); accum(u3);
  }
  for (; j < d; j += EPI){
    int jj = j + grp;
    if (jj < d){
      int i0 = srcs[st + jj];
      uint4 u0 = *(const uint4*)(x + (size_t)i0*F + fo);
      accum(u0);
    }
  }
  #pragma unroll
  for (int off = LPR; off < 64; off <<= 1){
    #pragma unroll
    for (int v=0;v<8;++v) acc[v] += __shfl_xor(acc[v], off);
  }
  if (grp == 0){
    float sc = invd[w];
    uint4 o;
    o.x = (unsigned)f2b(acc[0]*sc) | ((unsigned)f2b(acc[1]*sc)<<16);
    o.y = (unsigned)f2b(acc[2]*sc) | ((unsigned)f2b(acc[3]*sc)<<16);
    o.z = (unsigned)f2b(acc[4]*sc) | ((unsigned)f2b(acc[5]*sc)<<16);
    o.w = (unsigned)f2b(acc[6]*sc) | ((unsigned)f2b(acc[7]*sc)<<16);
    *(uint4*)(out + (size_t)w*F + fo) = o;
  }
}

// fp8 gather agg (layers 2,3, F=256): row = 256B = 16 lanes x 16B (16 fp8 each),
// 4 edge groups/wave, 4 rows in flight per group; fp32 accumulate; bf16 out.
__global__ void k_agg8(const unsigned* __restrict__ x8, const int* __restrict__ srcs,
                       const int* __restrict__ rowp, const int* __restrict__ deg,
                       const float* __restrict__ invd, ushort* __restrict__ out){
  int w = blockIdx.x*4 + (threadIdx.x>>6);
  int lane = threadIdx.x & 63;
  if (w >= NN) return;
  int st = rowp[w], d = deg[w];
  int grp = lane >> 4;            // 0..3
  int sub = lane & 15;            // 16B chunk within row
  const uint4* xr = (const uint4*)x8;
  float acc[16];
  #pragma unroll
  for (int v=0;v<16;++v) acc[v]=0.f;

  auto accum = [&](uint4 u){
    floatx2 p;
    p = __builtin_amdgcn_cvt_pk_f32_fp8(u.x, false); acc[0]+=p.x;  acc[1]+=p.y;
    p = __builtin_amdgcn_cvt_pk_f32_fp8(u.x, true);  acc[2]+=p.x;  acc[3]+=p.y;
    p = __builtin_amdgcn_cvt_pk_f32_fp8(u.y, false); acc[4]+=p.x;  acc[5]+=p.y;
    p = __builtin_amdgcn_cvt_pk_f32_fp8(u.y, true);  acc[6]+=p.x;  acc[7]+=p.y;
    p = __builtin_amdgcn_cvt_pk_f32_fp8(u.z, false); acc[8]+=p.x;  acc[9]+=p.y;
    p = __builtin_amdgcn_cvt_pk_f32_fp8(u.z, true);  acc[10]+=p.x; acc[11]+=p.y;
    p = __builtin_amdgcn_cvt_pk_f32_fp8(u.w, false); acc[12]+=p.x; acc[13]+=p.y;
    p = __builtin_amdgcn_cvt_pk_f32_fp8(u.w, true);  acc[14]+=p.x; acc[15]+=p.y;
  };

  int j = 0;
  for (; j + 16 <= d; j += 16){
    int i0 = srcs[st + j + grp];
    int i1 = srcs[st + j + 4 + grp];
    int i2 = srcs[st + j + 8 + grp];
    int i3 = srcs[st + j + 12 + grp];
    uint4 u0 = xr[(size_t)i0*16 + sub];
    uint4 u1 = xr[(size_t)i1*16 + sub];
    uint4 u2 = xr[(size_t)i2*16 + sub];
    uint4 u3 = xr[(size_t)i3*16 + sub];
    accum(u0); accum(u1); accum(u2); accum(u3);
  }
  for (; j < d; j += 4){
    int jj = j + grp;
    if (jj < d){
      int i0 = srcs[st + jj];
      uint4 u0 = xr[(size_t)i0*16 + sub];
      accum(u0);
    }
  }
  #pragma unroll
  for (int off = 16; off < 64; off <<= 1){
    #pragma unroll
    for (int v=0;v<16;++v) acc[v] += __shfl_xor(acc[v], off);
  }
  if (grp == 0){
    float sc = invd[w];
    uint4 o1, o2;
    o1.x = (unsigned)f2b(acc[0]*sc)  | ((unsigned)f2b(acc[1]*sc)<<16);
    o1.y = (unsigned)f2b(acc[2]*sc)  | ((unsigned)f2b(acc[3]*sc)<<16);
    o1.z = (unsigned)f2b(acc[4]*sc)  | ((unsigned)f2b(acc[5]*sc)<<16);
    o1.w = (unsigned)f2b(acc[6]*sc)  | ((unsigned)f2b(acc[7]*sc)<<16);
    o2.x = (unsigned)f2b(acc[8]*sc)  | ((unsigned)f2b(acc[9]*sc)<<16);
    o2.y = (unsigned)f2b(acc[10]*sc) | ((unsigned)f2b(acc[11]*sc)<<16);
    o2.z = (unsigned)f2b(acc[12]*sc) | ((unsigned)f2b(acc[13]*sc)<<16);
    o2.w = (unsigned)f2b(acc[14]*sc) | ((unsigned)f2b(acc[15]*sc)<<16);
    ushort* op = out + (size_t)w*HID + sub*16;
    *(uint4*)op = o1;
    *(uint4*)(op + 8) = o2;
  }
}

// MFMA GEMM: out[m][n] = relu( sum_k [A1|A2][m][k] * Wc[n][k] + bias[n] ), bf16 in,
// bf16 out (+ optional fused fp8 e4m3 copy). BM=128, BN=256, BK=64, 8 waves.
#define LDT 72
__global__ __launch_bounds__(512) void k_gemm(
    const ushort* __restrict__ A1, int ldA1,
    const ushort* __restrict__ A2, int ldA2,
    const ushort* __restrict__ Wc, int F2,
    const float* __restrict__ bias, ushort* __restrict__ out,
    unsigned* __restrict__ out8, int M)
{
  __shared__ ushort As[128*LDT];
  __shared__ ushort Bs[256*LDT];
  int t = threadIdx.x;
  int l = t & 63;
  int wv = t >> 6;
  int wr = wv >> 2, wc = wv & 3;
  int m0 = blockIdx.x * 128;
  int F = F2 >> 1;
  f32x4 acc[4][4];
  #pragma unroll
  for (int a=0;a<4;++a)
  #pragma unroll
  for (int b=0;b<4;++b) acc[a][b] = (f32x4){0.f,0.f,0.f,0.f};

  int nsteps = F2/64;
  for (int s=0; s<nsteps; ++s){
    int kk = s*64;
    const ushort* src; int ld, kkl;
    if (kk < F){ src = A1; ld = ldA1; kkl = kk; }
    else       { src = A2; ld = ldA2; kkl = kk - F; }
    uint4 av[2];
    int arow[2], ack[2];
    #pragma unroll
    for (int i=0;i<2;++i){
      int c = t*2 + i;
      arow[i] = c >> 3; ack[i] = c & 7;
      int m = m0 + arow[i];
      av[i] = make_uint4(0u,0u,0u,0u);
      if (m < M) av[i] = *(const uint4*)(src + (size_t)m*ld + kkl + ack[i]*8);
    }
    uint4 bv[4];
    int brow[4], bck[4];
    #pragma unroll
    for (int i=0;i<4;++i){
      int c = t*4 + i;
      brow[i] = c >> 3; bck[i] = c & 7;
      bv[i] = *(const uint4*)(Wc + (size_t)brow[i]*F2 + kk + bck[i]*8);
    }
    #pragma unroll
    for (int i=0;i<2;++i)
      *(uint4*)&As[arow[i]*LDT + ack[i]*8] = av[i];
    #pragma unroll
    for (int i=0;i<4;++i)
      *(uint4*)&Bs[brow[i]*LDT + bck[i]*8] = bv[i];
    __syncthreads();

    #pragma unroll
    for (int ks=0; ks<2; ++ks){
      bf16x8 af[4], bf[4];
      int ko = ks*32 + (l>>4)*8;
      #pragma unroll
      for (int mf=0; mf<4; ++mf)
        af[mf] = *(bf16x8*)&As[(wr*64 + mf*16 + (l&15))*LDT + ko];
      #pragma unroll
      for (int nf=0; nf<4; ++nf)
        bf[nf] = *(bf16x8*)&Bs[(wc*64 + nf*16 + (l&15))*LDT + ko];
      #pragma unroll
      for (int mf=0; mf<4; ++mf)
      #pragma unroll
      for (int nf=0; nf<4; ++nf)
        acc[mf][nf] = __builtin_amdgcn_mfma_f32_16x16x32_bf16(bf[nf], af[mf], acc[mf][nf], 0, 0, 0);
    }
    __syncthreads();
  }

  #pragma unroll
  for (int mf=0; mf<4; ++mf){
    int m = m0 + wr*64 + mf*16 + (l&15);
    if (m >= M) continue;
    #pragma unroll
    for (int nf=0; nf<4; ++nf){
      int ncol = wc*64 + nf*16 + (l>>4)*4;
      float4 bb = *(const float4*)&bias[ncol];
      float v0 = fmaxf(acc[mf][nf][0] + bb.x, 0.f);
      float v1 = fmaxf(acc[mf][nf][1] + bb.y, 0.f);
      float v2 = fmaxf(acc[mf][nf][2] + bb.z, 0.f);
      float v3 = fmaxf(acc[mf][nf][3] + bb.w, 0.f);
      ushort4 o;
      o.x = f2b(v0); o.y = f2b(v1); o.z = f2b(v2); o.w = f2b(v3);
      *(ushort4*)(out + (size_t)m*HID + ncol) = o;
      if (out8){
        int r = __builtin_amdgcn_cvt_pk_fp8_f32(v0, v1, 0, false);
        r = __builtin_amdgcn_cvt_pk_fp8_f32(v2, v3, r, true);
        out8[(size_t)m*(HID/4) + (ncol>>2)] = (unsigned)r;
      }
    }
  }
}

// gate GEMV over bf16 h
__global__ void k_gate(const ushort* __restrict__ h, const float* __restrict__ Wg,
                       const float* __restrict__ bg, float* __restrict__ gate){
  int w = blockIdx.x*4 + (threadIdx.x>>6);
  int lane = threadIdx.x & 63;
  if (w >= NN) return;
  uint2 u = *(const uint2*)(h + (size_t)w*HID + lane*4);
  float4 wg = *(const float4*)(Wg + lane*4);
  float d = __uint_as_float(u.x<<16)*wg.x + __uint_as_float(u.x&0xFFFF0000u)*wg.y
          + __uint_as_float(u.y<<16)*wg.z + __uint_as_float(u.y&0xFFFF0000u)*wg.w;
  #pragma unroll
  for (int o=32;o>0;o>>=1) d += __shfl_down(d, o);
  if (lane==0) gate[w] = d + bg[0];
}

__global__ void k_seg(const int* __restrict__ batch, int* __restrict__ starts){
  int b = threadIdx.x;
  if (b > NBG) return;
  int lo = 0, hi = NN;
  while (lo < hi){ int mid = (lo+hi)>>1; if (batch[mid] < b) lo = mid+1; else hi = mid; }
  starts[b] = lo;
}

__global__ void k_msum(const float* __restrict__ gate, const int* __restrict__ starts,
                       float* __restrict__ m, float* __restrict__ s){
  __shared__ float sm[256];
  int b = blockIdx.x, t = threadIdx.x;
  int st = starts[b], en = starts[b+1];
  float mx = -3.0e38f;
  for (int i = st + t; i < en; i += 256) mx = fmaxf(mx, gate[i]);
  sm[t] = mx; __syncthreads();
  for (int o=128;o>0;o>>=1){ if (t<o) sm[t]=fmaxf(sm[t],sm[t+o]); __syncthreads(); }
  float M = sm[0]; __syncthreads();
  float su = 0.f;
  for (int i = st + t; i < en; i += 256) su += expf(gate[i]-M);
  sm[t] = su; __syncthreads();
  for (int o=128;o>0;o>>=1){ if (t<o) sm[t]+=sm[t+o]; __syncthreads(); }
  if (t==0){ m[b]=M; s[b]=sm[0]; }
}

__global__ void k_pool(const ushort* __restrict__ h, const float* __restrict__ gate,
                       const int* __restrict__ batch, const float* __restrict__ m,
                       const float* __restrict__ s, float* __restrict__ pooled){
  __shared__ float sa[256];
  __shared__ int sb[256];
  int t = threadIdx.x;
  int i0 = blockIdx.x*256;
  int iend = min(i0+256, NN);
  {
    int i = i0 + t;
    if (i < NN){
      int b = batch[i];
      sb[t] = b;
      sa[t] = expf(gate[i] - m[b]) / s[b];
    }
  }
  __syncthreads();
  float acc = 0.f;
  int bcur = sb[0];
  for (int i=i0;i<iend;++i){
    int b = sb[i-i0];
    if (b != bcur){
      atomicAdd(&pooled[bcur*HID + t], acc);
      acc = 0.f; bcur = b;
    }
    acc = fmaf(sa[i-i0], b2f(h[(size_t)i*HID + t]), acc);
  }
  atomicAdd(&pooled[bcur*HID + t], acc);
}

__global__ void k_head(const float* __restrict__ pooled, const float* __restrict__ Wl1,
                       const float* __restrict__ bl1, const float* __restrict__ Wl2,
                       const float* __restrict__ bl2, float* __restrict__ out){
  __shared__ float pr[256]; __shared__ float o1[256]; __shared__ float lg[16];
  int b = blockIdx.x, t = threadIdx.x;
  pr[t] = pooled[b*HID + t];
  __syncthreads();
  float a = bl1[t];
  const float* wr = Wl1 + (size_t)t*HID;
  #pragma unroll 4
  for (int k=0;k<HID;k+=4){
    float4 w4 = *(const float4*)(wr + k);
    a += pr[k]*w4.x + pr[k+1]*w4.y + pr[k+2]*w4.z + pr[k+3]*w4.w;
  }
  o1[t] = fmaxf(a, 0.f);
  __syncthreads();
  if (t < NC){
    float a2 = bl2[t];
    const float* w2 = Wl2 + (size_t)t*HID;
    for (int k=0;k<HID;++k) a2 += o1[k]*w2[k];
    lg[t] = a2;
  }
  __syncthreads();
  if (t == 0){
    float mx = lg[0];
    for (int c2=1;c2<NC;++c2) mx = fmaxf(mx, lg[c2]);
    float se = 0.f;
    for (int c2=0;c2<NC;++c2) se += expf(lg[c2]-mx);
    float lse = mx + logf(se);
    for (int c2=0;c2<NC;++c2) out[b*NC + c2] = lg[c2] - lse;
  }
}

extern "C" void kernel_launch(void* const* d_in, const int* in_sizes, int n_in,
                              void* d_out, int out_size, void* d_ws, size_t ws_size,
                              hipStream_t stream){
  const float* x   = (const float*)d_in[0];
  const int*   ei  = (const int*)d_in[1];
  const int*   bat = (const int*)d_in[2];
  const float* W1l = (const float*)d_in[3];
  const float* b1l = (const float*)d_in[4];
  const float* W1r = (const float*)d_in[5];
  const float* W2l = (const float*)d_in[6];
  const float* b2l = (const float*)d_in[7];
  const float* W2r = (const float*)d_in[8];
  const float* W3l = (const float*)d_in[9];
  const float* b3l = (const float*)d_in[10];
  const float* W3r = (const float*)d_in[11];
  const float* Wg  = (const float*)d_in[12];
  const float* bg  = (const float*)d_in[13];
  const float* Wl1 = (const float*)d_in[14];
  const float* bl1 = (const float*)d_in[15];
  const float* Wl2 = (const float*)d_in[16];
  const float* bl2 = (const float*)d_in[17];
  const int* srcI = ei;
  const int* dstI = ei + NE;
  float* out = (float*)d_out;

  char* w = (char*)d_ws;
  auto take = [&](size_t bytes)->char*{
    char* p = w; w += (bytes + 255) & ~(size_t)255; return p;
  };
  int*      deg    = (int*)take((size_t)NN*4);
  float*    invd   = (float*)take((size_t)NN*4);
  int*      rowp   = (int*)take((size_t)NN*4);
  int*      gcur   = (int*)take(256*4);
  int*      bincnt = (int*)take(256*4);
  int*      binoff = (int*)take(256*4);
  int*      srcs   = (int*)take((size_t)NE*4);
  unsigned* ebin   = (unsigned*)take((size_t)NE*4);
  float*    gate   = (float*)take((size_t)NN*4);
  int*      starts = (int*)take(128*4);
  float*    m      = (float*)take(64*4);
  float*    s      = (float*)take(64*4);
  float*    pooled = (float*)take(64*256*4);
  ushort*   xb     = (ushort*)take((size_t)NN*FIN*2);
  ushort*   Wc1    = (ushort*)take((size_t)HID*2*FIN*2);
  ushort*   Wc2    = (ushort*)take((size_t)HID*2*HID*2);
  ushort*   Wc3    = (ushort*)take((size_t)HID*2*HID*2);
  ushort*   AG     = (ushort*)take((size_t)NN*HID*2);
  ushort*   HB     = (ushort*)take((size_t)NN*HID*2);
  unsigned* H8     = (unsigned*)take((size_t)NN*HID);

  k_init<<<(NN+255)/256, 256, 0, stream>>>(bincnt, pooled);
  k_xb<<<(NN*FIN/4+255)/256, 256, 0, stream>>>(x, xb);
  k_wcat<<<(HID*2*FIN+255)/256, 256, 0, stream>>>(W1l, W1r, FIN, Wc1);
  k_wcat<<<(HID*2*HID+255)/256, 256, 0, stream>>>(W2l, W2r, HID, Wc2);
  k_wcat<<<(HID*2*HID+255)/256, 256, 0, stream>>>(W3l, W3r, HID, Wc3);
  k_binhist<<<(NE + 4095)/4096, 256, 0, stream>>>(dstI, bincnt);
  k_scanbins<<<1, 256, 0, stream>>>(bincnt, binoff, gcur);
  k_pass1<<<(NE + 4095)/4096, 256, 0, stream>>>(srcI, dstI, gcur, ebin);
  k_pass2<<<NBINS, 256, 0, stream>>>(ebin, binoff, rowp, deg, invd, srcs);

  int gblocks = (NN + 127)/128;
  // layer 1: agg(xb) -> AG (bf16); h1 = gemm(AG, xb) -> HB (+fp8 H8 fused)
  k_agg<128><<<(NN+3)/4, 256, 0, stream>>>(xb, srcs, rowp, deg, invd, AG);
  k_gemm<<<gblocks, 512, 0, stream>>>(AG, FIN, xb, FIN, Wc1, 2*FIN, b1l, HB, H8, NN);
  // layer 2: agg8(H8) -> AG; h2 = gemm(AG, HB) -> AG (in-place, +fp8 H8 fused)
  k_agg8<<<(NN+3)/4, 256, 0, stream>>>(H8, srcs, rowp, deg, invd, AG);
  k_gemm<<<gblocks, 512, 0, stream>>>(AG, HID, HB, HID, Wc2, 2*HID, b2l, AG, H8, NN);
  // layer 3: agg8(H8) -> HB; h3 = gemm(HB, AG) -> HB (no fp8 needed)
  k_agg8<<<(NN+3)/4, 256, 0, stream>>>(H8, srcs, rowp, deg, invd, HB);
  k_gemm<<<gblocks, 512, 0, stream>>>(HB, HID, AG, HID, Wc3, 2*HID, b3l, HB, (unsigned*)nullptr, NN);

  // attention pooling over h3 = HB
  k_gate<<<(NN+3)/4, 256, 0, stream>>>(HB, Wg, bg, gate);
  k_seg<<<1, 128, 0, stream>>>(bat, starts);
  k_msum<<<NBG, 256, 0, stream>>>(gate, starts, m, s);
  k_pool<<<(NN+255)/256, 256, 0, stream>>>(HB, gate, bat, m, s, pooled);
  k_head<<<NBG, 256, 0, stream>>>(pooled, Wl1, bl1, Wl2, bl2, out);
}

// Round 10
// 487.137 us; speedup vs baseline: 4.4420x; 1.1092x over previous
//
#include <hip/hip_runtime.h>

#define NN 50000
#define FIN 128
#define HID 256
#define NE 1600000
#define NBG 64
#define NC 10
#define NBINS ((NN + 255) >> 8)   // 196

typedef short bf16x8 __attribute__((ext_vector_type(8)));
typedef float f32x4 __attribute__((ext_vector_type(4)));
typedef float floatx2 __attribute__((ext_vector_type(2)));

static __device__ __forceinline__ ushort f2b(float f){
  unsigned u = __float_as_uint(f);
  unsigned r = (u + 0x7FFFu + ((u >> 16) & 1u)) >> 16;
  return (ushort)r;
}
static __device__ __forceinline__ float b2f(ushort u){
  return __uint_as_float(((unsigned)u) << 16);
}

__global__ void k_init(int* __restrict__ bincnt, float* __restrict__ pooled){
  int i = blockIdx.x*256 + threadIdx.x;
  if (i < 256) bincnt[i] = 0;
  if (i < NBG*HID) pooled[i] = 0.f;
}

// x fp32 [NN][128] -> bf16
__global__ void k_xb(const float* __restrict__ x, ushort* __restrict__ xb){
  int i = blockIdx.x*256 + threadIdx.x;           // element quad index
  if (i >= NN*FIN/4) return;
  float4 v = *(const float4*)(x + (size_t)i*4);
  ushort4 o; o.x=f2b(v.x); o.y=f2b(v.y); o.z=f2b(v.z); o.w=f2b(v.w);
  *(ushort4*)(xb + (size_t)i*4) = o;
}

// Wcat bf16 [256][2F] = [Wl | Wr]
__global__ void k_wcat(const float* __restrict__ Wl, const float* __restrict__ Wr,
                       int F, ushort* __restrict__ Wc){
  int F2 = 2*F;
  int i = blockIdx.x*256 + threadIdx.x;
  if (i >= HID*F2) return;
  int n = i / F2, k = i % F2;
  float v = (k < F) ? Wl[(size_t)n*F + k] : Wr[(size_t)n*F + (k-F)];
  Wc[i] = f2b(v);
}

// per-block LDS histogram of 196 dst-bins -> one global atomic per bin per block
__global__ __launch_bounds__(256) void k_binhist(const int* __restrict__ dst,
                                                 int* __restrict__ bincnt){
  __shared__ int lh[NBINS];
  int t = threadIdx.x;
  for (int i=t; i<NBINS; i+=256) lh[i]=0;
  __syncthreads();
  long e0 = (long)blockIdx.x * 4096;
  #pragma unroll
  for (int k=0;k<16;++k){
    long e = e0 + k*256 + t;
    if (e < NE) atomicAdd(&lh[dst[e] >> 8], 1);
  }
  __syncthreads();
  for (int i=t; i<NBINS; i+=256)
    if (lh[i]) atomicAdd(&bincnt[i], lh[i]);
}

// one-block exclusive scan of bin counts -> binoff[0..NBINS], seeds gcur
__global__ void k_scanbins(const int* __restrict__ bincnt, int* __restrict__ binoff,
                           int* __restrict__ gcur){
  __shared__ int buf[2][256];
  int t = threadIdx.x;
  int v = (t < NBINS) ? bincnt[t] : 0;
  buf[0][t] = v; __syncthreads();
  int pp = 0;
  for (int off=1; off<256; off<<=1){
    int nv = buf[pp][t];
    if (t >= off) nv += buf[pp][t-off];
    buf[pp^1][t] = nv; __syncthreads(); pp ^= 1;
  }
  int excl = buf[pp][t] - v;
  if (t < NBINS){ binoff[t] = excl; gcur[t] = excl; }
  if (t == 0) binoff[NBINS] = NE;
}

// pass 1: partition edges into 196 dst-bins; packed word = (dst&255)<<24 | src
__global__ __launch_bounds__(256) void k_pass1(const int* __restrict__ src,
                                               const int* __restrict__ dst,
                                               int* __restrict__ gcur,
                                               unsigned* __restrict__ ebin){
  __shared__ int lhist[NBINS];
  __shared__ int lbase[NBINS];
  int t = threadIdx.x;
  long e0 = (long)blockIdx.x * 4096;
  for (int i=t; i<NBINS; i+=256) lhist[i]=0;
  __syncthreads();
  unsigned pk[16]; int bn[16]; int rk[16];
  #pragma unroll
  for (int k=0;k<16;++k){
    long e = e0 + k*256 + t;
    bn[k] = -1;
    if (e < NE){
      int d = dst[e];
      int s = src[e];
      bn[k] = d >> 8;
      pk[k] = (unsigned)s | ((unsigned)(d & 255) << 24);
      rk[k] = atomicAdd(&lhist[bn[k]], 1);
    }
  }
  __syncthreads();
  for (int i=t; i<NBINS; i+=256)
    lbase[i] = atomicAdd(&gcur[i], lhist[i]);
  __syncthreads();
  #pragma unroll
  for (int k=0;k<16;++k)
    if (bn[k] >= 0) ebin[lbase[bn[k]] + rk[k]] = pk[k];
}

// pass 2: per bin, derive per-dst deg/rowp/invd (LDS hist + scan; CSR is
// dst-ordered and bins are dst-contiguous), then scatter srcs via LDS cursors.
__global__ __launch_bounds__(256) void k_pass2(const unsigned* __restrict__ ebin,
                                               const int* __restrict__ binoff,
                                               int* __restrict__ rowp,
                                               int* __restrict__ deg,
                                               float* __restrict__ invd,
                                               int* __restrict__ srcs){
  __shared__ int cnt[256];
  __shared__ int buf[2][256];
  __shared__ int cur[256];
  int b = blockIdx.x, t = threadIdx.x;
  int d0 = b << 8;
  int st = binoff[b], en = binoff[b+1];
  cnt[t] = 0;
  __syncthreads();
  for (int i = st + t; i < en; i += 256)
    atomicAdd(&cnt[ebin[i] >> 24], 1);
  __syncthreads();
  int v = cnt[t];
  buf[0][t] = v; __syncthreads();
  int pp = 0;
  for (int off=1; off<256; off<<=1){
    int nv = buf[pp][t];
    if (t >= off) nv += buf[pp][t-off];
    buf[pp^1][t] = nv; __syncthreads(); pp ^= 1;
  }
  int excl = st + buf[pp][t] - v;
  if (d0 + t < NN){
    rowp[d0 + t] = excl;
    deg[d0 + t] = v;
    invd[d0 + t] = 1.0f / (float)max(v, 1);
  }
  cur[t] = excl;
  __syncthreads();
  for (int i = st + t; i < en; i += 256){
    unsigned p = ebin[i];
    int doff = p >> 24;
    int pos = atomicAdd(&cur[doff], 1);
    srcs[pos] = (int)(p & 0xFFFFFFu);
  }
}

// bf16 gather agg (layer 1, F=128): 16B/lane, LPR=F/8 lanes/row, 4 rows in flight/group
template<int F>
__global__ void k_agg(const ushort* __restrict__ x, const int* __restrict__ srcs,
                      const int* __restrict__ rowp, const int* __restrict__ deg,
                      const float* __restrict__ invd, ushort* __restrict__ out){
  constexpr int LPR = F/8;        // lanes per row
  constexpr int EPI = 64/LPR;     // edge slots per wave-iter
  int w = blockIdx.x*4 + (threadIdx.x>>6);
  int lane = threadIdx.x & 63;
  if (w >= NN) return;
  int st = rowp[w], d = deg[w];
  int grp = lane / LPR;
  int fo  = (lane % LPR)*8;       // feature offset (elements)
  float acc[8];
  #pragma unroll
  for (int v=0;v<8;++v) acc[v]=0.f;

  auto accum = [&](uint4 u){
    acc[0] += __uint_as_float(u.x<<16); acc[1] += __uint_as_float(u.x & 0xFFFF0000u);
    acc[2] += __uint_as_float(u.y<<16); acc[3] += __uint_as_float(u.y & 0xFFFF0000u);
    acc[4] += __uint_as_float(u.z<<16); acc[5] += __uint_as_float(u.z & 0xFFFF0000u);
    acc[6] += __uint_as_float(u.w<<16); acc[7] += __uint_as_float(u.w & 0xFFFF0000u);
  };

  int j = 0;
  for (; j + 4*EPI <= d; j += 4*EPI){
    int i0 = srcs[st + j + grp];
    int i1 = srcs[st + j + EPI + grp];
    int i2 = srcs[st + j + 2*EPI + grp];
    int i3 = srcs[st + j + 3*EPI + grp];
    uint4 u0 = *(const uint4*)(x + (size_t)i0*F + fo);
    uint4 u1 = *(const uint4*)(x + (size_t)i1*F + fo);
    uint4 u2 = *(const uint4*)(x + (size_t)i2*F + fo);
    uint4 u3 = *(const uint4*)(x + (size_t)i3*F + fo);
    accum(u0); accum(u1); accum(u2); accum(u3);
  }
  for (; j < d; j += EPI){
    int jj = j + grp;
    if (jj < d){
      int i0 = srcs[st + jj];
      uint4 u0 = *(const uint4*)(x + (size_t)i0*F + fo);
      accum(u0);
    }
  }
  #pragma unroll
  for (int off = LPR; off < 64; off <<= 1){
    #pragma unroll
    for (int v=0;v<8;++v) acc[v] += __shfl_xor(acc[v], off);
  }
  if (grp == 0){
    float sc = invd[w];
    uint4 o;
    o.x = (unsigned)f2b(acc[0]*sc) | ((unsigned)f2b(acc[1]*sc)<<16);
    o.y = (unsigned)f2b(acc[2]*sc) | ((unsigned)f2b(acc[3]*sc)<<16);
    o.z = (unsigned)f2b(acc[4]*sc) | ((unsigned)f2b(acc[5]*sc)<<16);
    o.w = (unsigned)f2b(acc[6]*sc) | ((unsigned)f2b(acc[7]*sc)<<16);
    *(uint4*)(out + (size_t)w*F + fo) = o;
  }
}

// fp8 gather agg (layers 2,3, F=256): row = 256B = 16 lanes x 16B (16 fp8 each),
// 4 edge groups/wave, 4 rows in flight per group; fp32 accumulate; bf16 out.
__global__ void k_agg8(const unsigned* __restrict__ x8, const int* __restrict__ srcs,
                       const int* __restrict__ rowp, const int* __restrict__ deg,
                       const float* __restrict__ invd, ushort* __restrict__ out){
  int w = blockIdx.x*4 + (threadIdx.x>>6);
  int lane = threadIdx.x & 63;
  if (w >= NN) return;
  int st = rowp[w], d = deg[w];
  int grp = lane >> 4;            // 0..3
  int sub = lane & 15;            // 16B chunk within row
  const uint4* xr = (const uint4*)x8;
  float acc[16];
  #pragma unroll
  for (int v=0;v<16;++v) acc[v]=0.f;

  auto accum = [&](uint4 u){
    floatx2 p;
    p = __builtin_amdgcn_cvt_pk_f32_fp8(u.x, false); acc[0]+=p.x;  acc[1]+=p.y;
    p = __builtin_amdgcn_cvt_pk_f32_fp8(u.x, true);  acc[2]+=p.x;  acc[3]+=p.y;
    p = __builtin_amdgcn_cvt_pk_f32_fp8(u.y, false); acc[4]+=p.x;  acc[5]+=p.y;
    p = __builtin_amdgcn_cvt_pk_f32_fp8(u.y, true);  acc[6]+=p.x;  acc[7]+=p.y;
    p = __builtin_amdgcn_cvt_pk_f32_fp8(u.z, false); acc[8]+=p.x;  acc[9]+=p.y;
    p = __builtin_amdgcn_cvt_pk_f32_fp8(u.z, true);  acc[10]+=p.x; acc[11]+=p.y;
    p = __builtin_amdgcn_cvt_pk_f32_fp8(u.w, false); acc[12]+=p.x; acc[13]+=p.y;
    p = __builtin_amdgcn_cvt_pk_f32_fp8(u.w, true);  acc[14]+=p.x; acc[15]+=p.y;
  };

  int j = 0;
  for (; j + 16 <= d; j += 16){
    int i0 = srcs[st + j + grp];
    int i1 = srcs[st + j + 4 + grp];
    int i2 = srcs[st + j + 8 + grp];
    int i3 = srcs[st + j + 12 + grp];
    uint4 u0 = xr[(size_t)i0*16 + sub];
    uint4 u1 = xr[(size_t)i1*16 + sub];
    uint4 u2 = xr[(size_t)i2*16 + sub];
    uint4 u3 = xr[(size_t)i3*16 + sub];
    accum(u0); accum(u1); accum(u2); accum(u3);
  }
  for (; j < d; j += 4){
    int jj = j + grp;
    if (jj < d){
      int i0 = srcs[st + jj];
      uint4 u0 = xr[(size_t)i0*16 + sub];
      accum(u0);
    }
  }
  #pragma unroll
  for (int off = 16; off < 64; off <<= 1){
    #pragma unroll
    for (int v=0;v<16;++v) acc[v] += __shfl_xor(acc[v], off);
  }
  if (grp == 0){
    float sc = invd[w];
    uint4 o1, o2;
    o1.x = (unsigned)f2b(acc[0]*sc)  | ((unsigned)f2b(acc[1]*sc)<<16);
    o1.y = (unsigned)f2b(acc[2]*sc)  | ((unsigned)f2b(acc[3]*sc)<<16);
    o1.z = (unsigned)f2b(acc[4]*sc)  | ((unsigned)f2b(acc[5]*sc)<<16);
    o1.w = (unsigned)f2b(acc[6]*sc)  | ((unsigned)f2b(acc[7]*sc)<<16);
    o2.x = (unsigned)f2b(acc[8]*sc)  | ((unsigned)f2b(acc[9]*sc)<<16);
    o2.y = (unsigned)f2b(acc[10]*sc) | ((unsigned)f2b(acc[11]*sc)<<16);
    o2.z = (unsigned)f2b(acc[12]*sc) | ((unsigned)f2b(acc[13]*sc)<<16);
    o2.w = (unsigned)f2b(acc[14]*sc) | ((unsigned)f2b(acc[15]*sc)<<16);
    ushort* op = out + (size_t)w*HID + sub*16;
    *(uint4*)op = o1;
    *(uint4*)(op + 8) = o2;
  }
}

// MFMA GEMM: out[m][n] = relu( sum_k [A1|A2][m][k] * Wc[n][k] + bias[n] ), bf16 in,
// bf16 out (+ optional fused fp8 e4m3 copy). BM=128, BN=256, BK=64, 8 waves.
#define LDT 72
__global__ __launch_bounds__(512) void k_gemm(
    const ushort* __restrict__ A1, int ldA1,
    const ushort* __restrict__ A2, int ldA2,
    const ushort* __restrict__ Wc, int F2,
    const float* __restrict__ bias, ushort* __restrict__ out,
    unsigned* __restrict__ out8, int M)
{
  __shared__ ushort As[128*LDT];
  __shared__ ushort Bs[256*LDT];
  int t = threadIdx.x;
  int l = t & 63;
  int wv = t >> 6;
  int wr = wv >> 2, wc = wv & 3;
  int m0 = blockIdx.x * 128;
  int F = F2 >> 1;
  f32x4 acc[4][4];
  #pragma unroll
  for (int a=0;a<4;++a)
  #pragma unroll
  for (int b=0;b<4;++b) acc[a][b] = (f32x4){0.f,0.f,0.f,0.f};

  int nsteps = F2/64;
  for (int s=0; s<nsteps; ++s){
    int kk = s*64;
    const ushort* src; int ld, kkl;
    if (kk < F){ src = A1; ld = ldA1; kkl = kk; }
    else       { src = A2; ld = ldA2; kkl = kk - F; }
    uint4 av[2];
    int arow[2], ack[2];
    #pragma unroll
    for (int i=0;i<2;++i){
      int c = t*2 + i;
      arow[i] = c >> 3; ack[i] = c & 7;
      int m = m0 + arow[i];
      av[i] = make_uint4(0u,0u,0u,0u);
      if (m < M) av[i] = *(const uint4*)(src + (size_t)m*ld + kkl + ack[i]*8);
    }
    uint4 bv[4];
    int brow[4], bck[4];
    #pragma unroll
    for (int i=0;i<4;++i){
      int c = t*4 + i;
      brow[i] = c >> 3; bck[i] = c & 7;
      bv[i] = *(const uint4*)(Wc + (size_t)brow[i]*F2 + kk + bck[i]*8);
    }
    #pragma unroll
    for (int i=0;i<2;++i)
      *(uint4*)&As[arow[i]*LDT + ack[i]*8] = av[i];
    #pragma unroll
    for (int i=0;i<4;++i)
      *(uint4*)&Bs[brow[i]*LDT + bck[i]*8] = bv[i];
    __syncthreads();

    #pragma unroll
    for (int ks=0; ks<2; ++ks){
      bf16x8 af[4], bf[4];
      int ko = ks*32 + (l>>4)*8;
      #pragma unroll
      for (int mf=0; mf<4; ++mf)
        af[mf] = *(bf16x8*)&As[(wr*64 + mf*16 + (l&15))*LDT + ko];
      #pragma unroll
      for (int nf=0; nf<4; ++nf)
        bf[nf] = *(bf16x8*)&Bs[(wc*64 + nf*16 + (l&15))*LDT + ko];
      #pragma unroll
      for (int mf=0; mf<4; ++mf)
      #pragma unroll
      for (int nf=0; nf<4; ++nf)
        acc[mf][nf] = __builtin_amdgcn_mfma_f32_16x16x32_bf16(bf[nf], af[mf], acc[mf][nf], 0, 0, 0);
    }
    __syncthreads();
  }

  #pragma unroll
  for (int mf=0; mf<4; ++mf){
    int m = m0 + wr*64 + mf*16 + (l&15);
    if (m >= M) continue;
    #pragma unroll
    for (int nf=0; nf<4; ++nf){
      int ncol = wc*64 + nf*16 + (l>>4)*4;
      float4 bb = *(const float4*)&bias[ncol];
      float v0 = fmaxf(acc[mf][nf][0] + bb.x, 0.f);
      float v1 = fmaxf(acc[mf][nf][1] + bb.y, 0.f);
      float v2 = fmaxf(acc[mf][nf][2] + bb.z, 0.f);
      float v3 = fmaxf(acc[mf][nf][3] + bb.w, 0.f);
      ushort4 o;
      o.x = f2b(v0); o.y = f2b(v1); o.z = f2b(v2); o.w = f2b(v3);
      *(ushort4*)(out + (size_t)m*HID + ncol) = o;
      if (out8){
        int r = __builtin_amdgcn_cvt_pk_fp8_f32(v0, v1, 0, false);
        r = __builtin_amdgcn_cvt_pk_fp8_f32(v2, v3, r, true);
        out8[(size_t)m*(HID/4) + (ncol>>2)] = (unsigned)r;
      }
    }
  }
}

// gate GEMV over bf16 h
__global__ void k_gate(const ushort* __restrict__ h, const float* __restrict__ Wg,
                       const float* __restrict__ bg, float* __restrict__ gate){
  int w = blockIdx.x*4 + (threadIdx.x>>6);
  int lane = threadIdx.x & 63;
  if (w >= NN) return;
  uint2 u = *(const uint2*)(h + (size_t)w*HID + lane*4);
  float4 wg = *(const float4*)(Wg + lane*4);
  float d = __uint_as_float(u.x<<16)*wg.x + __uint_as_float(u.x&0xFFFF0000u)*wg.y
          + __uint_as_float(u.y<<16)*wg.z + __uint_as_float(u.y&0xFFFF0000u)*wg.w;
  #pragma unroll
  for (int o=32;o>0;o>>=1) d += __shfl_down(d, o);
  if (lane==0) gate[w] = d + bg[0];
}

__global__ void k_seg(const int* __restrict__ batch, int* __restrict__ starts){
  int b = threadIdx.x;
  if (b > NBG) return;
  int lo = 0, hi = NN;
  while (lo < hi){ int mid = (lo+hi)>>1; if (batch[mid] < b) lo = mid+1; else hi = mid; }
  starts[b] = lo;
}

__global__ void k_msum(const float* __restrict__ gate, const int* __restrict__ starts,
                       float* __restrict__ m, float* __restrict__ s){
  __shared__ float sm[256];
  int b = blockIdx.x, t = threadIdx.x;
  int st = starts[b], en = starts[b+1];
  float mx = -3.0e38f;
  for (int i = st + t; i < en; i += 256) mx = fmaxf(mx, gate[i]);
  sm[t] = mx; __syncthreads();
  for (int o=128;o>0;o>>=1){ if (t<o) sm[t]=fmaxf(sm[t],sm[t+o]); __syncthreads(); }
  float M = sm[0]; __syncthreads();
  float su = 0.f;
  for (int i = st + t; i < en; i += 256) su += expf(gate[i]-M);
  sm[t] = su; __syncthreads();
  for (int o=128;o>0;o>>=1){ if (t<o) sm[t]+=sm[t+o]; __syncthreads(); }
  if (t==0){ m[b]=M; s[b]=sm[0]; }
}

// pooling: 128 nodes/block, 4 node-streams x 64 lanes, lane owns a feature quad
// (ushort4 = 8B loads). Coefficients precomputed in LDS; register accumulate per
// stream; atomics only at segment boundaries / stream end (sorted batch).
__global__ __launch_bounds__(256) void k_pool(const ushort* __restrict__ h,
                                              const float* __restrict__ gate,
                                              const int* __restrict__ batch,
                                              const float* __restrict__ m,
                                              const float* __restrict__ s,
                                              float* __restrict__ pooled){
  __shared__ float sa[128];
  __shared__ int sb[128];
  int t = threadIdx.x;
  int i0 = blockIdx.x*128;
  if (t < 128){
    int i = i0 + t;
    if (i < NN){
      int b = batch[i];
      sb[t] = b;
      sa[t] = expf(gate[i] - m[b]) / s[b];
    } else sb[t] = -1;
  }
  __syncthreads();
  int strm = t >> 6;            // 0..3
  int f = (t & 63) * 4;         // feature quad
  int j0 = strm * 32;
  float a0=0.f, a1=0.f, a2=0.f, a3=0.f;
  int bcur = sb[j0];
  for (int j = j0; j < j0 + 32; ++j){
    int i = i0 + j;
    if (i >= NN) break;
    int b = sb[j];
    if (b != bcur){
      if (bcur >= 0){
        atomicAdd(&pooled[bcur*HID + f + 0], a0);
        atomicAdd(&pooled[bcur*HID + f + 1], a1);
        atomicAdd(&pooled[bcur*HID + f + 2], a2);
        atomicAdd(&pooled[bcur*HID + f + 3], a3);
      }
      a0=a1=a2=a3=0.f; bcur = b;
    }
    ushort4 hv = *(const ushort4*)(h + (size_t)i*HID + f);
    float c = sa[j];
    a0 = fmaf(c, b2f(hv.x), a0);
    a1 = fmaf(c, b2f(hv.y), a1);
    a2 = fmaf(c, b2f(hv.z), a2);
    a3 = fmaf(c, b2f(hv.w), a3);
  }
  if (bcur >= 0){
    atomicAdd(&pooled[bcur*HID + f + 0], a0);
    atomicAdd(&pooled[bcur*HID + f + 1], a1);
    atomicAdd(&pooled[bcur*HID + f + 2], a2);
    atomicAdd(&pooled[bcur*HID + f + 3], a3);
  }
}

__global__ void k_head(const float* __restrict__ pooled, const float* __restrict__ Wl1,
                       const float* __restrict__ bl1, const float* __restrict__ Wl2,
                       const float* __restrict__ bl2, float* __restrict__ out){
  __shared__ float pr[256]; __shared__ float o1[256]; __shared__ float lg[16];
  int b = blockIdx.x, t = threadIdx.x;
  pr[t] = pooled[b*HID + t];
  __syncthreads();
  float a = bl1[t];
  const float* wr = Wl1 + (size_t)t*HID;
  #pragma unroll 4
  for (int k=0;k<HID;k+=4){
    float4 w4 = *(const float4*)(wr + k);
    a += pr[k]*w4.x + pr[k+1]*w4.y + pr[k+2]*w4.z + pr[k+3]*w4.w;
  }
  o1[t] = fmaxf(a, 0.f);
  __syncthreads();
  if (t < NC){
    float a2 = bl2[t];
    const float* w2 = Wl2 + (size_t)t*HID;
    for (int k=0;k<HID;++k) a2 += o1[k]*w2[k];
    lg[t] = a2;
  }
  __syncthreads();
  if (t == 0){
    float mx = lg[0];
    for (int c2=1;c2<NC;++c2) mx = fmaxf(mx, lg[c2]);
    float se = 0.f;
    for (int c2=0;c2<NC;++c2) se += expf(lg[c2]-mx);
    float lse = mx + logf(se);
    for (int c2=0;c2<NC;++c2) out[b*NC + c2] = lg[c2] - lse;
  }
}

extern "C" void kernel_launch(void* const* d_in, const int* in_sizes, int n_in,
                              void* d_out, int out_size, void* d_ws, size_t ws_size,
                              hipStream_t stream){
  const float* x   = (const float*)d_in[0];
  const int*   ei  = (const int*)d_in[1];
  const int*   bat = (const int*)d_in[2];
  const float* W1l = (const float*)d_in[3];
  const float* b1l = (const float*)d_in[4];
  const float* W1r = (const float*)d_in[5];
  const float* W2l = (const float*)d_in[6];
  const float* b2l = (const float*)d_in[7];
  const float* W2r = (const float*)d_in[8];
  const float* W3l = (const float*)d_in[9];
  const float* b3l = (const float*)d_in[10];
  const float* W3r = (const float*)d_in[11];
  const float* Wg  = (const float*)d_in[12];
  const float* bg  = (const float*)d_in[13];
  const float* Wl1 = (const float*)d_in[14];
  const float* bl1 = (const float*)d_in[15];
  const float* Wl2 = (const float*)d_in[16];
  const float* bl2 = (const float*)d_in[17];
  const int* srcI = ei;
  const int* dstI = ei + NE;
  float* out = (float*)d_out;

  char* w = (char*)d_ws;
  auto take = [&](size_t bytes)->char*{
    char* p = w; w += (bytes + 255) & ~(size_t)255; return p;
  };
  int*      deg    = (int*)take((size_t)NN*4);
  float*    invd   = (float*)take((size_t)NN*4);
  int*      rowp   = (int*)take((size_t)NN*4);
  int*      gcur   = (int*)take(256*4);
  int*      bincnt = (int*)take(256*4);
  int*      binoff = (int*)take(256*4);
  int*      srcs   = (int*)take((size_t)NE*4);
  unsigned* ebin   = (unsigned*)take((size_t)NE*4);
  float*    gate   = (float*)take((size_t)NN*4);
  int*      starts = (int*)take(128*4);
  float*    m      = (float*)take(64*4);
  float*    s      = (float*)take(64*4);
  float*    pooled = (float*)take(64*256*4);
  ushort*   xb     = (ushort*)take((size_t)NN*FIN*2);
  ushort*   Wc1    = (ushort*)take((size_t)HID*2*FIN*2);
  ushort*   Wc2    = (ushort*)take((size_t)HID*2*HID*2);
  ushort*   Wc3    = (ushort*)take((size_t)HID*2*HID*2);
  ushort*   AG     = (ushort*)take((size_t)NN*HID*2);
  ushort*   HB     = (ushort*)take((size_t)NN*HID*2);
  unsigned* H8     = (unsigned*)take((size_t)NN*HID);

  k_init<<<(NN+255)/256, 256, 0, stream>>>(bincnt, pooled);
  k_xb<<<(NN*FIN/4+255)/256, 256, 0, stream>>>(x, xb);
  k_wcat<<<(HID*2*FIN+255)/256, 256, 0, stream>>>(W1l, W1r, FIN, Wc1);
  k_wcat<<<(HID*2*HID+255)/256, 256, 0, stream>>>(W2l, W2r, HID, Wc2);
  k_wcat<<<(HID*2*HID+255)/256, 256, 0, stream>>>(W3l, W3r, HID, Wc3);
  k_binhist<<<(NE + 4095)/4096, 256, 0, stream>>>(dstI, bincnt);
  k_scanbins<<<1, 256, 0, stream>>>(bincnt, binoff, gcur);
  k_pass1<<<(NE + 4095)/4096, 256, 0, stream>>>(srcI, dstI, gcur, ebin);
  k_pass2<<<NBINS, 256, 0, stream>>>(ebin, binoff, rowp, deg, invd, srcs);

  int gblocks = (NN + 127)/128;
  // layer 1: agg(xb) -> AG (bf16); h1 = gemm(AG, xb) -> HB (+fp8 H8 fused)
  k_agg<128><<<(NN+3)/4, 256, 0, stream>>>(xb, srcs, rowp, deg, invd, AG);
  k_gemm<<<gblocks, 512, 0, stream>>>(AG, FIN, xb, FIN, Wc1, 2*FIN, b1l, HB, H8, NN);
  // layer 2: agg8(H8) -> AG; h2 = gemm(AG, HB) -> AG (in-place, +fp8 H8 fused)
  k_agg8<<<(NN+3)/4, 256, 0, stream>>>(H8, srcs, rowp, deg, invd, AG);
  k_gemm<<<gblocks, 512, 0, stream>>>(AG, HID, HB, HID, Wc2, 2*HID, b2l, AG, H8, NN);
  // layer 3: agg8(H8) -> HB; h3 = gemm(HB, AG) -> HB (no fp8 needed)
  k_agg8<<<(NN+3)/4, 256, 0, stream>>>(H8, srcs, rowp, deg, invd, HB);
  k_gemm<<<gblocks, 512, 0, stream>>>(HB, HID, AG, HID, Wc3, 2*HID, b3l, HB, (unsigned*)nullptr, NN);

  // attention pooling over h3 = HB
  k_gate<<<(NN+3)/4, 256, 0, stream>>>(HB, Wg, bg, gate);
  k_seg<<<1, 128, 0, stream>>>(bat, starts);
  k_msum<<<NBG, 256, 0, stream>>>(gate, starts, m, s);
  k_pool<<<(NN+127)/128, 256, 0, stream>>>(HB, gate, bat, m, s, pooled);
  k_head<<<NBG, 256, 0, stream>>>(pooled, Wl1, bl1, Wl2, bl2, out);
}

// Round 12
// 473.538 us; speedup vs baseline: 4.5695x; 1.0287x over previous
//
#include <hip/hip_runtime.h>

#define NN 50000
#define FIN 128
#define HID 256
#define NE 1600000
#define NBG 64
#define NC 10
#define NBINS ((NN + 255) >> 8)   // 196

typedef short bf16x8 __attribute__((ext_vector_type(8)));
typedef float f32x4 __attribute__((ext_vector_type(4)));
typedef float floatx2 __attribute__((ext_vector_type(2)));

static __device__ __forceinline__ ushort f2b(float f){
  unsigned u = __float_as_uint(f);
  unsigned r = (u + 0x7FFFu + ((u >> 16) & 1u)) >> 16;
  return (ushort)r;
}
static __device__ __forceinline__ float b2f(ushort u){
  return __uint_as_float(((unsigned)u) << 16);
}

__global__ void k_init(int* __restrict__ bincnt, float* __restrict__ pooled){
  int i = blockIdx.x*256 + threadIdx.x;
  if (i < 256) bincnt[i] = 0;
  if (i < NBG*HID) pooled[i] = 0.f;
}

// x fp32 [NN][128] -> bf16 xb AND fp8 e4m3 X8
__global__ void k_xb(const float* __restrict__ x, ushort* __restrict__ xb,
                     unsigned* __restrict__ x8){
  int i = blockIdx.x*256 + threadIdx.x;           // 8 elems per thread
  if (i >= NN*FIN/8) return;
  float4 a = *(const float4*)(x + (size_t)i*8);
  float4 b = *(const float4*)(x + (size_t)i*8 + 4);
  ushort4 o1, o2;
  o1.x=f2b(a.x); o1.y=f2b(a.y); o1.z=f2b(a.z); o1.w=f2b(a.w);
  o2.x=f2b(b.x); o2.y=f2b(b.y); o2.z=f2b(b.z); o2.w=f2b(b.w);
  *(ushort4*)(xb + (size_t)i*8) = o1;
  *(ushort4*)(xb + (size_t)i*8 + 4) = o2;
  int r0 = __builtin_amdgcn_cvt_pk_fp8_f32(a.x, a.y, 0, false);
  r0 = __builtin_amdgcn_cvt_pk_fp8_f32(a.z, a.w, r0, true);
  int r1 = __builtin_amdgcn_cvt_pk_fp8_f32(b.x, b.y, 0, false);
  r1 = __builtin_amdgcn_cvt_pk_fp8_f32(b.z, b.w, r1, true);
  uint2 o; o.x = (unsigned)r0; o.y = (unsigned)r1;
  *(uint2*)(x8 + (size_t)i*2) = o;
}

// Wcat bf16 [256][2F] = [Wl | Wr]
__global__ void k_wcat(const float* __restrict__ Wl, const float* __restrict__ Wr,
                       int F, ushort* __restrict__ Wc){
  int F2 = 2*F;
  int i = blockIdx.x*256 + threadIdx.x;
  if (i >= HID*F2) return;
  int n = i / F2, k = i % F2;
  float v = (k < F) ? Wl[(size_t)n*F + k] : Wr[(size_t)n*F + (k-F)];
  Wc[i] = f2b(v);
}

// per-block LDS histogram of 196 dst-bins -> one global atomic per bin per block
__global__ __launch_bounds__(256) void k_binhist(const int* __restrict__ dst,
                                                 int* __restrict__ bincnt){
  __shared__ int lh[NBINS];
  int t = threadIdx.x;
  for (int i=t; i<NBINS; i+=256) lh[i]=0;
  __syncthreads();
  long e0 = (long)blockIdx.x * 4096;
  #pragma unroll
  for (int k=0;k<16;++k){
    long e = e0 + k*256 + t;
    if (e < NE) atomicAdd(&lh[dst[e] >> 8], 1);
  }
  __syncthreads();
  for (int i=t; i<NBINS; i+=256)
    if (lh[i]) atomicAdd(&bincnt[i], lh[i]);
}

// one-block exclusive scan of bin counts -> binoff[0..NBINS], seeds gcur
__global__ void k_scanbins(const int* __restrict__ bincnt, int* __restrict__ binoff,
                           int* __restrict__ gcur){
  __shared__ int buf[2][256];
  int t = threadIdx.x;
  int v = (t < NBINS) ? bincnt[t] : 0;
  buf[0][t] = v; __syncthreads();
  int pp = 0;
  for (int off=1; off<256; off<<=1){
    int nv = buf[pp][t];
    if (t >= off) nv += buf[pp][t-off];
    buf[pp^1][t] = nv; __syncthreads(); pp ^= 1;
  }
  int excl = buf[pp][t] - v;
  if (t < NBINS){ binoff[t] = excl; gcur[t] = excl; }
  if (t == 0) binoff[NBINS] = NE;
}

// pass 1: partition edges into 196 dst-bins; packed word = (dst&255)<<24 | src
__global__ __launch_bounds__(256) void k_pass1(const int* __restrict__ src,
                                               const int* __restrict__ dst,
                                               int* __restrict__ gcur,
                                               unsigned* __restrict__ ebin){
  __shared__ int lhist[NBINS];
  __shared__ int lbase[NBINS];
  int t = threadIdx.x;
  long e0 = (long)blockIdx.x * 4096;
  for (int i=t; i<NBINS; i+=256) lhist[i]=0;
  __syncthreads();
  unsigned pk[16]; int bn[16]; int rk[16];
  #pragma unroll
  for (int k=0;k<16;++k){
    long e = e0 + k*256 + t;
    bn[k] = -1;
    if (e < NE){
      int d = dst[e];
      int s = src[e];
      bn[k] = d >> 8;
      pk[k] = (unsigned)s | ((unsigned)(d & 255) << 24);
      rk[k] = atomicAdd(&lhist[bn[k]], 1);
    }
  }
  __syncthreads();
  for (int i=t; i<NBINS; i+=256)
    lbase[i] = atomicAdd(&gcur[i], lhist[i]);
  __syncthreads();
  #pragma unroll
  for (int k=0;k<16;++k)
    if (bn[k] >= 0) ebin[lbase[bn[k]] + rk[k]] = pk[k];
}

// pass 2: per bin, derive per-dst deg/rowp/invd (LDS hist + scan), scatter srcs.
__global__ __launch_bounds__(256) void k_pass2(const unsigned* __restrict__ ebin,
                                               const int* __restrict__ binoff,
                                               int* __restrict__ rowp,
                                               int* __restrict__ deg,
                                               float* __restrict__ invd,
                                               int* __restrict__ srcs){
  __shared__ int cnt[256];
  __shared__ int buf[2][256];
  __shared__ int cur[256];
  int b = blockIdx.x, t = threadIdx.x;
  int d0 = b << 8;
  int st = binoff[b], en = binoff[b+1];
  cnt[t] = 0;
  __syncthreads();
  for (int i = st + t; i < en; i += 256)
    atomicAdd(&cnt[ebin[i] >> 24], 1);
  __syncthreads();
  int v = cnt[t];
  buf[0][t] = v; __syncthreads();
  int pp = 0;
  for (int off=1; off<256; off<<=1){
    int nv = buf[pp][t];
    if (t >= off) nv += buf[pp][t-off];
    buf[pp^1][t] = nv; __syncthreads(); pp ^= 1;
  }
  int excl = st + buf[pp][t] - v;
  if (d0 + t < NN){
    rowp[d0 + t] = excl;
    deg[d0 + t] = v;
    invd[d0 + t] = 1.0f / (float)max(v, 1);
  }
  cur[t] = excl;
  __syncthreads();
  for (int i = st + t; i < en; i += 256){
    unsigned p = ebin[i];
    int doff = p >> 24;
    int pos = atomicAdd(&cur[doff], 1);
    srcs[pos] = (int)(p & 0xFFFFFFu);
  }
}

// fp8 gather agg: row = F bytes = LPR lanes x 16B; EPG=64/LPR edges/wave-iter,
// 4-deep unroll; packed floatx2 accumulate; bf16 out (stride F elems).
template<int F>
__global__ void k_agg8(const unsigned* __restrict__ x8, const int* __restrict__ srcs,
                       const int* __restrict__ rowp, const int* __restrict__ deg,
                       const float* __restrict__ invd, ushort* __restrict__ out){
  constexpr int LPR = F/16;      // lanes per row
  constexpr int EPG = 64/LPR;    // concurrent edges per wave
  int w = blockIdx.x*4 + (threadIdx.x>>6);
  int lane = threadIdx.x & 63;
  if (w >= NN) return;
  int st = rowp[w], d = deg[w];
  int grp = lane / LPR;
  int sub = lane % LPR;
  const uint4* xr = (const uint4*)x8;
  floatx2 acc[8];
  #pragma unroll
  for (int v=0;v<8;++v) acc[v] = (floatx2){0.f,0.f};

  auto accum = [&](uint4 u){
    acc[0] += __builtin_amdgcn_cvt_pk_f32_fp8(u.x, false);
    acc[1] += __builtin_amdgcn_cvt_pk_f32_fp8(u.x, true);
    acc[2] += __builtin_amdgcn_cvt_pk_f32_fp8(u.y, false);
    acc[3] += __builtin_amdgcn_cvt_pk_f32_fp8(u.y, true);
    acc[4] += __builtin_amdgcn_cvt_pk_f32_fp8(u.z, false);
    acc[5] += __builtin_amdgcn_cvt_pk_f32_fp8(u.z, true);
    acc[6] += __builtin_amdgcn_cvt_pk_f32_fp8(u.w, false);
    acc[7] += __builtin_amdgcn_cvt_pk_f32_fp8(u.w, true);
  };

  int j = 0;
  for (; j + 4*EPG <= d; j += 4*EPG){
    int i0 = srcs[st + j + grp];
    int i1 = srcs[st + j + EPG + grp];
    int i2 = srcs[st + j + 2*EPG + grp];
    int i3 = srcs[st + j + 3*EPG + grp];
    uint4 u0 = xr[(size_t)i0*LPR + sub];
    uint4 u1 = xr[(size_t)i1*LPR + sub];
    uint4 u2 = xr[(size_t)i2*LPR + sub];
    uint4 u3 = xr[(size_t)i3*LPR + sub];
    accum(u0); accum(u1); accum(u2); accum(u3);
  }
  for (; j < d; j += EPG){
    int jj = j + grp;
    if (jj < d){
      int i0 = srcs[st + jj];
      uint4 u0 = xr[(size_t)i0*LPR + sub];
      accum(u0);
    }
  }
  #pragma unroll
  for (int off = LPR; off < 64; off <<= 1){
    #pragma unroll
    for (int v=0;v<8;++v){
      acc[v].x += __shfl_xor(acc[v].x, off);
      acc[v].y += __shfl_xor(acc[v].y, off);
    }
  }
  if (grp == 0){
    float sc = invd[w];
    uint4 o1, o2;
    o1.x = (unsigned)f2b(acc[0].x*sc) | ((unsigned)f2b(acc[0].y*sc)<<16);
    o1.y = (unsigned)f2b(acc[1].x*sc) | ((unsigned)f2b(acc[1].y*sc)<<16);
    o1.z = (unsigned)f2b(acc[2].x*sc) | ((unsigned)f2b(acc[2].y*sc)<<16);
    o1.w = (unsigned)f2b(acc[3].x*sc) | ((unsigned)f2b(acc[3].y*sc)<<16);
    o2.x = (unsigned)f2b(acc[4].x*sc) | ((unsigned)f2b(acc[4].y*sc)<<16);
    o2.y = (unsigned)f2b(acc[5].x*sc) | ((unsigned)f2b(acc[5].y*sc)<<16);
    o2.z = (unsigned)f2b(acc[6].x*sc) | ((unsigned)f2b(acc[6].y*sc)<<16);
    o2.w = (unsigned)f2b(acc[7].x*sc) | ((unsigned)f2b(acc[7].y*sc)<<16);
    ushort* op = out + (size_t)w*F + sub*16;
    *(uint4*)op = o1;
    *(uint4*)(op + 8) = o2;
  }
}

// MFMA GEMM: out[m][n] = relu( sum_k [A1|A2][m][k] * Wc[n][k] + bias[n] ), bf16 in,
// bf16 out. Optional fused fp8 copy (out8) and fused gate GEMV (gateOut).
#define LDT 72
__global__ __launch_bounds__(512) void k_gemm(
    const ushort* __restrict__ A1, int ldA1,
    const ushort* __restrict__ A2, int ldA2,
    const ushort* __restrict__ Wc, int F2,
    const float* __restrict__ bias, ushort* __restrict__ out,
    unsigned* __restrict__ out8,
    const float* __restrict__ Wg, const float* __restrict__ bg,
    float* __restrict__ gateOut, int M)
{
  __shared__ ushort As[128*LDT];
  __shared__ ushort Bs[256*LDT];
  __shared__ float gl[128][4];
  int t = threadIdx.x;
  int l = t & 63;
  int wv = t >> 6;
  int wr = wv >> 2, wc = wv & 3;
  int m0 = blockIdx.x * 128;
  int F = F2 >> 1;
  f32x4 acc[4][4];
  #pragma unroll
  for (int a=0;a<4;++a)
  #pragma unroll
  for (int b=0;b<4;++b) acc[a][b] = (f32x4){0.f,0.f,0.f,0.f};

  int nsteps = F2/64;
  for (int s=0; s<nsteps; ++s){
    int kk = s*64;
    const ushort* src; int ld, kkl;
    if (kk < F){ src = A1; ld = ldA1; kkl = kk; }
    else       { src = A2; ld = ldA2; kkl = kk - F; }
    uint4 av[2];
    int arow[2], ack[2];
    #pragma unroll
    for (int i=0;i<2;++i){
      int c = t*2 + i;
      arow[i] = c >> 3; ack[i] = c & 7;
      int m = m0 + arow[i];
      av[i] = make_uint4(0u,0u,0u,0u);
      if (m < M) av[i] = *(const uint4*)(src + (size_t)m*ld + kkl + ack[i]*8);
    }
    uint4 bv[4];
    int brow[4], bck[4];
    #pragma unroll
    for (int i=0;i<4;++i){
      int c = t*4 + i;
      brow[i] = c >> 3; bck[i] = c & 7;
      bv[i] = *(const uint4*)(Wc + (size_t)brow[i]*F2 + kk + bck[i]*8);
    }
    #pragma unroll
    for (int i=0;i<2;++i)
      *(uint4*)&As[arow[i]*LDT + ack[i]*8] = av[i];
    #pragma unroll
    for (int i=0;i<4;++i)
      *(uint4*)&Bs[brow[i]*LDT + bck[i]*8] = bv[i];
    __syncthreads();

    #pragma unroll
    for (int ks=0; ks<2; ++ks){
      bf16x8 af[4], bf[4];
      int ko = ks*32 + (l>>4)*8;
      #pragma unroll
      for (int mf=0; mf<4; ++mf)
        af[mf] = *(bf16x8*)&As[(wr*64 + mf*16 + (l&15))*LDT + ko];
      #pragma unroll
      for (int nf=0; nf<4; ++nf)
        bf[nf] = *(bf16x8*)&Bs[(wc*64 + nf*16 + (l&15))*LDT + ko];
      #pragma unroll
      for (int mf=0; mf<4; ++mf)
      #pragma unroll
      for (int nf=0; nf<4; ++nf)
        acc[mf][nf] = __builtin_amdgcn_mfma_f32_16x16x32_bf16(bf[nf], af[mf], acc[mf][nf], 0, 0, 0);
    }
    __syncthreads();
  }

  float gp[4] = {0.f, 0.f, 0.f, 0.f};
  #pragma unroll
  for (int mf=0; mf<4; ++mf){
    int m = m0 + wr*64 + mf*16 + (l&15);
    if (m >= M) continue;
    #pragma unroll
    for (int nf=0; nf<4; ++nf){
      int ncol = wc*64 + nf*16 + (l>>4)*4;
      float4 bb = *(const float4*)&bias[ncol];
      float v0 = fmaxf(acc[mf][nf][0] + bb.x, 0.f);
      float v1 = fmaxf(acc[mf][nf][1] + bb.y, 0.f);
      float v2 = fmaxf(acc[mf][nf][2] + bb.z, 0.f);
      float v3 = fmaxf(acc[mf][nf][3] + bb.w, 0.f);
      ushort4 o;
      o.x = f2b(v0); o.y = f2b(v1); o.z = f2b(v2); o.w = f2b(v3);
      *(ushort4*)(out + (size_t)m*HID + ncol) = o;
      if (out8){
        int r = __builtin_amdgcn_cvt_pk_fp8_f32(v0, v1, 0, false);
        r = __builtin_amdgcn_cvt_pk_fp8_f32(v2, v3, r, true);
        out8[(size_t)m*(HID/4) + (ncol>>2)] = (unsigned)r;
      }
      if (gateOut){
        float4 wgv = *(const float4*)&Wg[ncol];
        gp[mf] += v0*wgv.x + v1*wgv.y + v2*wgv.z + v3*wgv.w;
      }
    }
  }
  if (gateOut){
    #pragma unroll
    for (int mf=0; mf<4; ++mf){
      float g = gp[mf];
      g += __shfl_xor(g, 16);
      g += __shfl_xor(g, 32);
      if ((l >> 4) == 0) gl[wr*64 + mf*16 + (l&15)][wc] = g;
    }
    __syncthreads();
    if (t < 128){
      int m = m0 + t;
      if (m < M)
        gateOut[m] = gl[t][0] + gl[t][1] + gl[t][2] + gl[t][3] + bg[0];
    }
  }
}

// per-segment max and sum-of-exp; segment bounds via in-kernel binary search
__global__ void k_msum(const float* __restrict__ gate, const int* __restrict__ batch,
                       float* __restrict__ m, float* __restrict__ s){
  __shared__ float sm[256];
  int b = blockIdx.x, t = threadIdx.x;
  int lo = 0, hi = NN;
  while (lo < hi){ int mid = (lo+hi)>>1; if (batch[mid] < b) lo = mid+1; else hi = mid; }
  int st = lo;
  hi = NN;
  while (lo < hi){ int mid = (lo+hi)>>1; if (batch[mid] < b+1) lo = mid+1; else hi = mid; }
  int en = lo;
  float mx = -3.0e38f;
  for (int i = st + t; i < en; i += 256) mx = fmaxf(mx, gate[i]);
  sm[t] = mx; __syncthreads();
  for (int o=128;o>0;o>>=1){ if (t<o) sm[t]=fmaxf(sm[t],sm[t+o]); __syncthreads(); }
  float M = sm[0]; __syncthreads();
  float su = 0.f;
  for (int i = st + t; i < en; i += 256) su += expf(gate[i]-M);
  sm[t] = su; __syncthreads();
  for (int o=128;o>0;o>>=1){ if (t<o) sm[t]+=sm[t+o]; __syncthreads(); }
  if (t==0){ m[b]=M; s[b]=sm[0]; }
}

// pooling: 128 nodes/block, 4 node-streams x 64 lanes, lane owns a feature quad.
__global__ __launch_bounds__(256) void k_pool(const ushort* __restrict__ h,
                                              const float* __restrict__ gate,
                                              const int* __restrict__ batch,
                                              const float* __restrict__ m,
                                              const float* __restrict__ s,
                                              float* __restrict__ pooled){
  __shared__ float sa[128];
  __shared__ int sb[128];
  int t = threadIdx.x;
  int i0 = blockIdx.x*128;
  if (t < 128){
    int i = i0 + t;
    if (i < NN){
      int b = batch[i];
      sb[t] = b;
      sa[t] = expf(gate[i] - m[b]) / s[b];
    } else sb[t] = -1;
  }
  __syncthreads();
  int strm = t >> 6;
  int f = (t & 63) * 4;
  int j0 = strm * 32;
  float a0=0.f, a1=0.f, a2=0.f, a3=0.f;
  int bcur = sb[j0];
  for (int j = j0; j < j0 + 32; ++j){
    int i = i0 + j;
    if (i >= NN) break;
    int b = sb[j];
    if (b != bcur){
      if (bcur >= 0){
        atomicAdd(&pooled[bcur*HID + f + 0], a0);
        atomicAdd(&pooled[bcur*HID + f + 1], a1);
        atomicAdd(&pooled[bcur*HID + f + 2], a2);
        atomicAdd(&pooled[bcur*HID + f + 3], a3);
      }
      a0=a1=a2=a3=0.f; bcur = b;
    }
    ushort4 hv = *(const ushort4*)(h + (size_t)i*HID + f);
    float c = sa[j];
    a0 = fmaf(c, b2f(hv.x), a0);
    a1 = fmaf(c, b2f(hv.y), a1);
    a2 = fmaf(c, b2f(hv.z), a2);
    a3 = fmaf(c, b2f(hv.w), a3);
  }
  if (bcur >= 0){
    atomicAdd(&pooled[bcur*HID + f + 0], a0);
    atomicAdd(&pooled[bcur*HID + f + 1], a1);
    atomicAdd(&pooled[bcur*HID + f + 2], a2);
    atomicAdd(&pooled[bcur*HID + f + 3], a3);
  }
}

__global__ void k_head(const float* __restrict__ pooled, const float* __restrict__ Wl1,
                       const float* __restrict__ bl1, const float* __restrict__ Wl2,
                       const float* __restrict__ bl2, float* __restrict__ out){
  __shared__ float pr[256]; __shared__ float o1[256]; __shared__ float lg[16];
  int b = blockIdx.x, t = threadIdx.x;
  pr[t] = pooled[b*HID + t];
  __syncthreads();
  float a = bl1[t];
  const float* wr = Wl1 + (size_t)t*HID;
  #pragma unroll 4
  for (int k=0;k<HID;k+=4){
    float4 w4 = *(const float4*)(wr + k);
    a += pr[k]*w4.x + pr[k+1]*w4.y + pr[k+2]*w4.z + pr[k+3]*w4.w;
  }
  o1[t] = fmaxf(a, 0.f);
  __syncthreads();
  if (t < NC){
    float a2 = bl2[t];
    const float* w2 = Wl2 + (size_t)t*HID;
    for (int k=0;k<HID;++k) a2 += o1[k]*w2[k];
    lg[t] = a2;
  }
  __syncthreads();
  if (t == 0){
    float mx = lg[0];
    for (int c2=1;c2<NC;++c2) mx = fmaxf(mx, lg[c2]);
    float se = 0.f;
    for (int c2=0;c2<NC;++c2) se += expf(lg[c2]-mx);
    float lse = mx + logf(se);
    for (int c2=0;c2<NC;++c2) out[b*NC + c2] = lg[c2] - lse;
  }
}

extern "C" void kernel_launch(void* const* d_in, const int* in_sizes, int n_in,
                              void* d_out, int out_size, void* d_ws, size_t ws_size,
                              hipStream_t stream){
  const float* x   = (const float*)d_in[0];
  const int*   ei  = (const int*)d_in[1];
  const int*   bat = (const int*)d_in[2];
  const float* W1l = (const float*)d_in[3];
  const float* b1l = (const float*)d_in[4];
  const float* W1r = (const float*)d_in[5];
  const float* W2l = (const float*)d_in[6];
  const float* b2l = (const float*)d_in[7];
  const float* W2r = (const float*)d_in[8];
  const float* W3l = (const float*)d_in[9];
  const float* b3l = (const float*)d_in[10];
  const float* W3r = (const float*)d_in[11];
  const float* Wg  = (const float*)d_in[12];
  const float* bg  = (const float*)d_in[13];
  const float* Wl1 = (const float*)d_in[14];
  const float* bl1 = (const float*)d_in[15];
  const float* Wl2 = (const float*)d_in[16];
  const float* bl2 = (const float*)d_in[17];
  const int* srcI = ei;
  const int* dstI = ei + NE;
  float* out = (float*)d_out;

  char* w = (char*)d_ws;
  auto take = [&](size_t bytes)->char*{
    char* p = w; w += (bytes + 255) & ~(size_t)255; return p;
  };
  int*      deg    = (int*)take((size_t)NN*4);
  float*    invd   = (float*)take((size_t)NN*4);
  int*      rowp   = (int*)take((size_t)NN*4);
  int*      gcur   = (int*)take(256*4);
  int*      bincnt = (int*)take(256*4);
  int*      binoff = (int*)take(256*4);
  int*      srcs   = (int*)take((size_t)NE*4);
  unsigned* ebin   = (unsigned*)take((size_t)NE*4);
  float*    gate   = (float*)take((size_t)NN*4);
  float*    m      = (float*)take(64*4);
  float*    s      = (float*)take(64*4);
  float*    pooled = (float*)take(64*256*4);
  ushort*   xb     = (ushort*)take((size_t)NN*FIN*2);
  unsigned* X8     = (unsigned*)take((size_t)NN*FIN);
  ushort*   Wc1    = (ushort*)take((size_t)HID*2*FIN*2);
  ushort*   Wc2    = (ushort*)take((size_t)HID*2*HID*2);
  ushort*   Wc3    = (ushort*)take((size_t)HID*2*HID*2);
  ushort*   AG     = (ushort*)take((size_t)NN*HID*2);
  ushort*   HB     = (ushort*)take((size_t)NN*HID*2);
  unsigned* H8     = (unsigned*)take((size_t)NN*HID);

  k_init<<<(NN+255)/256, 256, 0, stream>>>(bincnt, pooled);
  k_xb<<<(NN*FIN/8+255)/256, 256, 0, stream>>>(x, xb, X8);
  k_wcat<<<(HID*2*FIN+255)/256, 256, 0, stream>>>(W1l, W1r, FIN, Wc1);
  k_wcat<<<(HID*2*HID+255)/256, 256, 0, stream>>>(W2l, W2r, HID, Wc2);
  k_wcat<<<(HID*2*HID+255)/256, 256, 0, stream>>>(W3l, W3r, HID, Wc3);
  k_binhist<<<(NE + 4095)/4096, 256, 0, stream>>>(dstI, bincnt);
  k_scanbins<<<1, 256, 0, stream>>>(bincnt, binoff, gcur);
  k_pass1<<<(NE + 4095)/4096, 256, 0, stream>>>(srcI, dstI, gcur, ebin);
  k_pass2<<<NBINS, 256, 0, stream>>>(ebin, binoff, rowp, deg, invd, srcs);

  int gblocks = (NN + 127)/128;
  // layer 1: agg8(X8) -> AG (bf16, ld 128); h1 = gemm(AG, xb) -> HB (+fp8 H8)
  k_agg8<FIN><<<(NN+3)/4, 256, 0, stream>>>(X8, srcs, rowp, deg, invd, AG);
  k_gemm<<<gblocks, 512, 0, stream>>>(AG, FIN, xb, FIN, Wc1, 2*FIN, b1l, HB, H8,
                                      nullptr, nullptr, nullptr, NN);
  // layer 2: agg8(H8) -> AG; h2 = gemm(AG, HB) -> AG (in-place, +fp8 H8)
  k_agg8<HID><<<(NN+3)/4, 256, 0, stream>>>(H8, srcs, rowp, deg, invd, AG);
  k_gemm<<<gblocks, 512, 0, stream>>>(AG, HID, HB, HID, Wc2, 2*HID, b2l, AG, H8,
                                      nullptr, nullptr, nullptr, NN);
  // layer 3: agg8(H8) -> HB; h3 = gemm(HB, AG) -> HB (+fused gate GEMV)
  k_agg8<HID><<<(NN+3)/4, 256, 0, stream>>>(H8, srcs, rowp, deg, invd, HB);
  k_gemm<<<gblocks, 512, 0, stream>>>(HB, HID, AG, HID, Wc3, 2*HID, b3l, HB,
                                      (unsigned*)nullptr, Wg, bg, gate, NN);

  // attention pooling over h3 = HB
  k_msum<<<NBG, 256, 0, stream>>>(gate, bat, m, s);
  k_pool<<<(NN+127)/128, 256, 0, stream>>>(HB, gate, bat, m, s, pooled);
  k_head<<<NBG, 256, 0, stream>>>(pooled, Wl1, bl1, Wl2, bl2, out);
}